// Round 1
// baseline (2781.061 us; speedup 1.0000x reference)
//
#include <hip/hip_runtime.h>
#include <math.h>

// ---- problem constants (fixed by setup_inputs) ----
#define BB   8
#define S    6144
#define SM1  6143          // memory rows; x[:,SM1,:] == x_pre
#define DM   512
#define H    8
#define DK   64
#define M    32
#define WN   6113          // k + T - M + 1 = 2048+4096-32+1
#define DA   256
#define DAh  32
#define DP   128
#define DPh  16
#define EPSN 1e-12f

// ---- workspace layout (float offsets) ----
#define WS_WKT    0                       // H*DM*DK   = 262144  masked WkT [h][d][k]
#define WS_WKAT   262144                  // H*DA*DAh  = 65536   WkaT [h][a][c]
#define WS_WKPT   327680                  // H*DP*DPh  = 16384   WkpT [h][p][c]
#define WS_QHAT   344064                  // B*H*M*DK  = 131072
#define WS_QAHAT  475136                  // B*H*DAh   = 2048
#define WS_QPHAT  477184                  // B*H*DPh   = 1024
#define WS_LOGITS 478208                  // B*H*WN    = 391232  (becomes attn in-place)
#define WS_XBAR   869440                  // B*H*DM    = 32768   (contiguous after logits)
#define WS_ALAST  902208                  // B*H       = 64
#define WS_RES    902272                  // B*DK      = 512
#define WS_GI     902784                  // 31*B*192  = 47616
#define N_LOGITS  391232
#define N_XBAR    32768
// total ~950400 floats = 3.8 MB

// ---------------------------------------------------------------------------
// prep: masked+transposed Wk -> wkt[h][d][k]; Wka -> wkat[h][a][c]; Wkp -> wkpt[h][p][c]
__global__ void prep_weights(const float* __restrict__ Wk, const float* __restrict__ Wka,
                             const float* __restrict__ Wkp, const int* __restrict__ G,
                             float* __restrict__ wkt, float* __restrict__ wkat,
                             float* __restrict__ wkpt)
{
    int idx = blockIdx.x * 256 + threadIdx.x;
    if (idx < H*DM*DK) {
        int k = idx & 63; int d = (idx >> 6) & 511; int h = idx >> 15;
        wkt[idx] = Wk[(size_t)(h*DK + k)*DM + d] * (float)G[k*DK + (d & 63)];
    }
    int i2 = idx - H*DM*DK;
    if (i2 >= 0 && i2 < H*DA*DAh) {
        int c = i2 & 31; int a = (i2 >> 5) & 255; int h = i2 >> 13;
        wkat[i2] = Wka[(size_t)(h*DAh + c)*DA + a];
    }
    int i3 = idx - H*DM*DK - H*DA*DAh;
    if (i3 >= 0 && i3 < H*DP*DPh) {
        int c = i3 & 15; int p = (i3 >> 4) & 127; int h = i3 >> 11;
        wkpt[i3] = Wkp[(size_t)(h*DPh + c)*DP + p];
    }
}

// ---------------------------------------------------------------------------
// qhat: normalized Q rows for last M positions, plus qa_hat/qp_hat at last row.
__global__ __launch_bounds__(256) void qhat_k(
    const float* __restrict__ memory, const float* __restrict__ x_pre,
    const float* __restrict__ aux, const float* __restrict__ pos,
    const float* __restrict__ Wq, const float* __restrict__ bq,
    const float* __restrict__ Wqa, const float* __restrict__ bqa,
    const float* __restrict__ Wqp, const float* __restrict__ bqp,
    const int* __restrict__ G,
    float* __restrict__ qhat, float* __restrict__ qahat, float* __restrict__ qphat)
{
    int bh = blockIdx.x; int b = bh >> 3, h = bh & 7;
    int tid = threadIdx.x;
    __shared__ float q[M][DK];
    __shared__ float nrm[M];
    __shared__ float qa[DAh];
    __shared__ float qp[DPh];

    int k = tid & 63;
    int mg = tid >> 6;                    // 0..3
    for (int mp = 0; mp < 8; ++mp) {
        int m = mp*4 + mg;
        int t = S - M + m;                // 6112..6143
        const float* xr = (t < SM1) ? (memory + ((size_t)b*SM1 + t)*DM)
                                    : (x_pre + (size_t)b*DM);
        const float* wr = Wq + (size_t)(h*DK + k)*DM;
        const int* grow = G + k*DK;
        float s = 0.f;
        for (int d = 0; d < DM; ++d) s += xr[d] * wr[d] * (float)grow[d & 63];
        q[m][k] = s + bq[h*DK + k];
    }
    if (tid < DAh) {
        int c = tid;
        const float* ar = aux + ((size_t)b*S + (S-1))*DA;
        const float* wr = Wqa + (size_t)(h*DAh + c)*DA;
        float s = 0.f;
        for (int a = 0; a < DA; ++a) s += ar[a]*wr[a];
        qa[c] = s + bqa[h*DAh + c];
    }
    if (tid >= 64 && tid < 64 + DPh) {
        int c = tid - 64;
        const float* pr = pos + ((size_t)b*S + (S-1))*DP;
        const float* wr = Wqp + (size_t)(h*DPh + c)*DP;
        float s = 0.f;
        for (int p2 = 0; p2 < DP; ++p2) s += pr[p2]*wr[p2];
        qp[c] = s + bqp[h*DPh + c];
    }
    __syncthreads();
    if (tid < M) {
        float s = 0.f;
        for (int kk = 0; kk < DK; ++kk) { float v = q[tid][kk]; s += v*v; }
        nrm[tid] = fmaxf(sqrtf(s), EPSN);
    }
    __syncthreads();
    for (int i = tid; i < M*DK; i += 256) {
        int m = i >> 6, kk = i & 63;
        qhat[(size_t)bh*M*DK + i] = q[m][kk] / nrm[m];
    }
    if (tid < DAh) {
        float s = 0.f;
        for (int c = 0; c < DAh; ++c) s += qa[c]*qa[c];
        qahat[(size_t)bh*DAh + tid] = qa[tid] / fmaxf(sqrtf(s), EPSN);
    }
    if (tid < DPh) {
        float s = 0.f;
        for (int c = 0; c < DPh; ++c) s += qp[c]*qp[c];
        qphat[(size_t)bh*DPh + tid] = qp[tid] / fmaxf(sqrtf(s), EPSN);
    }
}

// ---------------------------------------------------------------------------
// K projection (masked, biased, l2-normalized) fused with banded Q.K -> logits (+= w/M * dot)
// One block = (b, h, 32-row tile of t). Tiled fp32 GEMM through LDS.
#define TILE_T 32
__global__ __launch_bounds__(256) void kproj_band(
    const float* __restrict__ memory, const float* __restrict__ x_pre,
    const float* __restrict__ wkt, const float* __restrict__ bk,
    const float* __restrict__ qhat, const float* __restrict__ wscal,
    float* __restrict__ logits)
{
    int tile = blockIdx.x % (S / TILE_T);
    int h = (blockIdx.x / (S / TILE_T)) % H;
    int b = blockIdx.x / ((S / TILE_T) * H);
    int t0 = tile * TILE_T;
    int tid = threadIdx.x;
    int ty = tid >> 4;            // 0..15
    int tx = tid & 15;            // 0..15

    __shared__ float As[TILE_T][68];      // +4 pad: kills 4-way bank alias on a-reads
    __shared__ float Bs[64][64];
    __shared__ float Kh[TILE_T][65];      // +1 pad: conflict-free column reads in dots
    __shared__ float Qh[M][65];
    __shared__ float tnloc[64];
    __shared__ float norms[TILE_T];

    {   // stage qhat tile
        const float* qsrc = qhat + (size_t)(b*H + h)*M*DK;
        for (int i = tid; i < M*DK; i += 256) Qh[i >> 6][i & 63] = qsrc[i];
    }
    if (tid < 64) tnloc[tid] = 0.f;

    float acc[2][4];
    #pragma unroll
    for (int i = 0; i < 2; ++i)
        #pragma unroll
        for (int j = 0; j < 4; ++j) acc[i][j] = 0.f;

    const float* wk_h = wkt + (size_t)h * DM * DK;

    for (int dt = 0; dt < DM/64; ++dt) {
        int d0 = dt * 64;
        {   // A-tile: 32 rows x 64 d
            int row = tid >> 3;
            int col = (tid & 7) * 8;
            int t = t0 + row;
            const float* xr = (t < SM1) ? (memory + ((size_t)b*SM1 + t)*DM)
                                        : (x_pre + (size_t)b*DM);
            const float4* src = (const float4*)(xr + d0 + col);
            float4 v0 = src[0], v1 = src[1];
            *(float4*)&As[row][col]   = v0;
            *(float4*)&As[row][col+4] = v1;
        }
        {   // B-tile: 64 d x 64 k
            int dd  = tid >> 2;
            int col = (tid & 3) * 16;
            const float4* src = (const float4*)(wk_h + (size_t)(d0 + dd)*DK + col);
            float4 v0 = src[0], v1 = src[1], v2 = src[2], v3 = src[3];
            *(float4*)&Bs[dd][col]    = v0;
            *(float4*)&Bs[dd][col+4]  = v1;
            *(float4*)&Bs[dd][col+8]  = v2;
            *(float4*)&Bs[dd][col+12] = v3;
        }
        __syncthreads();
        int r0 = ty * 2;
        #pragma unroll 8
        for (int dd = 0; dd < 64; ++dd) {
            float a0 = As[r0][dd];
            float a1 = As[r0+1][dd];
            float4 b4 = *(const float4*)&Bs[dd][tx*4];
            acc[0][0] += a0*b4.x; acc[0][1] += a0*b4.y; acc[0][2] += a0*b4.z; acc[0][3] += a0*b4.w;
            acc[1][0] += a1*b4.x; acc[1][1] += a1*b4.y; acc[1][2] += a1*b4.z; acc[1][3] += a1*b4.w;
        }
        __syncthreads();
    }
    {   // bias + store to Kh
        int r0 = ty * 2;
        #pragma unroll
        for (int i = 0; i < 2; ++i)
            #pragma unroll
            for (int j = 0; j < 4; ++j) {
                int k = tx*4 + j;
                Kh[r0+i][k] = acc[i][j] + bk[h*DK + k];
            }
    }
    __syncthreads();
    if (tid < TILE_T) {
        float s = 0.f;
        #pragma unroll 8
        for (int k = 0; k < 64; ++k) { float v = Kh[tid][k]; s += v*v; }
        norms[tid] = fmaxf(sqrtf(s), EPSN);
    }
    __syncthreads();
    {
        int r = tid >> 3; int kb = (tid & 7) * 8;
        float inv = 1.f / norms[r];
        #pragma unroll
        for (int i = 0; i < 8; ++i) Kh[r][kb+i] *= inv;
    }
    __syncthreads();
    {   // banded dots: (t_local, m) -> diag (t_local - m + 31), pre-reduced in LDS
        float wom = wscal[0] * (1.f/32.f);
        int tl = tid & 31;
        int mg = tid >> 5;                // 0..7
        #pragma unroll
        for (int mi = 0; mi < 4; ++mi) {
            int m = mg + mi*8;
            int j = t0 + tl - m;
            float d = 0.f;
            #pragma unroll 8
            for (int k = 0; k < 64; ++k) d += Qh[m][k] * Kh[tl][k];
            if (j >= 0 && j < WN) atomicAdd(&tnloc[tl - m + 31], wom * d);
        }
    }
    __syncthreads();
    if (tid < 63) {
        int j = t0 + tid - 31;
        if (j >= 0 && j < WN)
            atomicAdd(&logits[(size_t)(b*H + h)*WN + j], tnloc[tid]);
    }
}

// ---------------------------------------------------------------------------
// dot2: one wave per (b,h,j); KA row projected, normalized, dotted with qa_hat.
__global__ __launch_bounds__(256) void ka_dot2(
    const float* __restrict__ aux, const float* __restrict__ wkat,
    const float* __restrict__ bka, const float* __restrict__ qahat,
    const float* __restrict__ wa, float* __restrict__ logits)
{
    int wid = blockIdx.x * 4 + (threadIdx.x >> 6);
    int lane = threadIdx.x & 63;
    int j = wid % WN;
    int bh = wid / WN;
    if (bh >= BB*H) return;
    int b = bh >> 3, h = bh & 7;
    int t = 31 + j;
    int c = lane & 31, half = lane >> 5;
    const float* ar = aux + ((size_t)b*S + t)*DA + half*128;
    const float* wv = wkat + (size_t)h*DA*DAh + (size_t)(half*128)*DAh + c;
    float p = 0.f;
    #pragma unroll 4
    for (int i = 0; i < 128; ++i) p += ar[i] * wv[(size_t)i*DAh];
    p += __shfl_xor(p, 32);
    float v = p + bka[h*DAh + c];
    float s = v*v;
    #pragma unroll
    for (int d = 16; d >= 1; d >>= 1) s += __shfl_xor(s, d);
    float inv = 1.f / fmaxf(sqrtf(s), EPSN);
    float dp = (v * inv) * qahat[(size_t)bh*DAh + c];
    #pragma unroll
    for (int d = 16; d >= 1; d >>= 1) dp += __shfl_xor(dp, d);
    if (lane == 0) logits[(size_t)bh*WN + j] += wa[0] * dp;   // unique writer per j
}

// dot3: same for pos path (DPh=16, DP=128)
__global__ __launch_bounds__(256) void kp_dot3(
    const float* __restrict__ pos, const float* __restrict__ wkpt,
    const float* __restrict__ bkp, const float* __restrict__ qphat,
    const float* __restrict__ wp, float* __restrict__ logits)
{
    int wid = blockIdx.x * 4 + (threadIdx.x >> 6);
    int lane = threadIdx.x & 63;
    int j = wid % WN;
    int bh = wid / WN;
    if (bh >= BB*H) return;
    int b = bh >> 3, h = bh & 7;
    int t = 31 + j;
    int c = lane & 15, q4 = lane >> 4;
    const float* pr = pos + ((size_t)b*S + t)*DP + q4*32;
    const float* wv = wkpt + (size_t)h*DP*DPh + (size_t)(q4*32)*DPh + c;
    float p = 0.f;
    #pragma unroll 4
    for (int i = 0; i < 32; ++i) p += pr[i] * wv[(size_t)i*DPh];
    p += __shfl_xor(p, 16);
    p += __shfl_xor(p, 32);
    float v = p + bkp[h*DPh + c];
    float s = v*v;
    #pragma unroll
    for (int d = 8; d >= 1; d >>= 1) s += __shfl_xor(s, d);
    float inv = 1.f / fmaxf(sqrtf(s), EPSN);
    float dp = (v * inv) * qphat[(size_t)bh*DPh + c];
    #pragma unroll
    for (int d = 8; d >= 1; d >>= 1) dp += __shfl_xor(dp, d);
    if (lane == 0) logits[(size_t)bh*WN + j] += wp[0] * dp;
}

// ---------------------------------------------------------------------------
// softmax over WN per (b,h); in-place logits -> attn; record attn[WN-1]
__global__ __launch_bounds__(256) void softmax_k(float* __restrict__ logits,
                                                 float* __restrict__ alast)
{
    int bh = blockIdx.x;
    float* L = logits + (size_t)bh*WN;
    __shared__ float red[256];
    int tid = threadIdx.x;
    float mx = -1e30f;
    for (int j = tid; j < WN; j += 256) mx = fmaxf(mx, L[j]);
    red[tid] = mx; __syncthreads();
    for (int s2 = 128; s2 > 0; s2 >>= 1) {
        if (tid < s2) red[tid] = fmaxf(red[tid], red[tid+s2]);
        __syncthreads();
    }
    mx = red[0]; __syncthreads();
    float sm = 0.f;
    for (int j = tid; j < WN; j += 256) sm += expf(L[j] - mx);
    red[tid] = sm; __syncthreads();
    for (int s2 = 128; s2 > 0; s2 >>= 1) {
        if (tid < s2) red[tid] += red[tid+s2];
        __syncthreads();
    }
    float inv = 1.f / red[0];
    for (int j = tid; j < WN; j += 256) {
        float a = expf(L[j] - mx) * inv;
        L[j] = a;
        if (j == WN-1) alast[bh] = a;
    }
}

// ---------------------------------------------------------------------------
// xbar[b,h,:] = sum_{j<WN-1} attn[b,h,j] * x[b, 31+j, :]   (V GEMM folded away)
#define JC 191   // 32 chunks * 191 = 6112 = WN-1 exactly
__global__ __launch_bounds__(256) void xbar_k(
    const float* __restrict__ memory, const float* __restrict__ attn,
    float* __restrict__ xbar)
{
    int chunk = blockIdx.x & 31;
    int b = blockIdx.x >> 5;
    int j0 = chunk * JC;
    __shared__ float al[H][JC];
    int tid = threadIdx.x;
    for (int i = tid; i < H*JC; i += 256) {
        int hh = i / JC, jj = i - hh*JC;
        al[hh][jj] = attn[(size_t)(b*H + hh)*WN + j0 + jj];
    }
    __syncthreads();
    int d0 = tid * 2;
    float acc[H][2];
    #pragma unroll
    for (int hh = 0; hh < H; ++hh) { acc[hh][0] = 0.f; acc[hh][1] = 0.f; }
    for (int jj = 0; jj < JC; ++jj) {
        int t = 31 + j0 + jj;             // <= 6142, always memory
        const float2 xv = *(const float2*)(memory + ((size_t)b*SM1 + t)*DM + d0);
        #pragma unroll
        for (int hh = 0; hh < H; ++hh) {
            float a = al[hh][jj];
            acc[hh][0] += a * xv.x;
            acc[hh][1] += a * xv.y;
        }
    }
    #pragma unroll
    for (int hh = 0; hh < H; ++hh) {
        atomicAdd(&xbar[(size_t)(b*H+hh)*DM + d0],     acc[hh][0]);
        atomicAdd(&xbar[(size_t)(b*H+hh)*DM + d0 + 1], acc[hh][1]);
    }
}

// ---------------------------------------------------------------------------
// GRU input gates for the 31 recent rows: gi[t,b,c] = b_ih[c] + x_row . W_ih[c,:]
__global__ __launch_bounds__(192) void gi_k(
    const float* __restrict__ memory, const float* __restrict__ W_ih,
    const float* __restrict__ b_ih, float* __restrict__ gi_all)
{
    int t = blockIdx.x >> 3;
    int b = blockIdx.x & 7;
    int c = threadIdx.x;
    const float* xr = memory + ((size_t)b*SM1 + (S - M) + t)*DM;   // rows 6112..6142
    const float* wr = W_ih + (size_t)c*DM;
    float s = b_ih[c];
    for (int d = 0; d < DM; d += 4) {
        float4 x4 = *(const float4*)(xr + d);
        float4 w4 = *(const float4*)(wr + d);
        s += x4.x*w4.x + x4.y*w4.y + x4.z*w4.z + x4.w*w4.w;
    }
    gi_all[((size_t)t*BB + b)*192 + c] = s;
}

// GRU scan: 31 sequential steps, all batches in one block.
__global__ __launch_bounds__(512) void gru_scan(
    const float* __restrict__ gi_all, const float* __restrict__ W_hh,
    const float* __restrict__ b_hh, float* __restrict__ res)
{
    __shared__ float Wl[192*64];
    __shared__ float bl[192];
    __shared__ float hst[BB][DK];
    __shared__ float ghl[BB][192];
    int tid = threadIdx.x;
    for (int i = tid; i < 192*64; i += 512) Wl[i] = W_hh[i];
    if (tid < 192) bl[tid] = b_hh[tid];
    { int bb = tid >> 6, k = tid & 63; hst[bb][k] = 0.f; }
    __syncthreads();
    for (int t = 0; t < 31; ++t) {
        #pragma unroll
        for (int i = 0; i < 3; ++i) {
            int idx = tid + i*512;
            int bb = idx / 192, c = idx - bb*192;
            float s = bl[c];
            #pragma unroll 8
            for (int k2 = 0; k2 < 64; ++k2) s += hst[bb][k2] * Wl[c*64 + k2];
            ghl[bb][c] = s;
        }
        __syncthreads();
        int bb = tid >> 6, k = tid & 63;
        const float* gi = gi_all + ((size_t)t*BB + bb)*192;
        float ir = gi[k], iz = gi[64+k], in = gi[128+k];
        float hr = ghl[bb][k], hz = ghl[bb][64+k], hn = ghl[bb][128+k];
        float r = 1.f/(1.f + expf(-(ir + hr)));
        float z = 1.f/(1.f + expf(-(iz + hz)));
        float n = tanhf(in + r*hn);
        float hnew = (1.f - z)*n + z*hst[bb][k];
        hst[bb][k] = hnew;                 // own element; all cross reads done pre-sync
        __syncthreads();
    }
    int bb = tid >> 6, k = tid & 63;
    res[bb*DK + k] = hst[bb][k];
}

// ---------------------------------------------------------------------------
// epilogue: hist = Wv_masked . xbar + bv*(1-alast); deta = hist + alast*res;
//           out = x_pre + WO_masked . deta + bO
__global__ __launch_bounds__(512) void final_k(
    const float* __restrict__ x_pre, const float* __restrict__ xbar,
    const float* __restrict__ Wv, const float* __restrict__ bv,
    const float* __restrict__ WO, const float* __restrict__ bO,
    const float* __restrict__ alast, const float* __restrict__ res,
    const int* __restrict__ G, float* __restrict__ out)
{
    int b = blockIdx.x;
    int tid = threadIdx.x;
    __shared__ float gl[64*64];      // gl[e*64 + k] = G[k][e]  (transposed: conflict-free)
    __shared__ float deta[512];
    for (int i = tid; i < 4096; i += 512) gl[i] = (float)G[(i & 63)*64 + (i >> 6)];
    __syncthreads();
    int h = tid >> 6, dk = tid & 63;
    float ala = alast[b*H + h];
    const float* xb  = xbar + (size_t)(b*H + h)*DM;
    const float* wvr = Wv + (size_t)tid*DM;
    const float* gcol = gl + dk;
    float s = 0.f;
    for (int e = 0; e < DM; e += 4) {
        float4 wv4 = *(const float4*)(wvr + e);
        float4 xb4 = *(const float4*)(xb + e);
        int eb = e & 63;
        s += wv4.x*gcol[eb*64]     *xb4.x + wv4.y*gcol[(eb+1)*64]*xb4.y
           + wv4.z*gcol[(eb+2)*64]*xb4.z + wv4.w*gcol[(eb+3)*64]*xb4.w;
    }
    float hist = s + bv[tid]*(1.f - ala);
    deta[tid] = hist + ala * res[b*DK + dk];
    __syncthreads();
    int dpos = tid;
    const float* wor = WO + (size_t)dpos*DM;
    const float* gcol2 = gl + (dpos & 63);
    float o = 0.f;
    for (int jj = 0; jj < DM; jj += 4) {
        float4 wo4 = *(const float4*)(wor + jj);
        int jb = jj & 63;
        o += wo4.x*gcol2[jb*64]     *deta[jj]   + wo4.y*gcol2[(jb+1)*64]*deta[jj+1]
           + wo4.z*gcol2[(jb+2)*64]*deta[jj+2] + wo4.w*gcol2[(jb+3)*64]*deta[jj+3];
    }
    out[(size_t)b*DM + dpos] = x_pre[(size_t)b*DM + dpos] + o + bO[dpos];
}

// ---------------------------------------------------------------------------
extern "C" void kernel_launch(void* const* d_in, const int* in_sizes, int n_in,
                              void* d_out, int out_size, void* d_ws, size_t ws_size,
                              hipStream_t stream)
{
    const float* memory = (const float*)d_in[0];
    const float* x_pre  = (const float*)d_in[1];
    const float* aux    = (const float*)d_in[2];
    const float* pos    = (const float*)d_in[3];
    const float* Wq  = (const float*)d_in[4];
    const float* bq  = (const float*)d_in[5];
    const float* Wk  = (const float*)d_in[6];
    const float* bk  = (const float*)d_in[7];
    const float* Wv  = (const float*)d_in[8];
    const float* bv  = (const float*)d_in[9];
    const float* Wqa = (const float*)d_in[10];
    const float* bqa = (const float*)d_in[11];
    const float* Wka = (const float*)d_in[12];
    const float* bka = (const float*)d_in[13];
    const float* Wqp = (const float*)d_in[14];
    const float* bqp = (const float*)d_in[15];
    const float* Wkp = (const float*)d_in[16];
    const float* bkp = (const float*)d_in[17];
    const float* W_ih = (const float*)d_in[18];
    const float* W_hh = (const float*)d_in[19];
    const float* b_ih = (const float*)d_in[20];
    const float* b_hh = (const float*)d_in[21];
    const float* WO  = (const float*)d_in[22];
    const float* bO  = (const float*)d_in[23];
    const float* w   = (const float*)d_in[24];
    const float* w_a = (const float*)d_in[25];
    const float* w_p = (const float*)d_in[26];
    const int*   G   = (const int*)d_in[27];
    (void)in_sizes; (void)n_in; (void)out_size; (void)ws_size;

    float* ws = (float*)d_ws;
    float* wkt    = ws + WS_WKT;
    float* wkat   = ws + WS_WKAT;
    float* wkpt   = ws + WS_WKPT;
    float* qhat   = ws + WS_QHAT;
    float* qahat  = ws + WS_QAHAT;
    float* qphat  = ws + WS_QPHAT;
    float* logits = ws + WS_LOGITS;
    float* xbar   = ws + WS_XBAR;
    float* alast  = ws + WS_ALAST;
    float* resb   = ws + WS_RES;
    float* gi_all = ws + WS_GI;
    float* outp   = (float*)d_out;

    // zero logits + xbar (contiguous)
    hipMemsetAsync(logits, 0, (size_t)(N_LOGITS + N_XBAR)*sizeof(float), stream);

    prep_weights<<<(H*DM*DK + H*DA*DAh + H*DP*DPh + 255)/256, 256, 0, stream>>>(
        Wk, Wka, Wkp, G, wkt, wkat, wkpt);

    qhat_k<<<BB*H, 256, 0, stream>>>(memory, x_pre, aux, pos, Wq, bq, Wqa, bqa,
                                     Wqp, bqp, G, qhat, qahat, qphat);

    kproj_band<<<BB*H*(S/TILE_T), 256, 0, stream>>>(memory, x_pre, wkt, bk, qhat,
                                                    w, logits);

    ka_dot2<<<(BB*H*WN)/4, 256, 0, stream>>>(aux, wkat, bka, qahat, w_a, logits);
    kp_dot3<<<(BB*H*WN)/4, 256, 0, stream>>>(pos, wkpt, bkp, qphat, w_p, logits);

    softmax_k<<<BB*H, 256, 0, stream>>>(logits, alast);

    xbar_k<<<BB*32, 256, 0, stream>>>(memory, logits, xbar);

    gi_k<<<31*BB, 192, 0, stream>>>(memory, W_ih, b_ih, gi_all);
    gru_scan<<<1, 512, 0, stream>>>(gi_all, W_hh, b_hh, resb);

    final_k<<<BB, 512, 0, stream>>>(x_pre, xbar, Wv, bv, WO, bO, alast, resb, G, outp);
}

// Round 2
// 1624.590 us; speedup vs baseline: 1.7119x; 1.7119x over previous
//
#include <hip/hip_runtime.h>
#include <math.h>

// ---- problem constants (fixed by setup_inputs) ----
#define BB   8
#define S    6144
#define SM1  6143          // memory rows; x[:,SM1,:] == x_pre
#define DM   512
#define H    8
#define DK   64
#define M    32
#define WN   6113          // k + T - M + 1 = 2048+4096-32+1
#define DA   256
#define DAh  32
#define DP   128
#define DPh  16
#define EPSN 1e-12f

// ---- workspace layout (float offsets) ----
#define WS_WKT    0                       // H*DM*DK   = 262144  masked WkT [h][d][k]
#define WS_WKAT   262144                  // H*DA*DAh  = 65536   WkaT [h][a][c]
#define WS_WKPT   327680                  // H*DP*DPh  = 16384   WkpT [h][p][c]
#define WS_QHAT   344064                  // B*H*M*DK  = 131072
#define WS_QAHAT  475136                  // B*H*DAh   = 2048
#define WS_QPHAT  477184                  // B*H*DPh   = 1024
#define WS_LOGITS 478208                  // B*H*WN    = 391232  (becomes attn in-place)
#define WS_XBAR   869440                  // B*H*DM    = 32768   (contiguous after logits)
#define WS_ALAST  902208                  // B*H       = 64
#define WS_RES    902272                  // B*DK      = 512
#define WS_GI     902784                  // 31*B*192  = 47616
#define WS_WQM    950400                  // H*DK*DM   = 262144  masked Wq [h][k][d]
#define N_LOGITS  391232
#define N_XBAR    32768
// total 1212544 floats = 4.85 MB

// ---------------------------------------------------------------------------
// prep: masked+transposed Wk -> wkt[h][d][k]; Wka -> wkat[h][a][c];
//       Wkp -> wkpt[h][p][c]; masked Wq (same layout as input) -> wqm
__global__ void prep_weights(const float* __restrict__ Wk, const float* __restrict__ Wka,
                             const float* __restrict__ Wkp, const float* __restrict__ Wq,
                             const int* __restrict__ G,
                             float* __restrict__ wkt, float* __restrict__ wkat,
                             float* __restrict__ wkpt, float* __restrict__ wqm)
{
    int idx = blockIdx.x * 256 + threadIdx.x;
    if (idx < H*DM*DK) {
        int k = idx & 63; int d = (idx >> 6) & 511; int h = idx >> 15;
        wkt[idx] = Wk[(size_t)(h*DK + k)*DM + d] * (float)G[k*DK + (d & 63)];
    }
    int i2 = idx - H*DM*DK;
    if (i2 >= 0 && i2 < H*DA*DAh) {
        int c = i2 & 31; int a = (i2 >> 5) & 255; int h = i2 >> 13;
        wkat[i2] = Wka[(size_t)(h*DAh + c)*DA + a];
    }
    int i3 = idx - H*DM*DK - H*DA*DAh;
    if (i3 >= 0 && i3 < H*DP*DPh) {
        int c = i3 & 15; int p = (i3 >> 4) & 127; int h = i3 >> 11;
        wkpt[i3] = Wkp[(size_t)(h*DPh + c)*DP + p];
    }
    int i4 = idx - H*DM*DK - H*DA*DAh - H*DP*DPh;
    if (i4 >= 0 && i4 < H*DK*DM) {
        int d = i4 & 511; int k = (i4 >> 9) & 63;
        wqm[i4] = Wq[i4] * (float)G[k*DK + (d & 63)];
    }
}

// ---------------------------------------------------------------------------
// qhat: normalized Q rows for last M positions, plus qa_hat/qp_hat at last row.
__global__ __launch_bounds__(256) void qhat_k(
    const float* __restrict__ memory, const float* __restrict__ x_pre,
    const float* __restrict__ aux, const float* __restrict__ pos,
    const float* __restrict__ wqm, const float* __restrict__ bq,
    const float* __restrict__ Wqa, const float* __restrict__ bqa,
    const float* __restrict__ Wqp, const float* __restrict__ bqp,
    float* __restrict__ qhat, float* __restrict__ qahat, float* __restrict__ qphat)
{
    int bh = blockIdx.x; int b = bh >> 3, h = bh & 7;
    int tid = threadIdx.x;
    __shared__ float q[M][DK];
    __shared__ float nrm[M];
    __shared__ float qa[DAh];
    __shared__ float qp[DPh];

    int k = tid & 63;
    int mg = tid >> 6;                    // 0..3
    const float* wr = wqm + (size_t)(h*DK + k)*DM;
    for (int mp = 0; mp < 8; ++mp) {
        int m = mp*4 + mg;
        int t = S - M + m;                // 6112..6143
        const float* xr = (t < SM1) ? (memory + ((size_t)b*SM1 + t)*DM)
                                    : (x_pre + (size_t)b*DM);
        float s = 0.f;
        for (int d = 0; d < DM; d += 4) {
            float4 x4 = *(const float4*)(xr + d);
            float4 w4 = *(const float4*)(wr + d);
            s += x4.x*w4.x + x4.y*w4.y + x4.z*w4.z + x4.w*w4.w;
        }
        q[m][k] = s + bq[h*DK + k];
    }
    if (tid < DAh) {
        int c = tid;
        const float* ar = aux + ((size_t)b*S + (S-1))*DA;
        const float* wv = Wqa + (size_t)(h*DAh + c)*DA;
        float s = 0.f;
        for (int a = 0; a < DA; ++a) s += ar[a]*wv[a];
        qa[c] = s + bqa[h*DAh + c];
    }
    if (tid >= 64 && tid < 64 + DPh) {
        int c = tid - 64;
        const float* pr = pos + ((size_t)b*S + (S-1))*DP;
        const float* wv = Wqp + (size_t)(h*DPh + c)*DP;
        float s = 0.f;
        for (int p2 = 0; p2 < DP; ++p2) s += pr[p2]*wv[p2];
        qp[c] = s + bqp[h*DPh + c];
    }
    __syncthreads();
    if (tid < M) {
        float s = 0.f;
        for (int kk = 0; kk < DK; ++kk) { float v = q[tid][kk]; s += v*v; }
        nrm[tid] = fmaxf(sqrtf(s), EPSN);
    }
    __syncthreads();
    for (int i = tid; i < M*DK; i += 256) {
        int m = i >> 6, kk = i & 63;
        qhat[(size_t)bh*M*DK + i] = q[m][kk] / nrm[m];
    }
    if (tid < DAh) {
        float s = 0.f;
        for (int c = 0; c < DAh; ++c) s += qa[c]*qa[c];
        qahat[(size_t)bh*DAh + tid] = qa[tid] / fmaxf(sqrtf(s), EPSN);
    }
    if (tid < DPh) {
        float s = 0.f;
        for (int c = 0; c < DPh; ++c) s += qp[c]*qp[c];
        qphat[(size_t)bh*DPh + tid] = qp[tid] / fmaxf(sqrtf(s), EPSN);
    }
}

// ---------------------------------------------------------------------------
// K projection (masked, biased, l2-normalized) fused with banded Q.K -> logits (+= w/M * dot)
#define TILE_T 32
__global__ __launch_bounds__(256) void kproj_band(
    const float* __restrict__ memory, const float* __restrict__ x_pre,
    const float* __restrict__ wkt, const float* __restrict__ bk,
    const float* __restrict__ qhat, const float* __restrict__ wscal,
    float* __restrict__ logits)
{
    int tile = blockIdx.x % (S / TILE_T);
    int h = (blockIdx.x / (S / TILE_T)) % H;
    int b = blockIdx.x / ((S / TILE_T) * H);
    int t0 = tile * TILE_T;
    int tid = threadIdx.x;
    int ty = tid >> 4;            // 0..15
    int tx = tid & 15;            // 0..15

    __shared__ float As[TILE_T][68];
    __shared__ float Bs[64][64];
    __shared__ float Kh[TILE_T][65];
    __shared__ float Qh[M][65];
    __shared__ float tnloc[64];
    __shared__ float norms[TILE_T];

    {
        const float* qsrc = qhat + (size_t)(b*H + h)*M*DK;
        for (int i = tid; i < M*DK; i += 256) Qh[i >> 6][i & 63] = qsrc[i];
    }
    if (tid < 64) tnloc[tid] = 0.f;

    float acc[2][4];
    #pragma unroll
    for (int i = 0; i < 2; ++i)
        #pragma unroll
        for (int j = 0; j < 4; ++j) acc[i][j] = 0.f;

    const float* wk_h = wkt + (size_t)h * DM * DK;

    for (int dt = 0; dt < DM/64; ++dt) {
        int d0 = dt * 64;
        {
            int row = tid >> 3;
            int col = (tid & 7) * 8;
            int t = t0 + row;
            const float* xr = (t < SM1) ? (memory + ((size_t)b*SM1 + t)*DM)
                                        : (x_pre + (size_t)b*DM);
            const float4* src = (const float4*)(xr + d0 + col);
            float4 v0 = src[0], v1 = src[1];
            *(float4*)&As[row][col]   = v0;
            *(float4*)&As[row][col+4] = v1;
        }
        {
            int dd  = tid >> 2;
            int col = (tid & 3) * 16;
            const float4* src = (const float4*)(wk_h + (size_t)(d0 + dd)*DK + col);
            float4 v0 = src[0], v1 = src[1], v2 = src[2], v3 = src[3];
            *(float4*)&Bs[dd][col]    = v0;
            *(float4*)&Bs[dd][col+4]  = v1;
            *(float4*)&Bs[dd][col+8]  = v2;
            *(float4*)&Bs[dd][col+12] = v3;
        }
        __syncthreads();
        int r0 = ty * 2;
        #pragma unroll 8
        for (int dd = 0; dd < 64; ++dd) {
            float a0 = As[r0][dd];
            float a1 = As[r0+1][dd];
            float4 b4 = *(const float4*)&Bs[dd][tx*4];
            acc[0][0] += a0*b4.x; acc[0][1] += a0*b4.y; acc[0][2] += a0*b4.z; acc[0][3] += a0*b4.w;
            acc[1][0] += a1*b4.x; acc[1][1] += a1*b4.y; acc[1][2] += a1*b4.z; acc[1][3] += a1*b4.w;
        }
        __syncthreads();
    }
    {
        int r0 = ty * 2;
        #pragma unroll
        for (int i = 0; i < 2; ++i)
            #pragma unroll
            for (int j = 0; j < 4; ++j) {
                int k = tx*4 + j;
                Kh[r0+i][k] = acc[i][j] + bk[h*DK + k];
            }
    }
    __syncthreads();
    if (tid < TILE_T) {
        float s = 0.f;
        #pragma unroll 8
        for (int k = 0; k < 64; ++k) { float v = Kh[tid][k]; s += v*v; }
        norms[tid] = fmaxf(sqrtf(s), EPSN);
    }
    __syncthreads();
    {
        int r = tid >> 3; int kb = (tid & 7) * 8;
        float inv = 1.f / norms[r];
        #pragma unroll
        for (int i = 0; i < 8; ++i) Kh[r][kb+i] *= inv;
    }
    __syncthreads();
    {
        float wom = wscal[0] * (1.f/32.f);
        int tl = tid & 31;
        int mg = tid >> 5;
        #pragma unroll
        for (int mi = 0; mi < 4; ++mi) {
            int m = mg + mi*8;
            int j = t0 + tl - m;
            float d = 0.f;
            #pragma unroll 8
            for (int k = 0; k < 64; ++k) d += Qh[m][k] * Kh[tl][k];
            if (j >= 0 && j < WN) atomicAdd(&tnloc[tl - m + 31], wom * d);
        }
    }
    __syncthreads();
    if (tid < 63) {
        int j = t0 + tid - 31;
        if (j >= 0 && j < WN)
            atomicAdd(&logits[(size_t)(b*H + h)*WN + j], tnloc[tid]);
    }
}

// ---------------------------------------------------------------------------
// ka_proj_dot: tiled GEMM aux(32 x 256) @ WkaT_h(256 x 32) per head, fused
// normalize + dot(qa_hat) epilogue -> logits += wa * dot2.
// One block = (b, 32-row j-tile). K chunked 2x128 to stay under 64KB LDS.
__global__ __launch_bounds__(256) void ka_proj_dot(
    const float* __restrict__ aux, const float* __restrict__ wkat,
    const float* __restrict__ bka, const float* __restrict__ qahat,
    const float* __restrict__ wa, float* __restrict__ logits)
{
    int tile = blockIdx.x % 192;
    int b    = blockIdx.x / 192;
    int j0   = tile * 32;
    int tid  = threadIdx.x;

    __shared__ float As[32][260];     // 32 rows x 256 (pad 4: stride%32==4, conflict-free col reads)
    __shared__ float Bs[128][36];     // K-chunk x 32 cols (pad to 36 for aligned float4)

    {   // stage 32 aux rows (clamped at tail tile)
        int row = tid >> 3;
        int cb  = (tid & 7) * 32;
        int j = j0 + row; if (j > WN-1) j = WN-1;
        const float* ar = aux + ((size_t)b*S + (31 + j))*DA + cb;
        #pragma unroll
        for (int i = 0; i < 8; ++i)
            *(float4*)&As[row][cb + i*4] = *(const float4*)(ar + i*4);
    }

    int r  = tid >> 3;                // 0..31 (output row)
    int tx = tid & 7;                 // 0..7
    int c0 = tx * 4;                  // 4 channels per thread
    int j  = j0 + r;
    float wav = wa[0];

    for (int h = 0; h < H; ++h) {
        float acc0 = 0.f, acc1 = 0.f, acc2 = 0.f, acc3 = 0.f;
        const float* wsrc = wkat + (size_t)h*DA*DAh;
        for (int kc = 0; kc < 2; ++kc) {
            __syncthreads();
            {   // stage B chunk: rows kc*128..+127 of (256 x 32)
                int idx = tid * 4;
                #pragma unroll
                for (int i = 0; i < 4; ++i) {
                    int e = idx + i*1024;
                    int a = e >> 5, c = e & 31;
                    *(float4*)&Bs[a][c] = *(const float4*)(wsrc + (size_t)(kc*128 + a)*DAh + c);
                }
            }
            __syncthreads();
            int kbase = kc * 128;
            #pragma unroll 8
            for (int kk = 0; kk < 128; ++kk) {
                float a = As[r][kbase + kk];
                float4 b4 = *(const float4*)&Bs[kk][c0];
                acc0 += a*b4.x; acc1 += a*b4.y; acc2 += a*b4.z; acc3 += a*b4.w;
            }
        }
        // epilogue: bias, sumsq + dot across the 8-lane tx group
        const float* qa = qahat + (size_t)(b*H + h)*DAh + c0;
        float v0 = acc0 + bka[h*DAh + c0];
        float v1 = acc1 + bka[h*DAh + c0+1];
        float v2 = acc2 + bka[h*DAh + c0+2];
        float v3 = acc3 + bka[h*DAh + c0+3];
        float ss = v0*v0 + v1*v1 + v2*v2 + v3*v3;
        float dp = v0*qa[0] + v1*qa[1] + v2*qa[2] + v3*qa[3];
        #pragma unroll
        for (int d = 1; d <= 4; d <<= 1) {
            ss += __shfl_xor(ss, d);
            dp += __shfl_xor(dp, d);
        }
        if (tx == 0 && j < WN)
            logits[(size_t)(b*H + h)*WN + j] += wav * dp / fmaxf(sqrtf(ss), EPSN);
    }
}

// ---------------------------------------------------------------------------
// kp_proj_dot: pos(32 x 128) @ WkpT(128 x 16) for 4 heads at once, fused epilogue.
__global__ __launch_bounds__(256) void kp_proj_dot(
    const float* __restrict__ pos, const float* __restrict__ wkpt,
    const float* __restrict__ bkp, const float* __restrict__ qphat,
    const float* __restrict__ wp, float* __restrict__ logits)
{
    int tile = blockIdx.x % 192;
    int b    = blockIdx.x / 192;
    int j0   = tile * 32;
    int tid  = threadIdx.x;

    __shared__ float As[32][132];     // 32 rows x 128 (stride%32==4)
    __shared__ float Bs[128][68];     // 128 k x 64 cols (4 heads x 16 ch)

    {   // stage 32 pos rows
        int row = tid >> 3;
        int cb  = (tid & 7) * 16;
        int j = j0 + row; if (j > WN-1) j = WN-1;
        const float* pr = pos + ((size_t)b*S + (31 + j))*DP + cb;
        #pragma unroll
        for (int i = 0; i < 4; ++i)
            *(float4*)&As[row][cb + i*4] = *(const float4*)(pr + i*4);
    }

    int r  = tid >> 3;
    int tx = tid & 7;                 // 8 cols each: head hh = tx>>1, ch base (tx&1)*8
    int j  = j0 + r;
    float wpv = wp[0];

    for (int hg = 0; hg < 2; ++hg) {
        __syncthreads();
        {   // stage B: 4 heads' (128 x 16) -> Bs[k][hh*16 + c]
            int idx = tid * 4;
            #pragma unroll
            for (int i = 0; i < 8; ++i) {
                int e = idx + i*1024;
                int col = e & 63, p = e >> 6;
                int hh = col >> 4, c = col & 15;
                *(float4*)&Bs[p][col] =
                    *(const float4*)(wkpt + (size_t)(hg*4 + hh)*DP*DPh + (size_t)p*DPh + c);
            }
        }
        __syncthreads();
        float acc[8];
        #pragma unroll
        for (int i = 0; i < 8; ++i) acc[i] = 0.f;
        int cb = tx * 8;
        #pragma unroll 4
        for (int kk = 0; kk < 128; ++kk) {
            float a = As[r][kk];
            float4 b0 = *(const float4*)&Bs[kk][cb];
            float4 b1 = *(const float4*)&Bs[kk][cb + 4];
            acc[0] += a*b0.x; acc[1] += a*b0.y; acc[2] += a*b0.z; acc[3] += a*b0.w;
            acc[4] += a*b1.x; acc[5] += a*b1.y; acc[6] += a*b1.z; acc[7] += a*b1.w;
        }
        int hh = hg*4 + (tx >> 1);
        int ch0 = (tx & 1) * 8;
        const float* qp = qphat + (size_t)(b*H + hh)*DPh + ch0;
        const float* bb = bkp + hh*DPh + ch0;
        float ss = 0.f, dp = 0.f;
        #pragma unroll
        for (int i = 0; i < 8; ++i) {
            float v = acc[i] + bb[i];
            ss += v*v; dp += v*qp[i];
        }
        ss += __shfl_xor(ss, 1);
        dp += __shfl_xor(dp, 1);
        if ((tx & 1) == 0 && j < WN)
            logits[(size_t)(b*H + hh)*WN + j] += wpv * dp / fmaxf(sqrtf(ss), EPSN);
    }
}

// ---------------------------------------------------------------------------
// softmax over WN per (b,h); in-place logits -> attn; record attn[WN-1]
__global__ __launch_bounds__(256) void softmax_k(float* __restrict__ logits,
                                                 float* __restrict__ alast)
{
    int bh = blockIdx.x;
    float* L = logits + (size_t)bh*WN;
    __shared__ float red[256];
    int tid = threadIdx.x;
    float mx = -1e30f;
    for (int j = tid; j < WN; j += 256) mx = fmaxf(mx, L[j]);
    red[tid] = mx; __syncthreads();
    for (int s2 = 128; s2 > 0; s2 >>= 1) {
        if (tid < s2) red[tid] = fmaxf(red[tid], red[tid+s2]);
        __syncthreads();
    }
    mx = red[0]; __syncthreads();
    float sm = 0.f;
    for (int j = tid; j < WN; j += 256) sm += expf(L[j] - mx);
    red[tid] = sm; __syncthreads();
    for (int s2 = 128; s2 > 0; s2 >>= 1) {
        if (tid < s2) red[tid] += red[tid+s2];
        __syncthreads();
    }
    float inv = 1.f / red[0];
    for (int j = tid; j < WN; j += 256) {
        float a = expf(L[j] - mx) * inv;
        L[j] = a;
        if (j == WN-1) alast[bh] = a;
    }
}

// ---------------------------------------------------------------------------
// xbar[b,h,:] = sum_{j<WN-1} attn[b,h,j] * x[b, 31+j, :]
#define JC 191
__global__ __launch_bounds__(256) void xbar_k(
    const float* __restrict__ memory, const float* __restrict__ attn,
    float* __restrict__ xbar)
{
    int chunk = blockIdx.x & 31;
    int b = blockIdx.x >> 5;
    int j0 = chunk * JC;
    __shared__ float al[H][JC];
    int tid = threadIdx.x;
    for (int i = tid; i < H*JC; i += 256) {
        int hh = i / JC, jj = i - hh*JC;
        al[hh][jj] = attn[(size_t)(b*H + hh)*WN + j0 + jj];
    }
    __syncthreads();
    int d0 = tid * 2;
    float acc[H][2];
    #pragma unroll
    for (int hh = 0; hh < H; ++hh) { acc[hh][0] = 0.f; acc[hh][1] = 0.f; }
    for (int jj = 0; jj < JC; ++jj) {
        int t = 31 + j0 + jj;
        const float2 xv = *(const float2*)(memory + ((size_t)b*SM1 + t)*DM + d0);
        #pragma unroll
        for (int hh = 0; hh < H; ++hh) {
            float a = al[hh][jj];
            acc[hh][0] += a * xv.x;
            acc[hh][1] += a * xv.y;
        }
    }
    #pragma unroll
    for (int hh = 0; hh < H; ++hh) {
        atomicAdd(&xbar[(size_t)(b*H+hh)*DM + d0],     acc[hh][0]);
        atomicAdd(&xbar[(size_t)(b*H+hh)*DM + d0 + 1], acc[hh][1]);
    }
}

// ---------------------------------------------------------------------------
__global__ __launch_bounds__(192) void gi_k(
    const float* __restrict__ memory, const float* __restrict__ W_ih,
    const float* __restrict__ b_ih, float* __restrict__ gi_all)
{
    int t = blockIdx.x >> 3;
    int b = blockIdx.x & 7;
    int c = threadIdx.x;
    const float* xr = memory + ((size_t)b*SM1 + (S - M) + t)*DM;
    const float* wr = W_ih + (size_t)c*DM;
    float s = b_ih[c];
    for (int d = 0; d < DM; d += 4) {
        float4 x4 = *(const float4*)(xr + d);
        float4 w4 = *(const float4*)(wr + d);
        s += x4.x*w4.x + x4.y*w4.y + x4.z*w4.z + x4.w*w4.w;
    }
    gi_all[((size_t)t*BB + b)*192 + c] = s;
}

__global__ __launch_bounds__(512) void gru_scan(
    const float* __restrict__ gi_all, const float* __restrict__ W_hh,
    const float* __restrict__ b_hh, float* __restrict__ res)
{
    __shared__ float Wl[192*64];
    __shared__ float bl[192];
    __shared__ float hst[BB][DK];
    __shared__ float ghl[BB][192];
    int tid = threadIdx.x;
    for (int i = tid; i < 192*64; i += 512) Wl[i] = W_hh[i];
    if (tid < 192) bl[tid] = b_hh[tid];
    { int bb = tid >> 6, k = tid & 63; hst[bb][k] = 0.f; }
    __syncthreads();
    for (int t = 0; t < 31; ++t) {
        #pragma unroll
        for (int i = 0; i < 3; ++i) {
            int idx = tid + i*512;
            int bb = idx / 192, c = idx - bb*192;
            float s = bl[c];
            #pragma unroll 8
            for (int k2 = 0; k2 < 64; ++k2) s += hst[bb][k2] * Wl[c*64 + k2];
            ghl[bb][c] = s;
        }
        __syncthreads();
        int bb = tid >> 6, k = tid & 63;
        const float* gi = gi_all + ((size_t)t*BB + bb)*192;
        float ir = gi[k], iz = gi[64+k], in = gi[128+k];
        float hr = ghl[bb][k], hz = ghl[bb][64+k], hn = ghl[bb][128+k];
        float r = 1.f/(1.f + expf(-(ir + hr)));
        float z = 1.f/(1.f + expf(-(iz + hz)));
        float n = tanhf(in + r*hn);
        float hnew = (1.f - z)*n + z*hst[bb][k];
        hst[bb][k] = hnew;
        __syncthreads();
    }
    int bb = tid >> 6, k = tid & 63;
    res[bb*DK + k] = hst[bb][k];
}

// ---------------------------------------------------------------------------
__global__ __launch_bounds__(512) void final_k(
    const float* __restrict__ x_pre, const float* __restrict__ xbar,
    const float* __restrict__ Wv, const float* __restrict__ bv,
    const float* __restrict__ WO, const float* __restrict__ bO,
    const float* __restrict__ alast, const float* __restrict__ res,
    const int* __restrict__ G, float* __restrict__ out)
{
    int b = blockIdx.x;
    int tid = threadIdx.x;
    __shared__ float gl[64*64];
    __shared__ float deta[512];
    for (int i = tid; i < 4096; i += 512) gl[i] = (float)G[(i & 63)*64 + (i >> 6)];
    __syncthreads();
    int h = tid >> 6, dk = tid & 63;
    float ala = alast[b*H + h];
    const float* xb  = xbar + (size_t)(b*H + h)*DM;
    const float* wvr = Wv + (size_t)tid*DM;
    const float* gcol = gl + dk;
    float s = 0.f;
    for (int e = 0; e < DM; e += 4) {
        float4 wv4 = *(const float4*)(wvr + e);
        float4 xb4 = *(const float4*)(xb + e);
        int eb = e & 63;
        s += wv4.x*gcol[eb*64]     *xb4.x + wv4.y*gcol[(eb+1)*64]*xb4.y
           + wv4.z*gcol[(eb+2)*64]*xb4.z + wv4.w*gcol[(eb+3)*64]*xb4.w;
    }
    float hist = s + bv[tid]*(1.f - ala);
    deta[tid] = hist + ala * res[b*DK + dk];
    __syncthreads();
    int dpos = tid;
    const float* wor = WO + (size_t)dpos*DM;
    const float* gcol2 = gl + (dpos & 63);
    float o = 0.f;
    for (int jj = 0; jj < DM; jj += 4) {
        float4 wo4 = *(const float4*)(wor + jj);
        int jb = jj & 63;
        o += wo4.x*gcol2[jb*64]     *deta[jj]   + wo4.y*gcol2[(jb+1)*64]*deta[jj+1]
           + wo4.z*gcol2[(jb+2)*64]*deta[jj+2] + wo4.w*gcol2[(jb+3)*64]*deta[jj+3];
    }
    out[(size_t)b*DM + dpos] = x_pre[(size_t)b*DM + dpos] + o + bO[dpos];
}

// ---------------------------------------------------------------------------
extern "C" void kernel_launch(void* const* d_in, const int* in_sizes, int n_in,
                              void* d_out, int out_size, void* d_ws, size_t ws_size,
                              hipStream_t stream)
{
    const float* memory = (const float*)d_in[0];
    const float* x_pre  = (const float*)d_in[1];
    const float* aux    = (const float*)d_in[2];
    const float* pos    = (const float*)d_in[3];
    const float* Wq  = (const float*)d_in[4];
    const float* bq  = (const float*)d_in[5];
    const float* Wk  = (const float*)d_in[6];
    const float* bk  = (const float*)d_in[7];
    const float* Wv  = (const float*)d_in[8];
    const float* bv  = (const float*)d_in[9];
    const float* Wqa = (const float*)d_in[10];
    const float* bqa = (const float*)d_in[11];
    const float* Wka = (const float*)d_in[12];
    const float* bka = (const float*)d_in[13];
    const float* Wqp = (const float*)d_in[14];
    const float* bqp = (const float*)d_in[15];
    const float* Wkp = (const float*)d_in[16];
    const float* bkp = (const float*)d_in[17];
    const float* W_ih = (const float*)d_in[18];
    const float* W_hh = (const float*)d_in[19];
    const float* b_ih = (const float*)d_in[20];
    const float* b_hh = (const float*)d_in[21];
    const float* WO  = (const float*)d_in[22];
    const float* bO  = (const float*)d_in[23];
    const float* w   = (const float*)d_in[24];
    const float* w_a = (const float*)d_in[25];
    const float* w_p = (const float*)d_in[26];
    const int*   G   = (const int*)d_in[27];
    (void)in_sizes; (void)n_in; (void)out_size; (void)ws_size;

    float* ws = (float*)d_ws;
    float* wkt    = ws + WS_WKT;
    float* wkat   = ws + WS_WKAT;
    float* wkpt   = ws + WS_WKPT;
    float* qhat   = ws + WS_QHAT;
    float* qahat  = ws + WS_QAHAT;
    float* qphat  = ws + WS_QPHAT;
    float* logits = ws + WS_LOGITS;
    float* xbar   = ws + WS_XBAR;
    float* alast  = ws + WS_ALAST;
    float* resb   = ws + WS_RES;
    float* gi_all = ws + WS_GI;
    float* wqm    = ws + WS_WQM;
    float* outp   = (float*)d_out;

    hipMemsetAsync(logits, 0, (size_t)(N_LOGITS + N_XBAR)*sizeof(float), stream);

    prep_weights<<<(2*H*DM*DK + H*DA*DAh + H*DP*DPh + 255)/256, 256, 0, stream>>>(
        Wk, Wka, Wkp, Wq, G, wkt, wkat, wkpt, wqm);

    qhat_k<<<BB*H, 256, 0, stream>>>(memory, x_pre, aux, pos, wqm, bq, Wqa, bqa,
                                     Wqp, bqp, qhat, qahat, qphat);

    kproj_band<<<BB*H*(S/TILE_T), 256, 0, stream>>>(memory, x_pre, wkt, bk, qhat,
                                                    w, logits);

    ka_proj_dot<<<BB*192, 256, 0, stream>>>(aux, wkat, bka, qahat, w_a, logits);
    kp_proj_dot<<<BB*192, 256, 0, stream>>>(pos, wkpt, bkp, qphat, w_p, logits);

    softmax_k<<<BB*H, 256, 0, stream>>>(logits, alast);

    xbar_k<<<BB*32, 256, 0, stream>>>(memory, logits, xbar);

    gi_k<<<31*BB, 192, 0, stream>>>(memory, W_ih, b_ih, gi_all);
    gru_scan<<<1, 512, 0, stream>>>(gi_all, W_hh, b_hh, resb);

    final_k<<<BB, 512, 0, stream>>>(x_pre, xbar, Wv, bv, WO, bO, alast, resb, G, outp);
}

// Round 3
// 1229.620 us; speedup vs baseline: 2.2617x; 1.3212x over previous
//
#include <hip/hip_runtime.h>
#include <math.h>

// ---- problem constants (fixed by setup_inputs) ----
#define BB   8
#define S    6144
#define SM1  6143          // memory rows; x[:,SM1,:] == x_pre
#define DM   512
#define H    8
#define DK   64
#define M    32
#define WN   6113          // k + T - M + 1 = 2048+4096-32+1
#define DA   256
#define DAh  32
#define DP   128
#define DPh  16
#define EPSN 1e-12f

// ---- workspace layout (float offsets) ----
#define WS_WKT    0                       // reused: H*DM*DK bf16 packed Wk (131072 floats worth)
#define WS_WKAT   262144                  // H*DA*DAh  = 65536   WkaT [h][a][c]
#define WS_WKPT   327680                  // H*DP*DPh  = 16384   WkpT [h][p][c]
#define WS_QHAT   344064                  // B*H*M*DK  = 131072
#define WS_QAHAT  475136                  // B*H*DAh   = 2048
#define WS_QPHAT  477184                  // B*H*DPh   = 1024
#define WS_LOGITS 478208                  // B*H*WN    = 391232  (becomes attn in-place)
#define WS_XBAR   869440                  // B*H*DM    = 32768   (contiguous after logits)
#define WS_ALAST  902208                  // B*H       = 64
#define WS_RES    902272                  // B*DK      = 512
#define WS_GI     902784                  // 31*B*192  = 47616
#define WS_WQM    950400                  // H*DK*DM   = 262144  masked Wq [h][k][d]
#define N_LOGITS  391232
#define N_XBAR    32768

typedef __attribute__((ext_vector_type(8))) short short8;
typedef __attribute__((ext_vector_type(4))) float f32x4;

__device__ inline unsigned short f2bf(float f) {
    union { float f; unsigned u; } v; v.f = f;
    unsigned r = v.u + 0x7fffu + ((v.u >> 16) & 1u);   // RNE
    return (unsigned short)(r >> 16);
}

// ---------------------------------------------------------------------------
// prep: masked Wk -> packed bf16 wkb [h][(d>>3)*64+k][d&7] (MFMA B-frag order);
//       Wka -> wkat[h][a][c]; Wkp -> wkpt[h][p][c]; masked Wq -> wqm
__global__ void prep_weights(const float* __restrict__ Wk, const float* __restrict__ Wka,
                             const float* __restrict__ Wkp, const float* __restrict__ Wq,
                             const int* __restrict__ G,
                             unsigned short* __restrict__ wkb, float* __restrict__ wkat,
                             float* __restrict__ wkpt, float* __restrict__ wqm)
{
    int idx = blockIdx.x * 256 + threadIdx.x;
    if (idx < H*DM*DK) {
        int k = idx & 63; int d = (idx >> 6) & 511; int h = idx >> 15;
        float v = Wk[(size_t)(h*DK + k)*DM + d] * (float)G[k*DK + (d & 63)];
        wkb[(size_t)h*DM*DK + (((d >> 3)*DK + k) << 3) + (d & 7)] = f2bf(v);
    }
    int i2 = idx - H*DM*DK;
    if (i2 >= 0 && i2 < H*DA*DAh) {
        int c = i2 & 31; int a = (i2 >> 5) & 255; int h = i2 >> 13;
        wkat[i2] = Wka[(size_t)(h*DAh + c)*DA + a];
    }
    int i3 = idx - H*DM*DK - H*DA*DAh;
    if (i3 >= 0 && i3 < H*DP*DPh) {
        int c = i3 & 15; int p = (i3 >> 4) & 127; int h = i3 >> 11;
        wkpt[i3] = Wkp[(size_t)(h*DPh + c)*DP + p];
    }
    int i4 = idx - H*DM*DK - H*DA*DAh - H*DP*DPh;
    if (i4 >= 0 && i4 < H*DK*DM) {
        int d = i4 & 511; int k = (i4 >> 9) & 63;
        wqm[i4] = Wq[i4] * (float)G[k*DK + (d & 63)];
    }
}

// ---------------------------------------------------------------------------
// qhat: normalized Q rows for last M positions, plus qa_hat/qp_hat at last row.
__global__ __launch_bounds__(256) void qhat_k(
    const float* __restrict__ memory, const float* __restrict__ x_pre,
    const float* __restrict__ aux, const float* __restrict__ pos,
    const float* __restrict__ wqm, const float* __restrict__ bq,
    const float* __restrict__ Wqa, const float* __restrict__ bqa,
    const float* __restrict__ Wqp, const float* __restrict__ bqp,
    float* __restrict__ qhat, float* __restrict__ qahat, float* __restrict__ qphat)
{
    int bh = blockIdx.x; int b = bh >> 3, h = bh & 7;
    int tid = threadIdx.x;
    __shared__ float q[M][DK];
    __shared__ float nrm[M];
    __shared__ float qa[DAh];
    __shared__ float qp[DPh];

    int k = tid & 63;
    int mg = tid >> 6;                    // 0..3
    const float* wr = wqm + (size_t)(h*DK + k)*DM;
    for (int mp = 0; mp < 8; ++mp) {
        int m = mp*4 + mg;
        int t = S - M + m;                // 6112..6143
        const float* xr = (t < SM1) ? (memory + ((size_t)b*SM1 + t)*DM)
                                    : (x_pre + (size_t)b*DM);
        float s = 0.f;
        for (int d = 0; d < DM; d += 4) {
            float4 x4 = *(const float4*)(xr + d);
            float4 w4 = *(const float4*)(wr + d);
            s += x4.x*w4.x + x4.y*w4.y + x4.z*w4.z + x4.w*w4.w;
        }
        q[m][k] = s + bq[h*DK + k];
    }
    if (tid < DAh) {
        int c = tid;
        const float* ar = aux + ((size_t)b*S + (S-1))*DA;
        const float* wv = Wqa + (size_t)(h*DAh + c)*DA;
        float s = 0.f;
        for (int a = 0; a < DA; ++a) s += ar[a]*wv[a];
        qa[c] = s + bqa[h*DAh + c];
    }
    if (tid >= 64 && tid < 64 + DPh) {
        int c = tid - 64;
        const float* pr = pos + ((size_t)b*S + (S-1))*DP;
        const float* wv = Wqp + (size_t)(h*DPh + c)*DP;
        float s = 0.f;
        for (int p2 = 0; p2 < DP; ++p2) s += pr[p2]*wv[p2];
        qp[c] = s + bqp[h*DPh + c];
    }
    __syncthreads();
    if (tid < M) {
        float s = 0.f;
        for (int kk = 0; kk < DK; ++kk) { float v = q[tid][kk]; s += v*v; }
        nrm[tid] = fmaxf(sqrtf(s), EPSN);
    }
    __syncthreads();
    for (int i = tid; i < M*DK; i += 256) {
        int m = i >> 6, kk = i & 63;
        qhat[(size_t)bh*M*DK + i] = q[m][kk] / nrm[m];
    }
    if (tid < DAh) {
        float s = 0.f;
        for (int c = 0; c < DAh; ++c) s += qa[c]*qa[c];
        qahat[(size_t)bh*DAh + tid] = qa[tid] / fmaxf(sqrtf(s), EPSN);
    }
    if (tid < DPh) {
        float s = 0.f;
        for (int c = 0; c < DPh; ++c) s += qp[c]*qp[c];
        qphat[(size_t)bh*DPh + tid] = qp[tid] / fmaxf(sqrtf(s), EPSN);
    }
}

// ---------------------------------------------------------------------------
// MFMA K-projection (masked, biased, l2-normalized) fused with banded Q.K.
// One block = (b, h, 64-row t-tile). bf16 MFMA 16x16x32, fp32 accumulate.
#define KT 64
__global__ __launch_bounds__(256) void kproj_band_mfma(
    const float* __restrict__ memory, const float* __restrict__ x_pre,
    const unsigned short* __restrict__ wkb, const float* __restrict__ bk,
    const float* __restrict__ qhat, const float* __restrict__ wscal,
    float* __restrict__ logits)
{
    int tile = blockIdx.x % (S / KT);                // 96
    int h = (blockIdx.x / (S / KT)) % H;
    int b = blockIdx.x / ((S / KT) * H);
    int t0 = tile * KT;
    int tid = threadIdx.x;
    int wave = tid >> 6, lane = tid & 63;
    int quad = lane >> 4, l16 = lane & 15;

    __shared__ unsigned short Xs[KT][136];           // 64 x 128 bf16 (+8 pad)
    __shared__ unsigned short Wls[16*DK*8];          // packed W chunk (128 d x 64 k)
    __shared__ unsigned short Qs[M][72];             // Qhat bf16 32 x 64 (+8 pad)
    __shared__ unsigned short Kb[KT][72];            // normalized K bf16
    __shared__ float tnloc[KT + 31];                 // 95 diagonals

    {   // stage qhat -> bf16 Qs
        const float* qsrc = qhat + (size_t)(b*H + h)*M*DK;
        int i = tid * 8;                             // 2048 elems / 256 thr
        float4 a0 = *(const float4*)(qsrc + i);
        float4 a1 = *(const float4*)(qsrc + i + 4);
        int m = i >> 6, kk = i & 63;
        unsigned short* dst = &Qs[m][kk];
        dst[0]=f2bf(a0.x); dst[1]=f2bf(a0.y); dst[2]=f2bf(a0.z); dst[3]=f2bf(a0.w);
        dst[4]=f2bf(a1.x); dst[5]=f2bf(a1.y); dst[6]=f2bf(a1.z); dst[7]=f2bf(a1.w);
    }
    if (tid < KT + 31) tnloc[tid] = 0.f;

    f32x4 acc[4];
    #pragma unroll
    for (int nt = 0; nt < 4; ++nt) acc[nt] = (f32x4){0.f,0.f,0.f,0.f};

    int r0 = wave * 16;                              // this wave's 16 t-rows
    const unsigned short* wk_h = wkb + (size_t)h * DM * DK;

    for (int ch = 0; ch < 4; ++ch) {                 // d-chunks of 128
        __syncthreads();
        {   // stage Xs: 64 rows x 128 floats -> bf16
            int row = tid >> 2;
            int dseg = (tid & 3) * 32;
            int t = t0 + row;
            const float* xr = ((t < SM1) ? (memory + ((size_t)b*SM1 + t)*DM)
                                         : (x_pre + (size_t)b*DM)) + ch*128 + dseg;
            unsigned short* dst = &Xs[row][dseg];
            #pragma unroll
            for (int i = 0; i < 8; ++i) {
                float4 v = *(const float4*)(xr + i*4);
                dst[i*4+0]=f2bf(v.x); dst[i*4+1]=f2bf(v.y);
                dst[i*4+2]=f2bf(v.z); dst[i*4+3]=f2bf(v.w);
            }
        }
        {   // stage Wls: straight copy of 8192 shorts (pre-packed B-frag order)
            const short8* src = (const short8*)(wk_h + (size_t)ch*128*DK);
            short8* dst = (short8*)Wls;
            #pragma unroll
            for (int i = 0; i < 4; ++i) dst[tid + 256*i] = src[tid + 256*i];
        }
        __syncthreads();
        #pragma unroll
        for (int ks = 0; ks < 4; ++ks) {             // k32-steps within chunk
            short8 a = *(const short8*)&Xs[r0 + l16][ks*32 + quad*8];
            #pragma unroll
            for (int nt = 0; nt < 4; ++nt) {
                short8 bf = *(const short8*)&Wls[(((ks*4 + quad)*DK) + nt*16 + l16)*8];
                acc[nt] = __builtin_amdgcn_mfma_f32_16x16x32_bf16(a, bf, acc[nt], 0, 0, 0);
            }
        }
    }

    // bias + row l2-norm (butterfly over the 16 lanes sharing a quad) + bf16 store
    {
        float vv[4][4];
        float ss[4] = {0.f, 0.f, 0.f, 0.f};
        #pragma unroll
        for (int nt = 0; nt < 4; ++nt) {
            float bkv = bk[h*DK + nt*16 + l16];
            #pragma unroll
            for (int reg = 0; reg < 4; ++reg) {
                float v = acc[nt][reg] + bkv;
                vv[nt][reg] = v;
                ss[reg] += v*v;
            }
        }
        #pragma unroll
        for (int d2 = 1; d2 <= 8; d2 <<= 1) {
            #pragma unroll
            for (int reg = 0; reg < 4; ++reg) ss[reg] += __shfl_xor(ss[reg], d2);
        }
        float inv[4];
        #pragma unroll
        for (int reg = 0; reg < 4; ++reg)
            inv[reg] = 1.f / fmaxf(sqrtf(ss[reg]), EPSN);
        #pragma unroll
        for (int nt = 0; nt < 4; ++nt)
            #pragma unroll
            for (int reg = 0; reg < 4; ++reg)
                Kb[r0 + quad*4 + reg][nt*16 + l16] = f2bf(vv[nt][reg] * inv[reg]);
    }
    __syncthreads();

    // banded Q.K^T: 32 m-rows x 64 t-cols via MFMA; scatter per-diagonal
    {
        int mtile = wave & 1;                        // 16 m-rows
        int thalf = (wave >> 1) * 32;                // 32 t-cols
        f32x4 acc2[2];
        acc2[0] = (f32x4){0.f,0.f,0.f,0.f};
        acc2[1] = (f32x4){0.f,0.f,0.f,0.f};
        #pragma unroll
        for (int ks = 0; ks < 2; ++ks) {
            short8 a = *(const short8*)&Qs[mtile*16 + l16][ks*32 + quad*8];
            #pragma unroll
            for (int nt = 0; nt < 2; ++nt) {
                short8 bf = *(const short8*)&Kb[thalf + nt*16 + l16][ks*32 + quad*8];
                acc2[nt] = __builtin_amdgcn_mfma_f32_16x16x32_bf16(a, bf, acc2[nt], 0, 0, 0);
            }
        }
        int m = mtile*16 + quad*4;
        #pragma unroll
        for (int nt = 0; nt < 2; ++nt) {
            int tl = thalf + nt*16 + l16;
            #pragma unroll
            for (int reg = 0; reg < 4; ++reg) {
                int mm = m + reg;
                int j = t0 + tl - mm;
                if (j >= 0 && j < WN)
                    atomicAdd(&tnloc[tl - mm + 31], acc2[nt][reg]);
            }
        }
    }
    __syncthreads();
    if (tid < KT + 31) {
        int j = t0 + tid - 31;
        if (j >= 0 && j < WN)
            atomicAdd(&logits[(size_t)(b*H + h)*WN + j], wscal[0]*(1.f/32.f)*tnloc[tid]);
    }
}

// ---------------------------------------------------------------------------
// ka_proj_dot: tiled GEMM aux(32 x 256) @ WkaT_h(256 x 32) per head, fused
// normalize + dot(qa_hat) epilogue -> logits += wa * dot2.
__global__ __launch_bounds__(256) void ka_proj_dot(
    const float* __restrict__ aux, const float* __restrict__ wkat,
    const float* __restrict__ bka, const float* __restrict__ qahat,
    const float* __restrict__ wa, float* __restrict__ logits)
{
    int tile = blockIdx.x % 192;
    int b    = blockIdx.x / 192;
    int j0   = tile * 32;
    int tid  = threadIdx.x;

    __shared__ float As[32][260];
    __shared__ float Bs[128][36];

    {
        int row = tid >> 3;
        int cb  = (tid & 7) * 32;
        int j = j0 + row; if (j > WN-1) j = WN-1;
        const float* ar = aux + ((size_t)b*S + (31 + j))*DA + cb;
        #pragma unroll
        for (int i = 0; i < 8; ++i)
            *(float4*)&As[row][cb + i*4] = *(const float4*)(ar + i*4);
    }

    int r  = tid >> 3;
    int tx = tid & 7;
    int c0 = tx * 4;
    int j  = j0 + r;
    float wav = wa[0];

    for (int h = 0; h < H; ++h) {
        float acc0 = 0.f, acc1 = 0.f, acc2 = 0.f, acc3 = 0.f;
        const float* wsrc = wkat + (size_t)h*DA*DAh;
        for (int kc = 0; kc < 2; ++kc) {
            __syncthreads();
            {
                int idx = tid * 4;
                #pragma unroll
                for (int i = 0; i < 4; ++i) {
                    int e = idx + i*1024;
                    int a = e >> 5, c = e & 31;
                    *(float4*)&Bs[a][c] = *(const float4*)(wsrc + (size_t)(kc*128 + a)*DAh + c);
                }
            }
            __syncthreads();
            int kbase = kc * 128;
            #pragma unroll 8
            for (int kk = 0; kk < 128; ++kk) {
                float a = As[r][kbase + kk];
                float4 b4 = *(const float4*)&Bs[kk][c0];
                acc0 += a*b4.x; acc1 += a*b4.y; acc2 += a*b4.z; acc3 += a*b4.w;
            }
        }
        const float* qa = qahat + (size_t)(b*H + h)*DAh + c0;
        float v0 = acc0 + bka[h*DAh + c0];
        float v1 = acc1 + bka[h*DAh + c0+1];
        float v2 = acc2 + bka[h*DAh + c0+2];
        float v3 = acc3 + bka[h*DAh + c0+3];
        float ss = v0*v0 + v1*v1 + v2*v2 + v3*v3;
        float dp = v0*qa[0] + v1*qa[1] + v2*qa[2] + v3*qa[3];
        #pragma unroll
        for (int d = 1; d <= 4; d <<= 1) {
            ss += __shfl_xor(ss, d);
            dp += __shfl_xor(dp, d);
        }
        if (tx == 0 && j < WN)
            logits[(size_t)(b*H + h)*WN + j] += wav * dp / fmaxf(sqrtf(ss), EPSN);
    }
}

// ---------------------------------------------------------------------------
// kp_proj_dot: pos(32 x 128) @ WkpT(128 x 16) for 4 heads at once, fused epilogue.
__global__ __launch_bounds__(256) void kp_proj_dot(
    const float* __restrict__ pos, const float* __restrict__ wkpt,
    const float* __restrict__ bkp, const float* __restrict__ qphat,
    const float* __restrict__ wp, float* __restrict__ logits)
{
    int tile = blockIdx.x % 192;
    int b    = blockIdx.x / 192;
    int j0   = tile * 32;
    int tid  = threadIdx.x;

    __shared__ float As[32][132];
    __shared__ float Bs[128][68];

    {
        int row = tid >> 3;
        int cb  = (tid & 7) * 16;
        int j = j0 + row; if (j > WN-1) j = WN-1;
        const float* pr = pos + ((size_t)b*S + (31 + j))*DP + cb;
        #pragma unroll
        for (int i = 0; i < 4; ++i)
            *(float4*)&As[row][cb + i*4] = *(const float4*)(pr + i*4);
    }

    int r  = tid >> 3;
    int tx = tid & 7;
    int j  = j0 + r;
    float wpv = wp[0];

    for (int hg = 0; hg < 2; ++hg) {
        __syncthreads();
        {
            int idx = tid * 4;
            #pragma unroll
            for (int i = 0; i < 8; ++i) {
                int e = idx + i*1024;
                int col = e & 63, p = e >> 6;
                int hh = col >> 4, c = col & 15;
                *(float4*)&Bs[p][col] =
                    *(const float4*)(wkpt + (size_t)(hg*4 + hh)*DP*DPh + (size_t)p*DPh + c);
            }
        }
        __syncthreads();
        float acc[8];
        #pragma unroll
        for (int i = 0; i < 8; ++i) acc[i] = 0.f;
        int cb = tx * 8;
        #pragma unroll 4
        for (int kk = 0; kk < 128; ++kk) {
            float a = As[r][kk];
            float4 b0 = *(const float4*)&Bs[kk][cb];
            float4 b1 = *(const float4*)&Bs[kk][cb + 4];
            acc[0] += a*b0.x; acc[1] += a*b0.y; acc[2] += a*b0.z; acc[3] += a*b0.w;
            acc[4] += a*b1.x; acc[5] += a*b1.y; acc[6] += a*b1.z; acc[7] += a*b1.w;
        }
        int hh = hg*4 + (tx >> 1);
        int ch0 = (tx & 1) * 8;
        const float* qp = qphat + (size_t)(b*H + hh)*DPh + ch0;
        const float* bb = bkp + hh*DPh + ch0;
        float ss = 0.f, dp = 0.f;
        #pragma unroll
        for (int i = 0; i < 8; ++i) {
            float v = acc[i] + bb[i];
            ss += v*v; dp += v*qp[i];
        }
        ss += __shfl_xor(ss, 1);
        dp += __shfl_xor(dp, 1);
        if ((tx & 1) == 0 && j < WN)
            logits[(size_t)(b*H + hh)*WN + j] += wpv * dp / fmaxf(sqrtf(ss), EPSN);
    }
}

// ---------------------------------------------------------------------------
// softmax over WN per (b,h); in-place logits -> attn; record attn[WN-1]
__global__ __launch_bounds__(256) void softmax_k(float* __restrict__ logits,
                                                 float* __restrict__ alast)
{
    int bh = blockIdx.x;
    float* L = logits + (size_t)bh*WN;
    __shared__ float red[256];
    int tid = threadIdx.x;
    float mx = -1e30f;
    for (int j = tid; j < WN; j += 256) mx = fmaxf(mx, L[j]);
    red[tid] = mx; __syncthreads();
    for (int s2 = 128; s2 > 0; s2 >>= 1) {
        if (tid < s2) red[tid] = fmaxf(red[tid], red[tid+s2]);
        __syncthreads();
    }
    mx = red[0]; __syncthreads();
    float sm = 0.f;
    for (int j = tid; j < WN; j += 256) sm += expf(L[j] - mx);
    red[tid] = sm; __syncthreads();
    for (int s2 = 128; s2 > 0; s2 >>= 1) {
        if (tid < s2) red[tid] += red[tid+s2];
        __syncthreads();
    }
    float inv = 1.f / red[0];
    for (int j = tid; j < WN; j += 256) {
        float a = expf(L[j] - mx) * inv;
        L[j] = a;
        if (j == WN-1) alast[bh] = a;
    }
}

// ---------------------------------------------------------------------------
// xbar[b,h,:] = sum_{j<WN-1} attn[b,h,j] * x[b, 31+j, :]
#define JC 191
__global__ __launch_bounds__(256) void xbar_k(
    const float* __restrict__ memory, const float* __restrict__ attn,
    float* __restrict__ xbar)
{
    int chunk = blockIdx.x & 31;
    int b = blockIdx.x >> 5;
    int j0 = chunk * JC;
    __shared__ float al[H][JC];
    int tid = threadIdx.x;
    for (int i = tid; i < H*JC; i += 256) {
        int hh = i / JC, jj = i - hh*JC;
        al[hh][jj] = attn[(size_t)(b*H + hh)*WN + j0 + jj];
    }
    __syncthreads();
    int d0 = tid * 2;
    float acc[H][2];
    #pragma unroll
    for (int hh = 0; hh < H; ++hh) { acc[hh][0] = 0.f; acc[hh][1] = 0.f; }
    for (int jj = 0; jj < JC; ++jj) {
        int t = 31 + j0 + jj;
        const float2 xv = *(const float2*)(memory + ((size_t)b*SM1 + t)*DM + d0);
        #pragma unroll
        for (int hh = 0; hh < H; ++hh) {
            float a = al[hh][jj];
            acc[hh][0] += a * xv.x;
            acc[hh][1] += a * xv.y;
        }
    }
    #pragma unroll
    for (int hh = 0; hh < H; ++hh) {
        atomicAdd(&xbar[(size_t)(b*H+hh)*DM + d0],     acc[hh][0]);
        atomicAdd(&xbar[(size_t)(b*H+hh)*DM + d0 + 1], acc[hh][1]);
    }
}

// ---------------------------------------------------------------------------
__global__ __launch_bounds__(192) void gi_k(
    const float* __restrict__ memory, const float* __restrict__ W_ih,
    const float* __restrict__ b_ih, float* __restrict__ gi_all)
{
    int t = blockIdx.x >> 3;
    int b = blockIdx.x & 7;
    int c = threadIdx.x;
    const float* xr = memory + ((size_t)b*SM1 + (S - M) + t)*DM;
    const float* wr = W_ih + (size_t)c*DM;
    float s = b_ih[c];
    for (int d = 0; d < DM; d += 4) {
        float4 x4 = *(const float4*)(xr + d);
        float4 w4 = *(const float4*)(wr + d);
        s += x4.x*w4.x + x4.y*w4.y + x4.z*w4.z + x4.w*w4.w;
    }
    gi_all[((size_t)t*BB + b)*192 + c] = s;
}

__global__ __launch_bounds__(512) void gru_scan(
    const float* __restrict__ gi_all, const float* __restrict__ W_hh,
    const float* __restrict__ b_hh, float* __restrict__ res)
{
    __shared__ float Wl[192*64];
    __shared__ float bl[192];
    __shared__ float hst[BB][DK];
    __shared__ float ghl[BB][192];
    int tid = threadIdx.x;
    for (int i = tid; i < 192*64; i += 512) Wl[i] = W_hh[i];
    if (tid < 192) bl[tid] = b_hh[tid];
    { int bb = tid >> 6, k = tid & 63; hst[bb][k] = 0.f; }
    __syncthreads();
    for (int t = 0; t < 31; ++t) {
        #pragma unroll
        for (int i = 0; i < 3; ++i) {
            int idx = tid + i*512;
            int bb = idx / 192, c = idx - bb*192;
            float s = bl[c];
            #pragma unroll 8
            for (int k2 = 0; k2 < 64; ++k2) s += hst[bb][k2] * Wl[c*64 + k2];
            ghl[bb][c] = s;
        }
        __syncthreads();
        int bb = tid >> 6, k = tid & 63;
        const float* gi = gi_all + ((size_t)t*BB + bb)*192;
        float ir = gi[k], iz = gi[64+k], in = gi[128+k];
        float hr = ghl[bb][k], hz = ghl[bb][64+k], hn = ghl[bb][128+k];
        float r = 1.f/(1.f + expf(-(ir + hr)));
        float z = 1.f/(1.f + expf(-(iz + hz)));
        float n = tanhf(in + r*hn);
        float hnew = (1.f - z)*n + z*hst[bb][k];
        hst[bb][k] = hnew;
        __syncthreads();
    }
    int bb = tid >> 6, k = tid & 63;
    res[bb*DK + k] = hst[bb][k];
}

// ---------------------------------------------------------------------------
__global__ __launch_bounds__(512) void final_k(
    const float* __restrict__ x_pre, const float* __restrict__ xbar,
    const float* __restrict__ Wv, const float* __restrict__ bv,
    const float* __restrict__ WO, const float* __restrict__ bO,
    const float* __restrict__ alast, const float* __restrict__ res,
    const int* __restrict__ G, float* __restrict__ out)
{
    int b = blockIdx.x;
    int tid = threadIdx.x;
    __shared__ float gl[64*64];
    __shared__ float deta[512];
    for (int i = tid; i < 4096; i += 512) gl[i] = (float)G[(i & 63)*64 + (i >> 6)];
    __syncthreads();
    int h = tid >> 6, dk = tid & 63;
    float ala = alast[b*H + h];
    const float* xb  = xbar + (size_t)(b*H + h)*DM;
    const float* wvr = Wv + (size_t)tid*DM;
    const float* gcol = gl + dk;
    float s = 0.f;
    for (int e = 0; e < DM; e += 4) {
        float4 wv4 = *(const float4*)(wvr + e);
        float4 xb4 = *(const float4*)(xb + e);
        int eb = e & 63;
        s += wv4.x*gcol[eb*64]     *xb4.x + wv4.y*gcol[(eb+1)*64]*xb4.y
           + wv4.z*gcol[(eb+2)*64]*xb4.z + wv4.w*gcol[(eb+3)*64]*xb4.w;
    }
    float hist = s + bv[tid]*(1.f - ala);
    deta[tid] = hist + ala * res[b*DK + dk];
    __syncthreads();
    int dpos = tid;
    const float* wor = WO + (size_t)dpos*DM;
    const float* gcol2 = gl + (dpos & 63);
    float o = 0.f;
    for (int jj = 0; jj < DM; jj += 4) {
        float4 wo4 = *(const float4*)(wor + jj);
        int jb = jj & 63;
        o += wo4.x*gcol2[jb*64]     *deta[jj]   + wo4.y*gcol2[(jb+1)*64]*deta[jj+1]
           + wo4.z*gcol2[(jb+2)*64]*deta[jj+2] + wo4.w*gcol2[(jb+3)*64]*deta[jj+3];
    }
    out[(size_t)b*DM + dpos] = x_pre[(size_t)b*DM + dpos] + o + bO[dpos];
}

// ---------------------------------------------------------------------------
extern "C" void kernel_launch(void* const* d_in, const int* in_sizes, int n_in,
                              void* d_out, int out_size, void* d_ws, size_t ws_size,
                              hipStream_t stream)
{
    const float* memory = (const float*)d_in[0];
    const float* x_pre  = (const float*)d_in[1];
    const float* aux    = (const float*)d_in[2];
    const float* pos    = (const float*)d_in[3];
    const float* Wq  = (const float*)d_in[4];
    const float* bq  = (const float*)d_in[5];
    const float* Wk  = (const float*)d_in[6];
    const float* bk  = (const float*)d_in[7];
    const float* Wv  = (const float*)d_in[8];
    const float* bv  = (const float*)d_in[9];
    const float* Wqa = (const float*)d_in[10];
    const float* bqa = (const float*)d_in[11];
    const float* Wka = (const float*)d_in[12];
    const float* bka = (const float*)d_in[13];
    const float* Wqp = (const float*)d_in[14];
    const float* bqp = (const float*)d_in[15];
    const float* Wkp = (const float*)d_in[16];
    const float* bkp = (const float*)d_in[17];
    const float* W_ih = (const float*)d_in[18];
    const float* W_hh = (const float*)d_in[19];
    const float* b_ih = (const float*)d_in[20];
    const float* b_hh = (const float*)d_in[21];
    const float* WO  = (const float*)d_in[22];
    const float* bO  = (const float*)d_in[23];
    const float* w   = (const float*)d_in[24];
    const float* w_a = (const float*)d_in[25];
    const float* w_p = (const float*)d_in[26];
    const int*   G   = (const int*)d_in[27];
    (void)in_sizes; (void)n_in; (void)out_size; (void)ws_size;

    float* ws = (float*)d_ws;
    unsigned short* wkb = (unsigned short*)(ws + WS_WKT);
    float* wkat   = ws + WS_WKAT;
    float* wkpt   = ws + WS_WKPT;
    float* qhat   = ws + WS_QHAT;
    float* qahat  = ws + WS_QAHAT;
    float* qphat  = ws + WS_QPHAT;
    float* logits = ws + WS_LOGITS;
    float* xbar   = ws + WS_XBAR;
    float* alast  = ws + WS_ALAST;
    float* resb   = ws + WS_RES;
    float* gi_all = ws + WS_GI;
    float* wqm    = ws + WS_WQM;
    float* outp   = (float*)d_out;

    hipMemsetAsync(logits, 0, (size_t)(N_LOGITS + N_XBAR)*sizeof(float), stream);

    prep_weights<<<(2*H*DM*DK + H*DA*DAh + H*DP*DPh + 255)/256, 256, 0, stream>>>(
        Wk, Wka, Wkp, Wq, G, wkb, wkat, wkpt, wqm);

    qhat_k<<<BB*H, 256, 0, stream>>>(memory, x_pre, aux, pos, wqm, bq, Wqa, bqa,
                                     Wqp, bqp, qhat, qahat, qphat);

    kproj_band_mfma<<<BB*H*(S/KT), 256, 0, stream>>>(memory, x_pre, wkb, bk, qhat,
                                                     w, logits);

    ka_proj_dot<<<BB*192, 256, 0, stream>>>(aux, wkat, bka, qahat, w_a, logits);
    kp_proj_dot<<<BB*192, 256, 0, stream>>>(pos, wkpt, bkp, qphat, w_p, logits);

    softmax_k<<<BB*H, 256, 0, stream>>>(logits, alast);

    xbar_k<<<BB*32, 256, 0, stream>>>(memory, logits, xbar);

    gi_k<<<31*BB, 192, 0, stream>>>(memory, W_ih, b_ih, gi_all);
    gru_scan<<<1, 512, 0, stream>>>(gi_all, W_hh, b_hh, resb);

    final_k<<<BB, 512, 0, stream>>>(x_pre, xbar, Wv, bv, WO, bO, alast, resb, G, outp);
}

// Round 4
// 907.003 us; speedup vs baseline: 3.0662x; 1.3557x over previous
//
#include <hip/hip_runtime.h>
#include <math.h>

// ---- problem constants (fixed by setup_inputs) ----
#define BB   8
#define S    6144
#define SM1  6143          // memory rows; x[:,SM1,:] == x_pre
#define DM   512
#define H    8
#define DK   64
#define M    32
#define WN   6113          // k + T - M + 1 = 2048+4096-32+1
#define DA   256
#define DAh  32
#define DP   128
#define DPh  16
#define EPSN 1e-12f

// ---- workspace layout (float offsets) ----
#define WS_WKT    0                       // reused: H*DM*DK bf16 packed Wk (131072 floats worth)
#define WS_WKAT   262144                  // H*DA*DAh  = 65536   WkaT [h][a][c]
#define WS_WKPT   327680                  // H*DP*DPh  = 16384   WkpT [h][p][c]
#define WS_QHAT   344064                  // B*H*M*DK  = 131072
#define WS_QAHAT  475136                  // B*H*DAh   = 2048
#define WS_QPHAT  477184                  // B*H*DPh   = 1024
#define WS_LOGITS 478208                  // B*H*WN    = 391232  (becomes attn in-place)
#define WS_XBAR   869440                  // B*H*DM    = 32768   (contiguous after logits)
#define WS_ALAST  902208                  // B*H       = 64
#define WS_RES    902272                  // B*DK      = 512
#define WS_GI     902784                  // 31*B*192  = 47616
#define WS_WQM    950400                  // H*DK*DM   = 262144  masked Wq [h][k][d]
#define N_LOGITS  391232
#define N_XBAR    32768

typedef __attribute__((ext_vector_type(8))) short short8;
typedef __attribute__((ext_vector_type(4))) float f32x4;

__device__ inline unsigned short f2bf(float f) {
    union { float f; unsigned u; } v; v.f = f;
    unsigned r = v.u + 0x7fffu + ((v.u >> 16) & 1u);   // RNE
    return (unsigned short)(r >> 16);
}

// ---------------------------------------------------------------------------
// prep: masked Wk -> packed bf16 wkb [h][(d>>3)*64+k][d&7] (MFMA B-frag order);
//       Wka -> wkat[h][a][c]; Wkp -> wkpt[h][p][c]; masked Wq -> wqm
__global__ void prep_weights(const float* __restrict__ Wk, const float* __restrict__ Wka,
                             const float* __restrict__ Wkp, const float* __restrict__ Wq,
                             const int* __restrict__ G,
                             unsigned short* __restrict__ wkb, float* __restrict__ wkat,
                             float* __restrict__ wkpt, float* __restrict__ wqm)
{
    int idx = blockIdx.x * 256 + threadIdx.x;
    if (idx < H*DM*DK) {
        int k = idx & 63; int d = (idx >> 6) & 511; int h = idx >> 15;
        float v = Wk[(size_t)(h*DK + k)*DM + d] * (float)G[k*DK + (d & 63)];
        wkb[(size_t)h*DM*DK + (((d >> 3)*DK + k) << 3) + (d & 7)] = f2bf(v);
    }
    int i2 = idx - H*DM*DK;
    if (i2 >= 0 && i2 < H*DA*DAh) {
        int c = i2 & 31; int a = (i2 >> 5) & 255; int h = i2 >> 13;
        wkat[i2] = Wka[(size_t)(h*DAh + c)*DA + a];
    }
    int i3 = idx - H*DM*DK - H*DA*DAh;
    if (i3 >= 0 && i3 < H*DP*DPh) {
        int c = i3 & 15; int p = (i3 >> 4) & 127; int h = i3 >> 11;
        wkpt[i3] = Wkp[(size_t)(h*DPh + c)*DP + p];
    }
    int i4 = idx - H*DM*DK - H*DA*DAh - H*DP*DPh;
    if (i4 >= 0 && i4 < H*DK*DM) {
        int d = i4 & 511; int k = (i4 >> 9) & 63;
        wqm[i4] = Wq[i4] * (float)G[k*DK + (d & 63)];
    }
}

// ---------------------------------------------------------------------------
// qhat: normalized Q rows for last M positions, plus qa_hat/qp_hat at last row.
__global__ __launch_bounds__(256) void qhat_k(
    const float* __restrict__ memory, const float* __restrict__ x_pre,
    const float* __restrict__ aux, const float* __restrict__ pos,
    const float* __restrict__ wqm, const float* __restrict__ bq,
    const float* __restrict__ Wqa, const float* __restrict__ bqa,
    const float* __restrict__ Wqp, const float* __restrict__ bqp,
    float* __restrict__ qhat, float* __restrict__ qahat, float* __restrict__ qphat)
{
    int bh = blockIdx.x; int b = bh >> 3, h = bh & 7;
    int tid = threadIdx.x;
    __shared__ float q[M][DK];
    __shared__ float nrm[M];
    __shared__ float qa[DAh];
    __shared__ float qp[DPh];

    int k = tid & 63;
    int mg = tid >> 6;                    // 0..3
    const float* wr = wqm + (size_t)(h*DK + k)*DM;
    for (int mp = 0; mp < 8; ++mp) {
        int m = mp*4 + mg;
        int t = S - M + m;                // 6112..6143
        const float* xr = (t < SM1) ? (memory + ((size_t)b*SM1 + t)*DM)
                                    : (x_pre + (size_t)b*DM);
        float s = 0.f;
        for (int d = 0; d < DM; d += 4) {
            float4 x4 = *(const float4*)(xr + d);
            float4 w4 = *(const float4*)(wr + d);
            s += x4.x*w4.x + x4.y*w4.y + x4.z*w4.z + x4.w*w4.w;
        }
        q[m][k] = s + bq[h*DK + k];
    }
    if (tid < DAh) {
        int c = tid;
        const float* ar = aux + ((size_t)b*S + (S-1))*DA;
        const float* wv = Wqa + (size_t)(h*DAh + c)*DA;
        float s = 0.f;
        for (int a = 0; a < DA; ++a) s += ar[a]*wv[a];
        qa[c] = s + bqa[h*DAh + c];
    }
    if (tid >= 64 && tid < 64 + DPh) {
        int c = tid - 64;
        const float* pr = pos + ((size_t)b*S + (S-1))*DP;
        const float* wv = Wqp + (size_t)(h*DPh + c)*DP;
        float s = 0.f;
        for (int p2 = 0; p2 < DP; ++p2) s += pr[p2]*wv[p2];
        qp[c] = s + bqp[h*DPh + c];
    }
    __syncthreads();
    if (tid < M) {
        float s = 0.f;
        for (int kk = 0; kk < DK; ++kk) { float v = q[tid][kk]; s += v*v; }
        nrm[tid] = fmaxf(sqrtf(s), EPSN);
    }
    __syncthreads();
    for (int i = tid; i < M*DK; i += 256) {
        int m = i >> 6, kk = i & 63;
        qhat[(size_t)bh*M*DK + i] = q[m][kk] / nrm[m];
    }
    if (tid < DAh) {
        float s = 0.f;
        for (int c = 0; c < DAh; ++c) s += qa[c]*qa[c];
        qahat[(size_t)bh*DAh + tid] = qa[tid] / fmaxf(sqrtf(s), EPSN);
    }
    if (tid < DPh) {
        float s = 0.f;
        for (int c = 0; c < DPh; ++c) s += qp[c]*qp[c];
        qphat[(size_t)bh*DPh + tid] = qp[tid] / fmaxf(sqrtf(s), EPSN);
    }
}

// ---------------------------------------------------------------------------
// MFMA K-projection (masked, biased, l2-normalized) fused with banded Q.K.
#define KT 64
__global__ __launch_bounds__(256) void kproj_band_mfma(
    const float* __restrict__ memory, const float* __restrict__ x_pre,
    const unsigned short* __restrict__ wkb, const float* __restrict__ bk,
    const float* __restrict__ qhat, const float* __restrict__ wscal,
    float* __restrict__ logits)
{
    int tile = blockIdx.x % (S / KT);                // 96
    int h = (blockIdx.x / (S / KT)) % H;
    int b = blockIdx.x / ((S / KT) * H);
    int t0 = tile * KT;
    int tid = threadIdx.x;
    int wave = tid >> 6, lane = tid & 63;
    int quad = lane >> 4, l16 = lane & 15;

    __shared__ unsigned short Xs[KT][136];           // 64 x 128 bf16 (+8 pad)
    __shared__ unsigned short Wls[16*DK*8];          // packed W chunk (128 d x 64 k)
    __shared__ unsigned short Qs[M][72];             // Qhat bf16 32 x 64 (+8 pad)
    __shared__ unsigned short Kb[KT][72];            // normalized K bf16
    __shared__ float tnloc[KT + 31];                 // 95 diagonals

    {   // stage qhat -> bf16 Qs
        const float* qsrc = qhat + (size_t)(b*H + h)*M*DK;
        int i = tid * 8;
        float4 a0 = *(const float4*)(qsrc + i);
        float4 a1 = *(const float4*)(qsrc + i + 4);
        int m = i >> 6, kk = i & 63;
        unsigned short* dst = &Qs[m][kk];
        dst[0]=f2bf(a0.x); dst[1]=f2bf(a0.y); dst[2]=f2bf(a0.z); dst[3]=f2bf(a0.w);
        dst[4]=f2bf(a1.x); dst[5]=f2bf(a1.y); dst[6]=f2bf(a1.z); dst[7]=f2bf(a1.w);
    }
    if (tid < KT + 31) tnloc[tid] = 0.f;

    f32x4 acc[4];
    #pragma unroll
    for (int nt = 0; nt < 4; ++nt) acc[nt] = (f32x4){0.f,0.f,0.f,0.f};

    int r0 = wave * 16;
    const unsigned short* wk_h = wkb + (size_t)h * DM * DK;

    for (int ch = 0; ch < 4; ++ch) {
        __syncthreads();
        {
            int row = tid >> 2;
            int dseg = (tid & 3) * 32;
            int t = t0 + row;
            const float* xr = ((t < SM1) ? (memory + ((size_t)b*SM1 + t)*DM)
                                         : (x_pre + (size_t)b*DM)) + ch*128 + dseg;
            unsigned short* dst = &Xs[row][dseg];
            #pragma unroll
            for (int i = 0; i < 8; ++i) {
                float4 v = *(const float4*)(xr + i*4);
                dst[i*4+0]=f2bf(v.x); dst[i*4+1]=f2bf(v.y);
                dst[i*4+2]=f2bf(v.z); dst[i*4+3]=f2bf(v.w);
            }
        }
        {
            const short8* src = (const short8*)(wk_h + (size_t)ch*128*DK);
            short8* dst = (short8*)Wls;
            #pragma unroll
            for (int i = 0; i < 4; ++i) dst[tid + 256*i] = src[tid + 256*i];
        }
        __syncthreads();
        #pragma unroll
        for (int ks = 0; ks < 4; ++ks) {
            short8 a = *(const short8*)&Xs[r0 + l16][ks*32 + quad*8];
            #pragma unroll
            for (int nt = 0; nt < 4; ++nt) {
                short8 bf = *(const short8*)&Wls[(((ks*4 + quad)*DK) + nt*16 + l16)*8];
                acc[nt] = __builtin_amdgcn_mfma_f32_16x16x32_bf16(a, bf, acc[nt], 0, 0, 0);
            }
        }
    }

    {
        float vv[4][4];
        float ss[4] = {0.f, 0.f, 0.f, 0.f};
        #pragma unroll
        for (int nt = 0; nt < 4; ++nt) {
            float bkv = bk[h*DK + nt*16 + l16];
            #pragma unroll
            for (int reg = 0; reg < 4; ++reg) {
                float v = acc[nt][reg] + bkv;
                vv[nt][reg] = v;
                ss[reg] += v*v;
            }
        }
        #pragma unroll
        for (int d2 = 1; d2 <= 8; d2 <<= 1) {
            #pragma unroll
            for (int reg = 0; reg < 4; ++reg) ss[reg] += __shfl_xor(ss[reg], d2);
        }
        float inv[4];
        #pragma unroll
        for (int reg = 0; reg < 4; ++reg)
            inv[reg] = 1.f / fmaxf(sqrtf(ss[reg]), EPSN);
        #pragma unroll
        for (int nt = 0; nt < 4; ++nt)
            #pragma unroll
            for (int reg = 0; reg < 4; ++reg)
                Kb[r0 + quad*4 + reg][nt*16 + l16] = f2bf(vv[nt][reg] * inv[reg]);
    }
    __syncthreads();

    {
        int mtile = wave & 1;
        int thalf = (wave >> 1) * 32;
        f32x4 acc2[2];
        acc2[0] = (f32x4){0.f,0.f,0.f,0.f};
        acc2[1] = (f32x4){0.f,0.f,0.f,0.f};
        #pragma unroll
        for (int ks = 0; ks < 2; ++ks) {
            short8 a = *(const short8*)&Qs[mtile*16 + l16][ks*32 + quad*8];
            #pragma unroll
            for (int nt = 0; nt < 2; ++nt) {
                short8 bf = *(const short8*)&Kb[thalf + nt*16 + l16][ks*32 + quad*8];
                acc2[nt] = __builtin_amdgcn_mfma_f32_16x16x32_bf16(a, bf, acc2[nt], 0, 0, 0);
            }
        }
        int m = mtile*16 + quad*4;
        #pragma unroll
        for (int nt = 0; nt < 2; ++nt) {
            int tl = thalf + nt*16 + l16;
            #pragma unroll
            for (int reg = 0; reg < 4; ++reg) {
                int mm = m + reg;
                int j = t0 + tl - mm;
                if (j >= 0 && j < WN)
                    atomicAdd(&tnloc[tl - mm + 31], acc2[nt][reg]);
            }
        }
    }
    __syncthreads();
    if (tid < KT + 31) {
        int j = t0 + tid - 31;
        if (j >= 0 && j < WN)
            atomicAdd(&logits[(size_t)(b*H + h)*WN + j], wscal[0]*(1.f/32.f)*tnloc[tid]);
    }
}

// ---------------------------------------------------------------------------
// ka_proj_dot: tiled GEMM aux(32 x 256) @ WkaT_h(256 x 32) per head, fused
// normalize + dot(qa_hat) epilogue -> logits += wa * dot2.
__global__ __launch_bounds__(256) void ka_proj_dot(
    const float* __restrict__ aux, const float* __restrict__ wkat,
    const float* __restrict__ bka, const float* __restrict__ qahat,
    const float* __restrict__ wa, float* __restrict__ logits)
{
    int tile = blockIdx.x % 192;
    int b    = blockIdx.x / 192;
    int j0   = tile * 32;
    int tid  = threadIdx.x;

    __shared__ float As[32][260];
    __shared__ float Bs[128][36];

    {
        int row = tid >> 3;
        int cb  = (tid & 7) * 32;
        int j = j0 + row; if (j > WN-1) j = WN-1;
        const float* ar = aux + ((size_t)b*S + (31 + j))*DA + cb;
        #pragma unroll
        for (int i = 0; i < 8; ++i)
            *(float4*)&As[row][cb + i*4] = *(const float4*)(ar + i*4);
    }

    int r  = tid >> 3;
    int tx = tid & 7;
    int c0 = tx * 4;
    int j  = j0 + r;
    float wav = wa[0];

    for (int h = 0; h < H; ++h) {
        float acc0 = 0.f, acc1 = 0.f, acc2 = 0.f, acc3 = 0.f;
        const float* wsrc = wkat + (size_t)h*DA*DAh;
        for (int kc = 0; kc < 2; ++kc) {
            __syncthreads();
            {
                int idx = tid * 4;
                #pragma unroll
                for (int i = 0; i < 4; ++i) {
                    int e = idx + i*1024;
                    int a = e >> 5, c = e & 31;
                    *(float4*)&Bs[a][c] = *(const float4*)(wsrc + (size_t)(kc*128 + a)*DAh + c);
                }
            }
            __syncthreads();
            int kbase = kc * 128;
            #pragma unroll 8
            for (int kk = 0; kk < 128; ++kk) {
                float a = As[r][kbase + kk];
                float4 b4 = *(const float4*)&Bs[kk][c0];
                acc0 += a*b4.x; acc1 += a*b4.y; acc2 += a*b4.z; acc3 += a*b4.w;
            }
        }
        const float* qa = qahat + (size_t)(b*H + h)*DAh + c0;
        float v0 = acc0 + bka[h*DAh + c0];
        float v1 = acc1 + bka[h*DAh + c0+1];
        float v2 = acc2 + bka[h*DAh + c0+2];
        float v3 = acc3 + bka[h*DAh + c0+3];
        float ss = v0*v0 + v1*v1 + v2*v2 + v3*v3;
        float dp = v0*qa[0] + v1*qa[1] + v2*qa[2] + v3*qa[3];
        #pragma unroll
        for (int d = 1; d <= 4; d <<= 1) {
            ss += __shfl_xor(ss, d);
            dp += __shfl_xor(dp, d);
        }
        if (tx == 0 && j < WN)
            logits[(size_t)(b*H + h)*WN + j] += wav * dp / fmaxf(sqrtf(ss), EPSN);
    }
}

// ---------------------------------------------------------------------------
// kp_proj_dot: pos(32 x 128) @ WkpT(128 x 16) for 4 heads at once, fused epilogue.
__global__ __launch_bounds__(256) void kp_proj_dot(
    const float* __restrict__ pos, const float* __restrict__ wkpt,
    const float* __restrict__ bkp, const float* __restrict__ qphat,
    const float* __restrict__ wp, float* __restrict__ logits)
{
    int tile = blockIdx.x % 192;
    int b    = blockIdx.x / 192;
    int j0   = tile * 32;
    int tid  = threadIdx.x;

    __shared__ float As[32][132];
    __shared__ float Bs[128][68];

    {
        int row = tid >> 3;
        int cb  = (tid & 7) * 16;
        int j = j0 + row; if (j > WN-1) j = WN-1;
        const float* pr = pos + ((size_t)b*S + (31 + j))*DP + cb;
        #pragma unroll
        for (int i = 0; i < 4; ++i)
            *(float4*)&As[row][cb + i*4] = *(const float4*)(pr + i*4);
    }

    int r  = tid >> 3;
    int tx = tid & 7;
    int j  = j0 + r;
    float wpv = wp[0];

    for (int hg = 0; hg < 2; ++hg) {
        __syncthreads();
        {
            int idx = tid * 4;
            #pragma unroll
            for (int i = 0; i < 8; ++i) {
                int e = idx + i*1024;
                int col = e & 63, p = e >> 6;
                int hh = col >> 4, c = col & 15;
                *(float4*)&Bs[p][col] =
                    *(const float4*)(wkpt + (size_t)(hg*4 + hh)*DP*DPh + (size_t)p*DPh + c);
            }
        }
        __syncthreads();
        float acc[8];
        #pragma unroll
        for (int i = 0; i < 8; ++i) acc[i] = 0.f;
        int cb = tx * 8;
        #pragma unroll 4
        for (int kk = 0; kk < 128; ++kk) {
            float a = As[r][kk];
            float4 b0 = *(const float4*)&Bs[kk][cb];
            float4 b1 = *(const float4*)&Bs[kk][cb + 4];
            acc[0] += a*b0.x; acc[1] += a*b0.y; acc[2] += a*b0.z; acc[3] += a*b0.w;
            acc[4] += a*b1.x; acc[5] += a*b1.y; acc[6] += a*b1.z; acc[7] += a*b1.w;
        }
        int hh = hg*4 + (tx >> 1);
        int ch0 = (tx & 1) * 8;
        const float* qp = qphat + (size_t)(b*H + hh)*DPh + ch0;
        const float* bb = bkp + hh*DPh + ch0;
        float ss = 0.f, dp = 0.f;
        #pragma unroll
        for (int i = 0; i < 8; ++i) {
            float v = acc[i] + bb[i];
            ss += v*v; dp += v*qp[i];
        }
        ss += __shfl_xor(ss, 1);
        dp += __shfl_xor(dp, 1);
        if ((tx & 1) == 0 && j < WN)
            logits[(size_t)(b*H + hh)*WN + j] += wpv * dp / fmaxf(sqrtf(ss), EPSN);
    }
}

// ---------------------------------------------------------------------------
// softmax over WN per (b,h); in-place logits -> attn; record attn[WN-1]
__global__ __launch_bounds__(256) void softmax_k(float* __restrict__ logits,
                                                 float* __restrict__ alast)
{
    int bh = blockIdx.x;
    float* L = logits + (size_t)bh*WN;
    __shared__ float red[256];
    int tid = threadIdx.x;
    float mx = -1e30f;
    for (int j = tid; j < WN; j += 256) mx = fmaxf(mx, L[j]);
    red[tid] = mx; __syncthreads();
    for (int s2 = 128; s2 > 0; s2 >>= 1) {
        if (tid < s2) red[tid] = fmaxf(red[tid], red[tid+s2]);
        __syncthreads();
    }
    mx = red[0]; __syncthreads();
    float sm = 0.f;
    for (int j = tid; j < WN; j += 256) sm += expf(L[j] - mx);
    red[tid] = sm; __syncthreads();
    for (int s2 = 128; s2 > 0; s2 >>= 1) {
        if (tid < s2) red[tid] += red[tid+s2];
        __syncthreads();
    }
    float inv = 1.f / red[0];
    for (int j = tid; j < WN; j += 256) {
        float a = expf(L[j] - mx) * inv;
        L[j] = a;
        if (j == WN-1) alast[bh] = a;
    }
}

// ---------------------------------------------------------------------------
// xbar[b,h,:] = sum_{j<WN-1} attn[b,h,j] * x[b, 31+j, :]
#define JC 191
__global__ __launch_bounds__(256) void xbar_k(
    const float* __restrict__ memory, const float* __restrict__ attn,
    float* __restrict__ xbar)
{
    int chunk = blockIdx.x & 31;
    int b = blockIdx.x >> 5;
    int j0 = chunk * JC;
    __shared__ float al[H][JC];
    int tid = threadIdx.x;
    for (int i = tid; i < H*JC; i += 256) {
        int hh = i / JC, jj = i - hh*JC;
        al[hh][jj] = attn[(size_t)(b*H + hh)*WN + j0 + jj];
    }
    __syncthreads();
    int d0 = tid * 2;
    float acc[H][2];
    #pragma unroll
    for (int hh = 0; hh < H; ++hh) { acc[hh][0] = 0.f; acc[hh][1] = 0.f; }
    for (int jj = 0; jj < JC; ++jj) {
        int t = 31 + j0 + jj;
        const float2 xv = *(const float2*)(memory + ((size_t)b*SM1 + t)*DM + d0);
        #pragma unroll
        for (int hh = 0; hh < H; ++hh) {
            float a = al[hh][jj];
            acc[hh][0] += a * xv.x;
            acc[hh][1] += a * xv.y;
        }
    }
    #pragma unroll
    for (int hh = 0; hh < H; ++hh) {
        atomicAdd(&xbar[(size_t)(b*H+hh)*DM + d0],     acc[hh][0]);
        atomicAdd(&xbar[(size_t)(b*H+hh)*DM + d0 + 1], acc[hh][1]);
    }
}

// ---------------------------------------------------------------------------
__global__ __launch_bounds__(192) void gi_k(
    const float* __restrict__ memory, const float* __restrict__ W_ih,
    const float* __restrict__ b_ih, float* __restrict__ gi_all)
{
    int t = blockIdx.x >> 3;
    int b = blockIdx.x & 7;
    int c = threadIdx.x;
    const float* xr = memory + ((size_t)b*SM1 + (S - M) + t)*DM;
    const float* wr = W_ih + (size_t)c*DM;
    float s = b_ih[c];
    for (int d = 0; d < DM; d += 4) {
        float4 x4 = *(const float4*)(xr + d);
        float4 w4 = *(const float4*)(wr + d);
        s += x4.x*w4.x + x4.y*w4.y + x4.z*w4.z + x4.w*w4.w;
    }
    gi_all[((size_t)t*BB + b)*192 + c] = s;
}

// ---------------------------------------------------------------------------
// GRU scan, register-resident: one wave per batch, W_hh rows {l,64+l,128+l}
// in VGPRs, h broadcast via v_readlane. Zero LDS, zero barriers.
__global__ __launch_bounds__(512) void gru_scan(
    const float* __restrict__ gi_all, const float* __restrict__ W_hh,
    const float* __restrict__ b_hh, float* __restrict__ res)
{
    int b = threadIdx.x >> 6;      // batch (wave id)
    int l = threadIdx.x & 63;      // hidden channel

    float w0[64], w1[64], w2[64];
    {
        const float* r0p = W_hh + (size_t)l*DK;
        const float* r1p = W_hh + (size_t)(64 + l)*DK;
        const float* r2p = W_hh + (size_t)(128 + l)*DK;
        #pragma unroll
        for (int i = 0; i < 16; ++i) {
            float4 a = *(const float4*)(r0p + i*4);
            w0[i*4]=a.x; w0[i*4+1]=a.y; w0[i*4+2]=a.z; w0[i*4+3]=a.w;
            float4 c = *(const float4*)(r1p + i*4);
            w1[i*4]=c.x; w1[i*4+1]=c.y; w1[i*4+2]=c.z; w1[i*4+3]=c.w;
            float4 e = *(const float4*)(r2p + i*4);
            w2[i*4]=e.x; w2[i*4+1]=e.y; w2[i*4+2]=e.z; w2[i*4+3]=e.w;
        }
    }
    float bh0 = b_hh[l], bh1 = b_hh[64 + l], bh2 = b_hh[128 + l];

    float h = 0.f;
    const float* g0 = gi_all + (size_t)b*192;       // t=0 block
    float gr = g0[l], gz = g0[64 + l], gn = g0[128 + l];

    #pragma unroll 1
    for (int t = 0; t < 31; ++t) {
        float a0 = bh0, a1 = bh1, a2 = bh2;
        #pragma unroll
        for (int k = 0; k < 64; ++k) {
            float hk = __int_as_float(__builtin_amdgcn_readlane(__float_as_int(h), k));
            a0 += hk * w0[k];
            a1 += hk * w1[k];
            a2 += hk * w2[k];
        }
        // prefetch next step's gi
        float ngr = 0.f, ngz = 0.f, ngn = 0.f;
        if (t < 30) {
            const float* g2 = gi_all + ((size_t)(t+1)*BB + b)*192;
            ngr = g2[l]; ngz = g2[64 + l]; ngn = g2[128 + l];
        }
        float r = 1.f / (1.f + expf(-(gr + a0)));
        float z = 1.f / (1.f + expf(-(gz + a1)));
        float n = tanhf(gn + r * a2);
        h = (1.f - z)*n + z*h;
        gr = ngr; gz = ngz; gn = ngn;
    }
    res[b*DK + l] = h;
}

// ---------------------------------------------------------------------------
__global__ __launch_bounds__(512) void final_k(
    const float* __restrict__ x_pre, const float* __restrict__ xbar,
    const float* __restrict__ Wv, const float* __restrict__ bv,
    const float* __restrict__ WO, const float* __restrict__ bO,
    const float* __restrict__ alast, const float* __restrict__ res,
    const int* __restrict__ G, float* __restrict__ out)
{
    int b = blockIdx.x;
    int tid = threadIdx.x;
    __shared__ float gl[64*64];
    __shared__ float deta[512];
    for (int i = tid; i < 4096; i += 512) gl[i] = (float)G[(i & 63)*64 + (i >> 6)];
    __syncthreads();
    int h = tid >> 6, dk = tid & 63;
    float ala = alast[b*H + h];
    const float* xb  = xbar + (size_t)(b*H + h)*DM;
    const float* wvr = Wv + (size_t)tid*DM;
    const float* gcol = gl + dk;
    float s = 0.f;
    for (int e = 0; e < DM; e += 4) {
        float4 wv4 = *(const float4*)(wvr + e);
        float4 xb4 = *(const float4*)(xb + e);
        int eb = e & 63;
        s += wv4.x*gcol[eb*64]     *xb4.x + wv4.y*gcol[(eb+1)*64]*xb4.y
           + wv4.z*gcol[(eb+2)*64]*xb4.z + wv4.w*gcol[(eb+3)*64]*xb4.w;
    }
    float hist = s + bv[tid]*(1.f - ala);
    deta[tid] = hist + ala * res[b*DK + dk];
    __syncthreads();
    int dpos = tid;
    const float* wor = WO + (size_t)dpos*DM;
    const float* gcol2 = gl + (dpos & 63);
    float o = 0.f;
    for (int jj = 0; jj < DM; jj += 4) {
        float4 wo4 = *(const float4*)(wor + jj);
        int jb = jj & 63;
        o += wo4.x*gcol2[jb*64]     *deta[jj]   + wo4.y*gcol2[(jb+1)*64]*deta[jj+1]
           + wo4.z*gcol2[(jb+2)*64]*deta[jj+2] + wo4.w*gcol2[(jb+3)*64]*deta[jj+3];
    }
    out[(size_t)b*DM + dpos] = x_pre[(size_t)b*DM + dpos] + o + bO[dpos];
}

// ---------------------------------------------------------------------------
extern "C" void kernel_launch(void* const* d_in, const int* in_sizes, int n_in,
                              void* d_out, int out_size, void* d_ws, size_t ws_size,
                              hipStream_t stream)
{
    const float* memory = (const float*)d_in[0];
    const float* x_pre  = (const float*)d_in[1];
    const float* aux    = (const float*)d_in[2];
    const float* pos    = (const float*)d_in[3];
    const float* Wq  = (const float*)d_in[4];
    const float* bq  = (const float*)d_in[5];
    const float* Wk  = (const float*)d_in[6];
    const float* bk  = (const float*)d_in[7];
    const float* Wv  = (const float*)d_in[8];
    const float* bv  = (const float*)d_in[9];
    const float* Wqa = (const float*)d_in[10];
    const float* bqa = (const float*)d_in[11];
    const float* Wka = (const float*)d_in[12];
    const float* bka = (const float*)d_in[13];
    const float* Wqp = (const float*)d_in[14];
    const float* bqp = (const float*)d_in[15];
    const float* Wkp = (const float*)d_in[16];
    const float* bkp = (const float*)d_in[17];
    const float* W_ih = (const float*)d_in[18];
    const float* W_hh = (const float*)d_in[19];
    const float* b_ih = (const float*)d_in[20];
    const float* b_hh = (const float*)d_in[21];
    const float* WO  = (const float*)d_in[22];
    const float* bO  = (const float*)d_in[23];
    const float* w   = (const float*)d_in[24];
    const float* w_a = (const float*)d_in[25];
    const float* w_p = (const float*)d_in[26];
    const int*   G   = (const int*)d_in[27];
    (void)in_sizes; (void)n_in; (void)out_size; (void)ws_size;

    float* ws = (float*)d_ws;
    unsigned short* wkb = (unsigned short*)(ws + WS_WKT);
    float* wkat   = ws + WS_WKAT;
    float* wkpt   = ws + WS_WKPT;
    float* qhat   = ws + WS_QHAT;
    float* qahat  = ws + WS_QAHAT;
    float* qphat  = ws + WS_QPHAT;
    float* logits = ws + WS_LOGITS;
    float* xbar   = ws + WS_XBAR;
    float* alast  = ws + WS_ALAST;
    float* resb   = ws + WS_RES;
    float* gi_all = ws + WS_GI;
    float* wqm    = ws + WS_WQM;
    float* outp   = (float*)d_out;

    hipMemsetAsync(logits, 0, (size_t)(N_LOGITS + N_XBAR)*sizeof(float), stream);

    prep_weights<<<(2*H*DM*DK + H*DA*DAh + H*DP*DPh + 255)/256, 256, 0, stream>>>(
        Wk, Wka, Wkp, Wq, G, wkb, wkat, wkpt, wqm);

    // GRU path first: independent of attention, tiny kernels
    gi_k<<<31*BB, 192, 0, stream>>>(memory, W_ih, b_ih, gi_all);
    gru_scan<<<1, 512, 0, stream>>>(gi_all, W_hh, b_hh, resb);

    qhat_k<<<BB*H, 256, 0, stream>>>(memory, x_pre, aux, pos, wqm, bq, Wqa, bqa,
                                     Wqp, bqp, qhat, qahat, qphat);

    kproj_band_mfma<<<BB*H*(S/KT), 256, 0, stream>>>(memory, x_pre, wkb, bk, qhat,
                                                     w, logits);

    ka_proj_dot<<<BB*192, 256, 0, stream>>>(aux, wkat, bka, qahat, w_a, logits);
    kp_proj_dot<<<BB*192, 256, 0, stream>>>(pos, wkpt, bkp, qphat, w_p, logits);

    softmax_k<<<BB*H, 256, 0, stream>>>(logits, alast);

    xbar_k<<<BB*32, 256, 0, stream>>>(memory, logits, xbar);

    final_k<<<BB, 512, 0, stream>>>(x_pre, xbar, Wv, bv, WO, bO, alast, resb, G, outp);
}

// Round 5
// 758.018 us; speedup vs baseline: 3.6689x; 1.1965x over previous
//
#include <hip/hip_runtime.h>
#include <math.h>

// ---- problem constants (fixed by setup_inputs) ----
#define BB   8
#define S    6144
#define SM1  6143          // memory rows; x[:,SM1,:] == x_pre
#define DM   512
#define H    8
#define DK   64
#define M    32
#define WN   6113          // k + T - M + 1
#define DA   256
#define DAh  32
#define DP   128
#define DPh  16
#define EPSN 1e-12f

// ---- workspace layout (float offsets) ----
#define WS_WKT    0                       // H*DM*DK bf16 packed Wk
#define WS_WKAT   262144                  // H*DA*DAh bf16 packed Wka (fits old fp32 slot)
#define WS_WKPT   327680                  // H*DP*DPh bf16 packed Wkp
#define WS_QHAT   344064                  // B*H*M*DK fp32
#define WS_QAHAT  475136                  // B*H*DAh fp32
#define WS_QPHAT  477184                  // B*H*DPh fp32
#define WS_LOGITS 478208                  // B*H*WN
#define WS_XBAR   869440                  // B*H*DM
#define WS_ALAST  902208
#define WS_RES    902272
#define WS_GI     902784
#define WS_WQM    950400                  // H*DK*DM masked Wq fp32
#define N_LOGITS  391232
#define N_XBAR    32768

typedef __attribute__((ext_vector_type(8))) short short8;
typedef __attribute__((ext_vector_type(4))) float f32x4;

__device__ inline unsigned short f2bf(float f) {
    union { float f; unsigned u; } v; v.f = f;
    unsigned r = v.u + 0x7fffu + ((v.u >> 16) & 1u);   // RNE
    return (unsigned short)(r >> 16);
}

union S8U { short8 v; unsigned short e[8]; };

// ---------------------------------------------------------------------------
// prep: masked Wk -> packed bf16 wkb [h][(d>>3)*64+k][d&7];
//       Wka -> packed bf16 wkab [h][(a>>3)*32+c][a&7];
//       Wkp -> packed bf16 wkpb [h][(p>>3)*16+c][p&7]; masked Wq -> wqm fp32
__global__ void prep_weights(const float* __restrict__ Wk, const float* __restrict__ Wka,
                             const float* __restrict__ Wkp, const float* __restrict__ Wq,
                             const int* __restrict__ G,
                             unsigned short* __restrict__ wkb,
                             unsigned short* __restrict__ wkab,
                             unsigned short* __restrict__ wkpb,
                             float* __restrict__ wqm)
{
    int idx = blockIdx.x * 256 + threadIdx.x;
    if (idx < H*DM*DK) {
        int k = idx & 63; int d = (idx >> 6) & 511; int h = idx >> 15;
        float v = Wk[(size_t)(h*DK + k)*DM + d] * (float)G[k*DK + (d & 63)];
        wkb[(size_t)h*DM*DK + (((d >> 3)*DK + k) << 3) + (d & 7)] = f2bf(v);
    }
    int i2 = idx - H*DM*DK;
    if (i2 >= 0 && i2 < H*DA*DAh) {
        int h = i2 >> 13; int r = i2 & 8191;
        int j = r & 7; int f = r >> 3;
        int c = f & 31; int a = (f >> 5)*8 + j;
        wkab[i2] = f2bf(Wka[(size_t)(h*DAh + c)*DA + a]);
    }
    int i3 = idx - H*DM*DK - H*DA*DAh;
    if (i3 >= 0 && i3 < H*DP*DPh) {
        int h = i3 >> 11; int r = i3 & 2047;
        int j = r & 7; int f = r >> 3;
        int c = f & 15; int p = (f >> 4)*8 + j;
        wkpb[i3] = f2bf(Wkp[(size_t)(h*DPh + c)*DP + p]);
    }
    int i4 = idx - H*DM*DK - H*DA*DAh - H*DP*DPh;
    if (i4 >= 0 && i4 < H*DK*DM) {
        int d = i4 & 511; int k = (i4 >> 9) & 63;
        wqm[i4] = Wq[i4] * (float)G[k*DK + (d & 63)];
    }
}

// ---------------------------------------------------------------------------
// qhat: normalized Q rows for last M positions, plus qa_hat/qp_hat at last row.
__global__ __launch_bounds__(256) void qhat_k(
    const float* __restrict__ memory, const float* __restrict__ x_pre,
    const float* __restrict__ aux, const float* __restrict__ pos,
    const float* __restrict__ wqm, const float* __restrict__ bq,
    const float* __restrict__ Wqa, const float* __restrict__ bqa,
    const float* __restrict__ Wqp, const float* __restrict__ bqp,
    float* __restrict__ qhat, float* __restrict__ qahat, float* __restrict__ qphat)
{
    int bh = blockIdx.x; int b = bh >> 3, h = bh & 7;
    int tid = threadIdx.x;
    __shared__ float q[M][DK];
    __shared__ float nrm[M];
    __shared__ float qa[DAh];
    __shared__ float qp[DPh];

    int k = tid & 63;
    int mg = tid >> 6;
    const float* wr = wqm + (size_t)(h*DK + k)*DM;
    for (int mp = 0; mp < 8; ++mp) {
        int m = mp*4 + mg;
        int t = S - M + m;
        const float* xr = (t < SM1) ? (memory + ((size_t)b*SM1 + t)*DM)
                                    : (x_pre + (size_t)b*DM);
        float s = 0.f;
        for (int d = 0; d < DM; d += 4) {
            float4 x4 = *(const float4*)(xr + d);
            float4 w4 = *(const float4*)(wr + d);
            s += x4.x*w4.x + x4.y*w4.y + x4.z*w4.z + x4.w*w4.w;
        }
        q[m][k] = s + bq[h*DK + k];
    }
    if (tid < DAh) {
        int c = tid;
        const float* ar = aux + ((size_t)b*S + (S-1))*DA;
        const float* wv = Wqa + (size_t)(h*DAh + c)*DA;
        float s = 0.f;
        for (int a = 0; a < DA; ++a) s += ar[a]*wv[a];
        qa[c] = s + bqa[h*DAh + c];
    }
    if (tid >= 64 && tid < 64 + DPh) {
        int c = tid - 64;
        const float* pr = pos + ((size_t)b*S + (S-1))*DP;
        const float* wv = Wqp + (size_t)(h*DPh + c)*DP;
        float s = 0.f;
        for (int p2 = 0; p2 < DP; ++p2) s += pr[p2]*wv[p2];
        qp[c] = s + bqp[h*DPh + c];
    }
    __syncthreads();
    if (tid < M) {
        float s = 0.f;
        for (int kk = 0; kk < DK; ++kk) { float v = q[tid][kk]; s += v*v; }
        nrm[tid] = fmaxf(sqrtf(s), EPSN);
    }
    __syncthreads();
    for (int i = tid; i < M*DK; i += 256) {
        int m = i >> 6, kk = i & 63;
        qhat[(size_t)bh*M*DK + i] = q[m][kk] / nrm[m];
    }
    if (tid < DAh) {
        float s = 0.f;
        for (int c = 0; c < DAh; ++c) s += qa[c]*qa[c];
        qahat[(size_t)bh*DAh + tid] = qa[tid] / fmaxf(sqrtf(s), EPSN);
    }
    if (tid < DPh) {
        float s = 0.f;
        for (int c = 0; c < DPh; ++c) s += qp[c]*qp[c];
        qphat[(size_t)bh*DPh + tid] = qp[tid] / fmaxf(sqrtf(s), EPSN);
    }
}

// ---------------------------------------------------------------------------
// kproj v2: grid (b, head-pair, tile128). X chunk staged/converted ONCE per
// pair (halves global X traffic & converts vs per-head blocks). Wave = 32 rows
// x 64 cols. Fused bias+l2norm (wave-local butterfly) + banded Q.K + scatter.
__global__ __launch_bounds__(256, 2) void kproj_band_mfma2(
    const float* __restrict__ memory, const float* __restrict__ x_pre,
    const unsigned short* __restrict__ wkb, const float* __restrict__ bk,
    const float* __restrict__ qhat, const float* __restrict__ wscal,
    float* __restrict__ logits)
{
    int bx = blockIdx.x;
    int hp = bx & 3, b = (bx >> 2) & 7, tile = bx >> 5;   // 48 tiles
    int t0 = tile * 128;
    int tid = threadIdx.x;
    int wave = tid >> 6, lane = tid & 63;
    int quad = lane >> 4, l16 = lane & 15;

    __shared__ unsigned short Xf[32*520];   // 128 rows x 128 d, A-frag order (+pad)
    __shared__ unsigned short Wf[16*520];   // 128 d x 64 k, B-frag order (+pad)
    __shared__ unsigned short Kb[128][72];  // normalized K bf16
    __shared__ unsigned short Qs[M][72];    // Qhat bf16
    __shared__ float tnloc[159];

    if (tid < 159) tnloc[tid] = 0.f;

    // stage Qs for head h0
    {
        int h = hp*2;
        const float* qsrc = qhat + (size_t)(b*H + h)*M*DK;
        int i = tid * 8;
        float4 a0 = *(const float4*)(qsrc + i);
        float4 a1 = *(const float4*)(qsrc + i + 4);
        S8U t8;
        t8.e[0]=f2bf(a0.x); t8.e[1]=f2bf(a0.y); t8.e[2]=f2bf(a0.z); t8.e[3]=f2bf(a0.w);
        t8.e[4]=f2bf(a1.x); t8.e[5]=f2bf(a1.y); t8.e[6]=f2bf(a1.z); t8.e[7]=f2bf(a1.w);
        *(short8*)&Qs[i >> 6][i & 63] = t8.v;
    }

    f32x4 acc[2][2][4];
    #pragma unroll
    for (int hi = 0; hi < 2; ++hi)
        #pragma unroll
        for (int mt = 0; mt < 2; ++mt)
            #pragma unroll
            for (int nt = 0; nt < 4; ++nt) acc[hi][mt][nt] = (f32x4){0.f,0.f,0.f,0.f};

    for (int ch = 0; ch < 4; ++ch) {
        __syncthreads();
        {   // X chunk: 128 rows x 128 d fp32 -> bf16 A-frag LDS (once, both heads)
            int r = tid >> 1, half = tid & 1;
            int t = t0 + r;
            const float* xr = ((t < SM1) ? (memory + ((size_t)b*SM1 + t)*DM)
                                         : (x_pre + (size_t)b*DM)) + ch*128 + half*64;
            int tt = r >> 4, lo = r & 15;
            #pragma unroll
            for (int g = 0; g < 8; ++g) {
                float4 v0 = *(const float4*)(xr + g*8);
                float4 v1 = *(const float4*)(xr + g*8 + 4);
                int d0 = half*64 + g*8;
                int ks = d0 >> 5, qd = (d0 >> 3) & 3;
                S8U t8;
                t8.e[0]=f2bf(v0.x); t8.e[1]=f2bf(v0.y); t8.e[2]=f2bf(v0.z); t8.e[3]=f2bf(v0.w);
                t8.e[4]=f2bf(v1.x); t8.e[5]=f2bf(v1.y); t8.e[6]=f2bf(v1.z); t8.e[7]=f2bf(v1.w);
                *(short8*)&Xf[(tt*4 + ks)*520 + (qd*16 + lo)*8] = t8.v;
            }
        }
        {   // W chunk head h0
            const unsigned short* src = wkb + (size_t)(hp*2)*DM*DK + (size_t)ch*8192;
            #pragma unroll
            for (int i = 0; i < 4; ++i) {
                int f = tid + 256*i;
                *(short8*)&Wf[(f >> 6)*520 + (f & 63)*8] = *(const short8*)(src + f*8);
            }
        }
        __syncthreads();
        #pragma unroll
        for (int ks = 0; ks < 4; ++ks) {
            short8 a0 = *(const short8*)&Xf[((wave*2 + 0)*4 + ks)*520 + lane*8];
            short8 a1 = *(const short8*)&Xf[((wave*2 + 1)*4 + ks)*520 + lane*8];
            #pragma unroll
            for (int nt = 0; nt < 4; ++nt) {
                short8 bf = *(const short8*)&Wf[(ks*4 + quad)*520 + (nt*16 + l16)*8];
                acc[0][0][nt] = __builtin_amdgcn_mfma_f32_16x16x32_bf16(a0, bf, acc[0][0][nt], 0, 0, 0);
                acc[0][1][nt] = __builtin_amdgcn_mfma_f32_16x16x32_bf16(a1, bf, acc[0][1][nt], 0, 0, 0);
            }
        }
        __syncthreads();
        {   // W chunk head h1
            const unsigned short* src = wkb + (size_t)(hp*2 + 1)*DM*DK + (size_t)ch*8192;
            #pragma unroll
            for (int i = 0; i < 4; ++i) {
                int f = tid + 256*i;
                *(short8*)&Wf[(f >> 6)*520 + (f & 63)*8] = *(const short8*)(src + f*8);
            }
        }
        __syncthreads();
        #pragma unroll
        for (int ks = 0; ks < 4; ++ks) {
            short8 a0 = *(const short8*)&Xf[((wave*2 + 0)*4 + ks)*520 + lane*8];
            short8 a1 = *(const short8*)&Xf[((wave*2 + 1)*4 + ks)*520 + lane*8];
            #pragma unroll
            for (int nt = 0; nt < 4; ++nt) {
                short8 bf = *(const short8*)&Wf[(ks*4 + quad)*520 + (nt*16 + l16)*8];
                acc[1][0][nt] = __builtin_amdgcn_mfma_f32_16x16x32_bf16(a0, bf, acc[1][0][nt], 0, 0, 0);
                acc[1][1][nt] = __builtin_amdgcn_mfma_f32_16x16x32_bf16(a1, bf, acc[1][1][nt], 0, 0, 0);
            }
        }
    }

    float wom = wscal[0] * (1.f/32.f);

    for (int hi = 0; hi < 2; ++hi) {
        int h = hp*2 + hi;
        __syncthreads();
        {   // bias + row l2-norm (wave-local: wave owns all 64 cols of its rows)
            float ss[2][4];
            float vv[2][4][4];
            #pragma unroll
            for (int mt = 0; mt < 2; ++mt)
                #pragma unroll
                for (int reg = 0; reg < 4; ++reg) ss[mt][reg] = 0.f;
            #pragma unroll
            for (int nt = 0; nt < 4; ++nt) {
                float bkv = bk[h*DK + nt*16 + l16];
                #pragma unroll
                for (int mt = 0; mt < 2; ++mt)
                    #pragma unroll
                    for (int reg = 0; reg < 4; ++reg) {
                        float v = acc[hi][mt][nt][reg] + bkv;
                        vv[mt][nt][reg] = v;
                        ss[mt][reg] += v*v;
                    }
            }
            #pragma unroll
            for (int d2 = 1; d2 <= 8; d2 <<= 1)
                #pragma unroll
                for (int mt = 0; mt < 2; ++mt)
                    #pragma unroll
                    for (int reg = 0; reg < 4; ++reg)
                        ss[mt][reg] += __shfl_xor(ss[mt][reg], d2);
            #pragma unroll
            for (int mt = 0; mt < 2; ++mt) {
                float inv[4];
                #pragma unroll
                for (int reg = 0; reg < 4; ++reg)
                    inv[reg] = 1.f / fmaxf(sqrtf(ss[mt][reg]), EPSN);
                #pragma unroll
                for (int nt = 0; nt < 4; ++nt)
                    #pragma unroll
                    for (int reg = 0; reg < 4; ++reg)
                        Kb[wave*32 + mt*16 + quad*4 + reg][nt*16 + l16] =
                            f2bf(vv[mt][nt][reg] * inv[reg]);
            }
        }
        __syncthreads();
        {   // banded Q.K^T on this wave's 32 t-cols
            f32x4 acc2[2][2];
            #pragma unroll
            for (int mt = 0; mt < 2; ++mt)
                #pragma unroll
                for (int nt = 0; nt < 2; ++nt) acc2[mt][nt] = (f32x4){0.f,0.f,0.f,0.f};
            #pragma unroll
            for (int ks = 0; ks < 2; ++ks) {
                short8 qa0 = *(const short8*)&Qs[l16     ][ks*32 + quad*8];
                short8 qa1 = *(const short8*)&Qs[16 + l16][ks*32 + quad*8];
                #pragma unroll
                for (int nt = 0; nt < 2; ++nt) {
                    short8 kf = *(const short8*)&Kb[wave*32 + nt*16 + l16][ks*32 + quad*8];
                    acc2[0][nt] = __builtin_amdgcn_mfma_f32_16x16x32_bf16(qa0, kf, acc2[0][nt], 0, 0, 0);
                    acc2[1][nt] = __builtin_amdgcn_mfma_f32_16x16x32_bf16(qa1, kf, acc2[1][nt], 0, 0, 0);
                }
            }
            #pragma unroll
            for (int mt = 0; mt < 2; ++mt)
                #pragma unroll
                for (int nt = 0; nt < 2; ++nt) {
                    int tcol = wave*32 + nt*16 + l16;
                    #pragma unroll
                    for (int reg = 0; reg < 4; ++reg) {
                        int m = mt*16 + quad*4 + reg;
                        int j = t0 + tcol - m;
                        if (j >= 0 && j < WN)
                            atomicAdd(&tnloc[tcol - m + 31], acc2[mt][nt][reg]);
                    }
                }
        }
        __syncthreads();
        if (tid < 159) {
            int j = t0 + tid - 31;
            if (j >= 0 && j < WN)
                atomicAdd(&logits[(size_t)(b*H + h)*WN + j], wom * tnloc[tid]);
            tnloc[tid] = 0.f;
        }
        if (hi == 0) {   // stage Qs for h1
            const float* qsrc = qhat + (size_t)(b*H + h + 1)*M*DK;
            int i = tid * 8;
            float4 a0 = *(const float4*)(qsrc + i);
            float4 a1 = *(const float4*)(qsrc + i + 4);
            S8U t8;
            t8.e[0]=f2bf(a0.x); t8.e[1]=f2bf(a0.y); t8.e[2]=f2bf(a0.z); t8.e[3]=f2bf(a0.w);
            t8.e[4]=f2bf(a1.x); t8.e[5]=f2bf(a1.y); t8.e[6]=f2bf(a1.z); t8.e[7]=f2bf(a1.w);
            *(short8*)&Qs[i >> 6][i & 63] = t8.v;
        }
    }
}

// ---------------------------------------------------------------------------
// ka v2 (MFMA): 64 j-rows per block; aux A-frags staged once; per-head packed
// B-frags; fused bias+norm+dot(qa_hat) -> logits += wa * dot2.
__global__ __launch_bounds__(256, 2) void ka_proj_mfma(
    const float* __restrict__ aux, const unsigned short* __restrict__ wkab,
    const float* __restrict__ bka, const float* __restrict__ qahat,
    const float* __restrict__ wa, float* __restrict__ logits)
{
    int tile = blockIdx.x % 96;
    int b    = blockIdx.x / 96;
    int j0   = tile * 64;
    int tid  = threadIdx.x;
    int wave = tid >> 6, lane = tid & 63;
    int quad = lane >> 4, l16 = lane & 15;

    __shared__ unsigned short Xa[32*520];   // 64 rows x 256 a, A-frag order
    __shared__ unsigned short Wab[32*264];  // 256 a x 32 c, B-frag order

    {   // stage aux rows (clamped)
        int r = tid >> 2, seg = tid & 3;
        int j = j0 + r; if (j > WN-1) j = WN-1;
        const float* ar = aux + ((size_t)b*S + (31 + j))*DA + seg*64;
        int tt = r >> 4, lo = r & 15;
        #pragma unroll
        for (int g = 0; g < 8; ++g) {
            float4 v0 = *(const float4*)(ar + g*8);
            float4 v1 = *(const float4*)(ar + g*8 + 4);
            int d0 = seg*64 + g*8;
            int ks = d0 >> 5, qd = (d0 >> 3) & 3;
            S8U t8;
            t8.e[0]=f2bf(v0.x); t8.e[1]=f2bf(v0.y); t8.e[2]=f2bf(v0.z); t8.e[3]=f2bf(v0.w);
            t8.e[4]=f2bf(v1.x); t8.e[5]=f2bf(v1.y); t8.e[6]=f2bf(v1.z); t8.e[7]=f2bf(v1.w);
            *(short8*)&Xa[(tt*8 + ks)*520 + (qd*16 + lo)*8] = t8.v;
        }
    }

    float wav = wa[0];
    for (int h = 0; h < H; ++h) {
        __syncthreads();
        {   // stage packed B
            const unsigned short* src = wkab + (size_t)h*DA*DAh;
            #pragma unroll
            for (int i = 0; i < 4; ++i) {
                int f = tid + 256*i;
                *(short8*)&Wab[(f >> 5)*264 + (f & 31)*8] = *(const short8*)(src + f*8);
            }
        }
        __syncthreads();
        f32x4 acc[2];
        acc[0] = (f32x4){0.f,0.f,0.f,0.f};
        acc[1] = (f32x4){0.f,0.f,0.f,0.f};
        #pragma unroll
        for (int ks = 0; ks < 8; ++ks) {
            short8 a = *(const short8*)&Xa[(wave*8 + ks)*520 + lane*8];
            #pragma unroll
            for (int nt = 0; nt < 2; ++nt) {
                short8 bf = *(const short8*)&Wab[(ks*4 + quad)*264 + (nt*16 + l16)*8];
                acc[nt] = __builtin_amdgcn_mfma_f32_16x16x32_bf16(a, bf, acc[nt], 0, 0, 0);
            }
        }
        float bk0 = bka[h*DAh + l16], bk1 = bka[h*DAh + 16 + l16];
        float q0 = qahat[(size_t)(b*H + h)*DAh + l16];
        float q1 = qahat[(size_t)(b*H + h)*DAh + 16 + l16];
        #pragma unroll
        for (int reg = 0; reg < 4; ++reg) {
            float v0 = acc[0][reg] + bk0;
            float v1 = acc[1][reg] + bk1;
            float ss = v0*v0 + v1*v1;
            float dp = v0*q0 + v1*q1;
            #pragma unroll
            for (int d2 = 1; d2 <= 8; d2 <<= 1) {
                ss += __shfl_xor(ss, d2);
                dp += __shfl_xor(dp, d2);
            }
            if (l16 == 0) {
                int j = j0 + wave*16 + quad*4 + reg;
                if (j < WN)
                    logits[(size_t)(b*H + h)*WN + j] += wav * dp / fmaxf(sqrtf(ss), EPSN);
            }
        }
    }
}

// ---------------------------------------------------------------------------
// kp v2 (MFMA): same pattern, DP=128, DPh=16 (single n-tile).
__global__ __launch_bounds__(256, 2) void kp_proj_mfma(
    const float* __restrict__ pos, const unsigned short* __restrict__ wkpb,
    const float* __restrict__ bkp, const float* __restrict__ qphat,
    const float* __restrict__ wp, float* __restrict__ logits)
{
    int tile = blockIdx.x % 96;
    int b    = blockIdx.x / 96;
    int j0   = tile * 64;
    int tid  = threadIdx.x;
    int wave = tid >> 6, lane = tid & 63;
    int quad = lane >> 4, l16 = lane & 15;

    __shared__ unsigned short Xp[16*520];   // 64 rows x 128 p
    __shared__ unsigned short Wpb[16*136];  // 128 p x 16 c

    {
        int r = tid >> 2, seg = tid & 3;
        int j = j0 + r; if (j > WN-1) j = WN-1;
        const float* pr = pos + ((size_t)b*S + (31 + j))*DP + seg*32;
        int tt = r >> 4, lo = r & 15;
        #pragma unroll
        for (int g = 0; g < 4; ++g) {
            float4 v0 = *(const float4*)(pr + g*8);
            float4 v1 = *(const float4*)(pr + g*8 + 4);
            int d0 = seg*32 + g*8;
            int ks = d0 >> 5, qd = (d0 >> 3) & 3;
            S8U t8;
            t8.e[0]=f2bf(v0.x); t8.e[1]=f2bf(v0.y); t8.e[2]=f2bf(v0.z); t8.e[3]=f2bf(v0.w);
            t8.e[4]=f2bf(v1.x); t8.e[5]=f2bf(v1.y); t8.e[6]=f2bf(v1.z); t8.e[7]=f2bf(v1.w);
            *(short8*)&Xp[(tt*4 + ks)*520 + (qd*16 + lo)*8] = t8.v;
        }
    }

    float wpv = wp[0];
    for (int h = 0; h < H; ++h) {
        __syncthreads();
        if (tid < 256) {
            int f = tid;
            *(short8*)&Wpb[(f >> 4)*136 + (f & 15)*8] =
                *(const short8*)(wkpb + (size_t)h*DP*DPh + f*8);
        }
        __syncthreads();
        f32x4 acc = (f32x4){0.f,0.f,0.f,0.f};
        #pragma unroll
        for (int ks = 0; ks < 4; ++ks) {
            short8 a = *(const short8*)&Xp[(wave*4 + ks)*520 + lane*8];
            short8 bf = *(const short8*)&Wpb[(ks*4 + quad)*136 + l16*8];
            acc = __builtin_amdgcn_mfma_f32_16x16x32_bf16(a, bf, acc, 0, 0, 0);
        }
        float bk0 = bkp[h*DPh + l16];
        float q0 = qphat[(size_t)(b*H + h)*DPh + l16];
        #pragma unroll
        for (int reg = 0; reg < 4; ++reg) {
            float v = acc[reg] + bk0;
            float ss = v*v;
            float dp = v*q0;
            #pragma unroll
            for (int d2 = 1; d2 <= 8; d2 <<= 1) {
                ss += __shfl_xor(ss, d2);
                dp += __shfl_xor(dp, d2);
            }
            if (l16 == 0) {
                int j = j0 + wave*16 + quad*4 + reg;
                if (j < WN)
                    logits[(size_t)(b*H + h)*WN + j] += wpv * dp / fmaxf(sqrtf(ss), EPSN);
            }
        }
    }
}

// ---------------------------------------------------------------------------
__global__ __launch_bounds__(256) void softmax_k(float* __restrict__ logits,
                                                 float* __restrict__ alast)
{
    int bh = blockIdx.x;
    float* L = logits + (size_t)bh*WN;
    __shared__ float red[256];
    int tid = threadIdx.x;
    float mx = -1e30f;
    for (int j = tid; j < WN; j += 256) mx = fmaxf(mx, L[j]);
    red[tid] = mx; __syncthreads();
    for (int s2 = 128; s2 > 0; s2 >>= 1) {
        if (tid < s2) red[tid] = fmaxf(red[tid], red[tid+s2]);
        __syncthreads();
    }
    mx = red[0]; __syncthreads();
    float sm = 0.f;
    for (int j = tid; j < WN; j += 256) sm += expf(L[j] - mx);
    red[tid] = sm; __syncthreads();
    for (int s2 = 128; s2 > 0; s2 >>= 1) {
        if (tid < s2) red[tid] += red[tid+s2];
        __syncthreads();
    }
    float inv = 1.f / red[0];
    for (int j = tid; j < WN; j += 256) {
        float a = expf(L[j] - mx) * inv;
        L[j] = a;
        if (j == WN-1) alast[bh] = a;
    }
}

// ---------------------------------------------------------------------------
#define JC 191
__global__ __launch_bounds__(256) void xbar_k(
    const float* __restrict__ memory, const float* __restrict__ attn,
    float* __restrict__ xbar)
{
    int chunk = blockIdx.x & 31;
    int b = blockIdx.x >> 5;
    int j0 = chunk * JC;
    __shared__ float al[H][JC];
    int tid = threadIdx.x;
    for (int i = tid; i < H*JC; i += 256) {
        int hh = i / JC, jj = i - hh*JC;
        al[hh][jj] = attn[(size_t)(b*H + hh)*WN + j0 + jj];
    }
    __syncthreads();
    int d0 = tid * 2;
    float acc[H][2];
    #pragma unroll
    for (int hh = 0; hh < H; ++hh) { acc[hh][0] = 0.f; acc[hh][1] = 0.f; }
    for (int jj = 0; jj < JC; ++jj) {
        int t = 31 + j0 + jj;
        const float2 xv = *(const float2*)(memory + ((size_t)b*SM1 + t)*DM + d0);
        #pragma unroll
        for (int hh = 0; hh < H; ++hh) {
            float a = al[hh][jj];
            acc[hh][0] += a * xv.x;
            acc[hh][1] += a * xv.y;
        }
    }
    #pragma unroll
    for (int hh = 0; hh < H; ++hh) {
        atomicAdd(&xbar[(size_t)(b*H+hh)*DM + d0],     acc[hh][0]);
        atomicAdd(&xbar[(size_t)(b*H+hh)*DM + d0 + 1], acc[hh][1]);
    }
}

// ---------------------------------------------------------------------------
__global__ __launch_bounds__(192) void gi_k(
    const float* __restrict__ memory, const float* __restrict__ W_ih,
    const float* __restrict__ b_ih, float* __restrict__ gi_all)
{
    int t = blockIdx.x >> 3;
    int b = blockIdx.x & 7;
    int c = threadIdx.x;
    const float* xr = memory + ((size_t)b*SM1 + (S - M) + t)*DM;
    const float* wr = W_ih + (size_t)c*DM;
    float s = b_ih[c];
    for (int d = 0; d < DM; d += 4) {
        float4 x4 = *(const float4*)(xr + d);
        float4 w4 = *(const float4*)(wr + d);
        s += x4.x*w4.x + x4.y*w4.y + x4.z*w4.z + x4.w*w4.w;
    }
    gi_all[((size_t)t*BB + b)*192 + c] = s;
}

__global__ __launch_bounds__(512) void gru_scan(
    const float* __restrict__ gi_all, const float* __restrict__ W_hh,
    const float* __restrict__ b_hh, float* __restrict__ res)
{
    int b = threadIdx.x >> 6;
    int l = threadIdx.x & 63;

    float w0[64], w1[64], w2[64];
    {
        const float* r0p = W_hh + (size_t)l*DK;
        const float* r1p = W_hh + (size_t)(64 + l)*DK;
        const float* r2p = W_hh + (size_t)(128 + l)*DK;
        #pragma unroll
        for (int i = 0; i < 16; ++i) {
            float4 a = *(const float4*)(r0p + i*4);
            w0[i*4]=a.x; w0[i*4+1]=a.y; w0[i*4+2]=a.z; w0[i*4+3]=a.w;
            float4 c = *(const float4*)(r1p + i*4);
            w1[i*4]=c.x; w1[i*4+1]=c.y; w1[i*4+2]=c.z; w1[i*4+3]=c.w;
            float4 e = *(const float4*)(r2p + i*4);
            w2[i*4]=e.x; w2[i*4+1]=e.y; w2[i*4+2]=e.z; w2[i*4+3]=e.w;
        }
    }
    float bh0 = b_hh[l], bh1 = b_hh[64 + l], bh2 = b_hh[128 + l];

    float h = 0.f;
    const float* g0 = gi_all + (size_t)b*192;
    float gr = g0[l], gz = g0[64 + l], gn = g0[128 + l];

    #pragma unroll 1
    for (int t = 0; t < 31; ++t) {
        float a0 = bh0, a1 = bh1, a2 = bh2;
        #pragma unroll
        for (int k = 0; k < 64; ++k) {
            float hk = __int_as_float(__builtin_amdgcn_readlane(__float_as_int(h), k));
            a0 += hk * w0[k];
            a1 += hk * w1[k];
            a2 += hk * w2[k];
        }
        float ngr = 0.f, ngz = 0.f, ngn = 0.f;
        if (t < 30) {
            const float* g2 = gi_all + ((size_t)(t+1)*BB + b)*192;
            ngr = g2[l]; ngz = g2[64 + l]; ngn = g2[128 + l];
        }
        float r = 1.f / (1.f + expf(-(gr + a0)));
        float z = 1.f / (1.f + expf(-(gz + a1)));
        float n = tanhf(gn + r * a2);
        h = (1.f - z)*n + z*h;
        gr = ngr; gz = ngz; gn = ngn;
    }
    res[b*DK + l] = h;
}

// ---------------------------------------------------------------------------
__global__ __launch_bounds__(512) void final_k(
    const float* __restrict__ x_pre, const float* __restrict__ xbar,
    const float* __restrict__ Wv, const float* __restrict__ bv,
    const float* __restrict__ WO, const float* __restrict__ bO,
    const float* __restrict__ alast, const float* __restrict__ res,
    const int* __restrict__ G, float* __restrict__ out)
{
    int b = blockIdx.x;
    int tid = threadIdx.x;
    __shared__ float gl[64*64];
    __shared__ float deta[512];
    for (int i = tid; i < 4096; i += 512) gl[i] = (float)G[(i & 63)*64 + (i >> 6)];
    __syncthreads();
    int h = tid >> 6, dk = tid & 63;
    float ala = alast[b*H + h];
    const float* xb  = xbar + (size_t)(b*H + h)*DM;
    const float* wvr = Wv + (size_t)tid*DM;
    const float* gcol = gl + dk;
    float s = 0.f;
    for (int e = 0; e < DM; e += 4) {
        float4 wv4 = *(const float4*)(wvr + e);
        float4 xb4 = *(const float4*)(xb + e);
        int eb = e & 63;
        s += wv4.x*gcol[eb*64]     *xb4.x + wv4.y*gcol[(eb+1)*64]*xb4.y
           + wv4.z*gcol[(eb+2)*64]*xb4.z + wv4.w*gcol[(eb+3)*64]*xb4.w;
    }
    float hist = s + bv[tid]*(1.f - ala);
    deta[tid] = hist + ala * res[b*DK + dk];
    __syncthreads();
    int dpos = tid;
    const float* wor = WO + (size_t)dpos*DM;
    const float* gcol2 = gl + (dpos & 63);
    float o = 0.f;
    for (int jj = 0; jj < DM; jj += 4) {
        float4 wo4 = *(const float4*)(wor + jj);
        int jb = jj & 63;
        o += wo4.x*gcol2[jb*64]     *deta[jj]   + wo4.y*gcol2[(jb+1)*64]*deta[jj+1]
           + wo4.z*gcol2[(jb+2)*64]*deta[jj+2] + wo4.w*gcol2[(jb+3)*64]*deta[jj+3];
    }
    out[(size_t)b*DM + dpos] = x_pre[(size_t)b*DM + dpos] + o + bO[dpos];
}

// ---------------------------------------------------------------------------
extern "C" void kernel_launch(void* const* d_in, const int* in_sizes, int n_in,
                              void* d_out, int out_size, void* d_ws, size_t ws_size,
                              hipStream_t stream)
{
    const float* memory = (const float*)d_in[0];
    const float* x_pre  = (const float*)d_in[1];
    const float* aux    = (const float*)d_in[2];
    const float* pos    = (const float*)d_in[3];
    const float* Wq  = (const float*)d_in[4];
    const float* bq  = (const float*)d_in[5];
    const float* Wk  = (const float*)d_in[6];
    const float* bk  = (const float*)d_in[7];
    const float* Wv  = (const float*)d_in[8];
    const float* bv  = (const float*)d_in[9];
    const float* Wqa = (const float*)d_in[10];
    const float* bqa = (const float*)d_in[11];
    const float* Wka = (const float*)d_in[12];
    const float* bka = (const float*)d_in[13];
    const float* Wqp = (const float*)d_in[14];
    const float* bqp = (const float*)d_in[15];
    const float* Wkp = (const float*)d_in[16];
    const float* bkp = (const float*)d_in[17];
    const float* W_ih = (const float*)d_in[18];
    const float* W_hh = (const float*)d_in[19];
    const float* b_ih = (const float*)d_in[20];
    const float* b_hh = (const float*)d_in[21];
    const float* WO  = (const float*)d_in[22];
    const float* bO  = (const float*)d_in[23];
    const float* w   = (const float*)d_in[24];
    const float* w_a = (const float*)d_in[25];
    const float* w_p = (const float*)d_in[26];
    const int*   G   = (const int*)d_in[27];
    (void)in_sizes; (void)n_in; (void)out_size; (void)ws_size;

    float* ws = (float*)d_ws;
    unsigned short* wkb  = (unsigned short*)(ws + WS_WKT);
    unsigned short* wkab = (unsigned short*)(ws + WS_WKAT);
    unsigned short* wkpb = (unsigned short*)(ws + WS_WKPT);
    float* qhat   = ws + WS_QHAT;
    float* qahat  = ws + WS_QAHAT;
    float* qphat  = ws + WS_QPHAT;
    float* logits = ws + WS_LOGITS;
    float* xbar   = ws + WS_XBAR;
    float* alast  = ws + WS_ALAST;
    float* resb   = ws + WS_RES;
    float* gi_all = ws + WS_GI;
    float* wqm    = ws + WS_WQM;
    float* outp   = (float*)d_out;

    hipMemsetAsync(logits, 0, (size_t)(N_LOGITS + N_XBAR)*sizeof(float), stream);

    prep_weights<<<(H*DM*DK + H*DA*DAh + H*DP*DPh + H*DK*DM + 255)/256, 256, 0, stream>>>(
        Wk, Wka, Wkp, Wq, G, wkb, wkab, wkpb, wqm);

    gi_k<<<31*BB, 192, 0, stream>>>(memory, W_ih, b_ih, gi_all);
    gru_scan<<<1, 512, 0, stream>>>(gi_all, W_hh, b_hh, resb);

    qhat_k<<<BB*H, 256, 0, stream>>>(memory, x_pre, aux, pos, wqm, bq, Wqa, bqa,
                                     Wqp, bqp, qhat, qahat, qphat);

    kproj_band_mfma2<<<48*BB*4, 256, 0, stream>>>(memory, x_pre, wkb, bk, qhat,
                                                  w, logits);

    ka_proj_mfma<<<BB*96, 256, 0, stream>>>(aux, wkab, bka, qahat, w_a, logits);
    kp_proj_mfma<<<BB*96, 256, 0, stream>>>(pos, wkpb, bkp, qphat, w_p, logits);

    softmax_k<<<BB*H, 256, 0, stream>>>(logits, alast);

    xbar_k<<<BB*32, 256, 0, stream>>>(memory, logits, xbar);

    final_k<<<BB, 512, 0, stream>>>(x_pre, xbar, Wv, bv, WO, bO, alast, resb, G, outp);
}

// Round 6
// 743.618 us; speedup vs baseline: 3.7399x; 1.0194x over previous
//
#include <hip/hip_runtime.h>
#include <math.h>

// ---- problem constants (fixed by setup_inputs) ----
#define BB   8
#define S    6144
#define SM1  6143          // memory rows; x[:,SM1,:] == x_pre
#define DM   512
#define H    8
#define DK   64
#define M    32
#define WN   6113          // k + T - M + 1
#define DA   256
#define DAh  32
#define DP   128
#define DPh  16
#define EPSN 1e-12f

// ---- workspace layout (float offsets) ----
#define WS_WKT    0                       // H*DM*DK bf16 packed Wk
#define WS_WKAT   262144                  // H*DA*DAh bf16 packed Wka
#define WS_WKPT   327680                  // H*DP*DPh bf16 packed Wkp
#define WS_QHAT   344064                  // B*H*M*DK fp32
#define WS_QAHAT  475136
#define WS_QPHAT  477184
#define WS_LOGITS 478208                  // B*H*WN
#define WS_XBAR   869440                  // B*H*DM
#define WS_ALAST  902208
#define WS_RES    902272
#define WS_GI     902784
#define WS_WQM    950400                  // H*DK*DM masked Wq fp32
#define WS_XBF    1212544                 // B*S*DM bf16 = 12582912 float-slots
#define N_LOGITS  391232
#define N_XBAR    32768

typedef __attribute__((ext_vector_type(8))) short short8;
typedef __attribute__((ext_vector_type(4))) float f32x4;

__device__ inline unsigned short f2bf(float f) {
    union { float f; unsigned u; } v; v.f = f;
    unsigned r = v.u + 0x7fffu + ((v.u >> 16) & 1u);   // RNE
    return (unsigned short)(r >> 16);
}
__device__ inline float bf2f(unsigned short u) {
    union { unsigned u; float f; } v; v.u = ((unsigned)u) << 16; return v.f;
}

union S8U { short8 v; unsigned short e[8]; };

// ---------------------------------------------------------------------------
__global__ void prep_weights(const float* __restrict__ Wk, const float* __restrict__ Wka,
                             const float* __restrict__ Wkp, const float* __restrict__ Wq,
                             const int* __restrict__ G,
                             unsigned short* __restrict__ wkb,
                             unsigned short* __restrict__ wkab,
                             unsigned short* __restrict__ wkpb,
                             float* __restrict__ wqm)
{
    int idx = blockIdx.x * 256 + threadIdx.x;
    if (idx < H*DM*DK) {
        int k = idx & 63; int d = (idx >> 6) & 511; int h = idx >> 15;
        float v = Wk[(size_t)(h*DK + k)*DM + d] * (float)G[k*DK + (d & 63)];
        wkb[(size_t)h*DM*DK + (((d >> 3)*DK + k) << 3) + (d & 7)] = f2bf(v);
    }
    int i2 = idx - H*DM*DK;
    if (i2 >= 0 && i2 < H*DA*DAh) {
        int h = i2 >> 13; int r = i2 & 8191;
        int j = r & 7; int f = r >> 3;
        int c = f & 31; int a = (f >> 5)*8 + j;
        wkab[i2] = f2bf(Wka[(size_t)(h*DAh + c)*DA + a]);
    }
    int i3 = idx - H*DM*DK - H*DA*DAh;
    if (i3 >= 0 && i3 < H*DP*DPh) {
        int h = i3 >> 11; int r = i3 & 2047;
        int j = r & 7; int f = r >> 3;
        int c = f & 15; int p = (f >> 4)*8 + j;
        wkpb[i3] = f2bf(Wkp[(size_t)(h*DPh + c)*DP + p]);
    }
    int i4 = idx - H*DM*DK - H*DA*DAh - H*DP*DPh;
    if (i4 >= 0 && i4 < H*DK*DM) {
        int d = i4 & 511; int k = (i4 >> 9) & 63;
        wqm[i4] = Wq[i4] * (float)G[k*DK + (d & 63)];
    }
}

// ---------------------------------------------------------------------------
// xcast: x (memory ++ x_pre) fp32 -> bf16 copy xbf[b][t][d]
__global__ __launch_bounds__(256) void xcast_k(
    const float* __restrict__ memory, const float* __restrict__ x_pre,
    unsigned short* __restrict__ xbf)
{
    size_t e = ((size_t)blockIdx.x*256 + threadIdx.x)*8;
    int b = (int)(e / ((size_t)S*DM));
    size_t r = e - (size_t)b*S*DM;
    int t = (int)(r >> 9);
    int d = (int)(r & 511);
    const float* src = (t < SM1) ? memory + ((size_t)b*SM1 + t)*DM + d
                                 : x_pre + (size_t)b*DM + d;
    float4 v0 = *(const float4*)src, v1 = *(const float4*)(src + 4);
    S8U t8;
    t8.e[0]=f2bf(v0.x); t8.e[1]=f2bf(v0.y); t8.e[2]=f2bf(v0.z); t8.e[3]=f2bf(v0.w);
    t8.e[4]=f2bf(v1.x); t8.e[5]=f2bf(v1.y); t8.e[6]=f2bf(v1.z); t8.e[7]=f2bf(v1.w);
    *(short8*)(xbf + e) = t8.v;
}

// ---------------------------------------------------------------------------
__global__ __launch_bounds__(256) void qhat_k(
    const float* __restrict__ memory, const float* __restrict__ x_pre,
    const float* __restrict__ aux, const float* __restrict__ pos,
    const float* __restrict__ wqm, const float* __restrict__ bq,
    const float* __restrict__ Wqa, const float* __restrict__ bqa,
    const float* __restrict__ Wqp, const float* __restrict__ bqp,
    float* __restrict__ qhat, float* __restrict__ qahat, float* __restrict__ qphat)
{
    int bh = blockIdx.x; int b = bh >> 3, h = bh & 7;
    int tid = threadIdx.x;
    __shared__ float q[M][DK];
    __shared__ float nrm[M];
    __shared__ float qa[DAh];
    __shared__ float qp[DPh];

    int k = tid & 63;
    int mg = tid >> 6;
    const float* wr = wqm + (size_t)(h*DK + k)*DM;
    for (int mp = 0; mp < 8; ++mp) {
        int m = mp*4 + mg;
        int t = S - M + m;
        const float* xr = (t < SM1) ? (memory + ((size_t)b*SM1 + t)*DM)
                                    : (x_pre + (size_t)b*DM);
        float s = 0.f;
        for (int d = 0; d < DM; d += 4) {
            float4 x4 = *(const float4*)(xr + d);
            float4 w4 = *(const float4*)(wr + d);
            s += x4.x*w4.x + x4.y*w4.y + x4.z*w4.z + x4.w*w4.w;
        }
        q[m][k] = s + bq[h*DK + k];
    }
    if (tid < DAh) {
        int c = tid;
        const float* ar = aux + ((size_t)b*S + (S-1))*DA;
        const float* wv = Wqa + (size_t)(h*DAh + c)*DA;
        float s = 0.f;
        for (int a = 0; a < DA; ++a) s += ar[a]*wv[a];
        qa[c] = s + bqa[h*DAh + c];
    }
    if (tid >= 64 && tid < 64 + DPh) {
        int c = tid - 64;
        const float* pr = pos + ((size_t)b*S + (S-1))*DP;
        const float* wv = Wqp + (size_t)(h*DPh + c)*DP;
        float s = 0.f;
        for (int p2 = 0; p2 < DP; ++p2) s += pr[p2]*wv[p2];
        qp[c] = s + bqp[h*DPh + c];
    }
    __syncthreads();
    if (tid < M) {
        float s = 0.f;
        for (int kk = 0; kk < DK; ++kk) { float v = q[tid][kk]; s += v*v; }
        nrm[tid] = fmaxf(sqrtf(s), EPSN);
    }
    __syncthreads();
    for (int i = tid; i < M*DK; i += 256) {
        int m = i >> 6, kk = i & 63;
        qhat[(size_t)bh*M*DK + i] = q[m][kk] / nrm[m];
    }
    if (tid < DAh) {
        float s = 0.f;
        for (int c = 0; c < DAh; ++c) s += qa[c]*qa[c];
        qahat[(size_t)bh*DAh + tid] = qa[tid] / fmaxf(sqrtf(s), EPSN);
    }
    if (tid < DPh) {
        float s = 0.f;
        for (int c = 0; c < DPh; ++c) s += qp[c]*qp[c];
        qphat[(size_t)bh*DPh + tid] = qp[tid] / fmaxf(sqrtf(s), EPSN);
    }
}

// ---------------------------------------------------------------------------
// kproj v3: A-frags direct from global bf16 xbf, B-frags direct from packed
// wkb. Zero barriers in the K-loop; tiny LDS (Qs/Kb/tnloc); fused norm+band.
// Grid (b, h, tile64), 4 waves x 16 rows.
__global__ __launch_bounds__(256, 4) void kproj_mfma3(
    const unsigned short* __restrict__ xbf, const unsigned short* __restrict__ wkb,
    const float* __restrict__ bk, const float* __restrict__ qhat,
    const float* __restrict__ wscal, float* __restrict__ logits)
{
    int bx = blockIdx.x;
    int tile = bx % 96, h = (bx / 96) & 7, b = bx / (96*8);
    int t0 = tile * 64;
    int tid = threadIdx.x;
    int wave = tid >> 6, lane = tid & 63;
    int quad = lane >> 4, l16 = lane & 15;

    __shared__ unsigned short Qs[M][72];
    __shared__ unsigned short Kb[64][72];
    __shared__ float tnloc[95];

    {   // stage Qs bf16
        const float* qsrc = qhat + (size_t)(b*H + h)*M*DK;
        int i = tid * 8;
        float4 a0 = *(const float4*)(qsrc + i);
        float4 a1 = *(const float4*)(qsrc + i + 4);
        S8U t8;
        t8.e[0]=f2bf(a0.x); t8.e[1]=f2bf(a0.y); t8.e[2]=f2bf(a0.z); t8.e[3]=f2bf(a0.w);
        t8.e[4]=f2bf(a1.x); t8.e[5]=f2bf(a1.y); t8.e[6]=f2bf(a1.z); t8.e[7]=f2bf(a1.w);
        *(short8*)&Qs[i >> 6][i & 63] = t8.v;
    }
    if (tid < 95) tnloc[tid] = 0.f;

    f32x4 acc[4];
    #pragma unroll
    for (int nt = 0; nt < 4; ++nt) acc[nt] = (f32x4){0.f,0.f,0.f,0.f};

    const unsigned short* xrow = xbf + ((size_t)b*S + t0 + wave*16 + l16)*DM;
    const unsigned short* wh = wkb + (size_t)h*DM*DK;

    #pragma unroll
    for (int ch = 0; ch < 4; ++ch) {
        #pragma unroll
        for (int ks = 0; ks < 4; ++ks) {
            short8 a = *(const short8*)(xrow + ch*128 + ks*32 + quad*8);
            #pragma unroll
            for (int nt = 0; nt < 4; ++nt) {
                short8 bf = *(const short8*)(wh + (((ch*16 + ks*4 + quad)*DK) + nt*16 + l16)*8);
                acc[nt] = __builtin_amdgcn_mfma_f32_16x16x32_bf16(a, bf, acc[nt], 0, 0, 0);
            }
        }
    }

    {   // bias + row l2-norm (butterfly over 16-lane quad group) + bf16 Kb
        float vv[4][4];
        float ss[4] = {0.f, 0.f, 0.f, 0.f};
        #pragma unroll
        for (int nt = 0; nt < 4; ++nt) {
            float bkv = bk[h*DK + nt*16 + l16];
            #pragma unroll
            for (int reg = 0; reg < 4; ++reg) {
                float v = acc[nt][reg] + bkv;
                vv[nt][reg] = v;
                ss[reg] += v*v;
            }
        }
        #pragma unroll
        for (int d2 = 1; d2 <= 8; d2 <<= 1)
            #pragma unroll
            for (int reg = 0; reg < 4; ++reg) ss[reg] += __shfl_xor(ss[reg], d2);
        #pragma unroll
        for (int reg = 0; reg < 4; ++reg) {
            float inv = 1.f / fmaxf(sqrtf(ss[reg]), EPSN);
            #pragma unroll
            for (int nt = 0; nt < 4; ++nt)
                Kb[wave*16 + quad*4 + reg][nt*16 + l16] = f2bf(vv[nt][reg] * inv);
        }
    }
    __syncthreads();

    {   // banded Q.K^T: 32 m-rows x 64 t-cols; per-diagonal LDS scatter
        int mtile = wave & 1;
        int thalf = (wave >> 1) * 32;
        f32x4 acc2[2];
        acc2[0] = (f32x4){0.f,0.f,0.f,0.f};
        acc2[1] = (f32x4){0.f,0.f,0.f,0.f};
        #pragma unroll
        for (int ks = 0; ks < 2; ++ks) {
            short8 a = *(const short8*)&Qs[mtile*16 + l16][ks*32 + quad*8];
            #pragma unroll
            for (int nt = 0; nt < 2; ++nt) {
                short8 kf = *(const short8*)&Kb[thalf + nt*16 + l16][ks*32 + quad*8];
                acc2[nt] = __builtin_amdgcn_mfma_f32_16x16x32_bf16(a, kf, acc2[nt], 0, 0, 0);
            }
        }
        int m0 = mtile*16 + quad*4;
        #pragma unroll
        for (int nt = 0; nt < 2; ++nt) {
            int tl = thalf + nt*16 + l16;
            #pragma unroll
            for (int reg = 0; reg < 4; ++reg) {
                int mm = m0 + reg;
                int j = t0 + tl - mm;
                if (j >= 0 && j < WN)
                    atomicAdd(&tnloc[tl - mm + 31], acc2[nt][reg]);
            }
        }
    }
    __syncthreads();
    if (tid < 95) {
        int j = t0 + tid - 31;
        if (j >= 0 && j < WN)
            atomicAdd(&logits[(size_t)(b*H + h)*WN + j], wscal[0]*(1.f/32.f)*tnloc[tid]);
    }
}

// ---------------------------------------------------------------------------
// ka v3: aux A-frags staged once in LDS; B-frags DIRECT from packed global
// (L2-hot) -> zero barriers in the head loop.
__global__ __launch_bounds__(256, 2) void ka_proj_mfma(
    const float* __restrict__ aux, const unsigned short* __restrict__ wkab,
    const float* __restrict__ bka, const float* __restrict__ qahat,
    const float* __restrict__ wa, float* __restrict__ logits)
{
    int tile = blockIdx.x % 96;
    int b    = blockIdx.x / 96;
    int j0   = tile * 64;
    int tid  = threadIdx.x;
    int wave = tid >> 6, lane = tid & 63;
    int quad = lane >> 4, l16 = lane & 15;

    __shared__ unsigned short Xa[32*520];

    {   // stage aux rows (clamped)
        int r = tid >> 2, seg = tid & 3;
        int j = j0 + r; if (j > WN-1) j = WN-1;
        const float* ar = aux + ((size_t)b*S + (31 + j))*DA + seg*64;
        int tt = r >> 4, lo = r & 15;
        #pragma unroll
        for (int g = 0; g < 8; ++g) {
            float4 v0 = *(const float4*)(ar + g*8);
            float4 v1 = *(const float4*)(ar + g*8 + 4);
            int d0 = seg*64 + g*8;
            int ks = d0 >> 5, qd = (d0 >> 3) & 3;
            S8U t8;
            t8.e[0]=f2bf(v0.x); t8.e[1]=f2bf(v0.y); t8.e[2]=f2bf(v0.z); t8.e[3]=f2bf(v0.w);
            t8.e[4]=f2bf(v1.x); t8.e[5]=f2bf(v1.y); t8.e[6]=f2bf(v1.z); t8.e[7]=f2bf(v1.w);
            *(short8*)&Xa[(tt*8 + ks)*520 + (qd*16 + lo)*8] = t8.v;
        }
    }
    __syncthreads();

    float wav = wa[0];
    for (int h = 0; h < H; ++h) {
        const unsigned short* wsrc = wkab + (size_t)h*DA*DAh;
        f32x4 acc[2];
        acc[0] = (f32x4){0.f,0.f,0.f,0.f};
        acc[1] = (f32x4){0.f,0.f,0.f,0.f};
        #pragma unroll
        for (int ks = 0; ks < 8; ++ks) {
            short8 a = *(const short8*)&Xa[(wave*8 + ks)*520 + lane*8];
            #pragma unroll
            for (int nt = 0; nt < 2; ++nt) {
                short8 bf = *(const short8*)(wsrc + (size_t)(((ks*4 + quad)*32) + nt*16 + l16)*8);
                acc[nt] = __builtin_amdgcn_mfma_f32_16x16x32_bf16(a, bf, acc[nt], 0, 0, 0);
            }
        }
        float bk0 = bka[h*DAh + l16], bk1 = bka[h*DAh + 16 + l16];
        float q0 = qahat[(size_t)(b*H + h)*DAh + l16];
        float q1 = qahat[(size_t)(b*H + h)*DAh + 16 + l16];
        #pragma unroll
        for (int reg = 0; reg < 4; ++reg) {
            float v0 = acc[0][reg] + bk0;
            float v1 = acc[1][reg] + bk1;
            float ss = v0*v0 + v1*v1;
            float dp = v0*q0 + v1*q1;
            #pragma unroll
            for (int d2 = 1; d2 <= 8; d2 <<= 1) {
                ss += __shfl_xor(ss, d2);
                dp += __shfl_xor(dp, d2);
            }
            if (l16 == 0) {
                int j = j0 + wave*16 + quad*4 + reg;
                if (j < WN)
                    logits[(size_t)(b*H + h)*WN + j] += wav * dp / fmaxf(sqrtf(ss), EPSN);
            }
        }
    }
}

// ---------------------------------------------------------------------------
// kp v3: same pattern, direct-global B.
__global__ __launch_bounds__(256, 2) void kp_proj_mfma(
    const float* __restrict__ pos, const unsigned short* __restrict__ wkpb,
    const float* __restrict__ bkp, const float* __restrict__ qphat,
    const float* __restrict__ wp, float* __restrict__ logits)
{
    int tile = blockIdx.x % 96;
    int b    = blockIdx.x / 96;
    int j0   = tile * 64;
    int tid  = threadIdx.x;
    int wave = tid >> 6, lane = tid & 63;
    int quad = lane >> 4, l16 = lane & 15;

    __shared__ unsigned short Xp[16*520];

    {
        int r = tid >> 2, seg = tid & 3;
        int j = j0 + r; if (j > WN-1) j = WN-1;
        const float* pr = pos + ((size_t)b*S + (31 + j))*DP + seg*32;
        int tt = r >> 4, lo = r & 15;
        #pragma unroll
        for (int g = 0; g < 4; ++g) {
            float4 v0 = *(const float4*)(pr + g*8);
            float4 v1 = *(const float4*)(pr + g*8 + 4);
            int d0 = seg*32 + g*8;
            int ks = d0 >> 5, qd = (d0 >> 3) & 3;
            S8U t8;
            t8.e[0]=f2bf(v0.x); t8.e[1]=f2bf(v0.y); t8.e[2]=f2bf(v0.z); t8.e[3]=f2bf(v0.w);
            t8.e[4]=f2bf(v1.x); t8.e[5]=f2bf(v1.y); t8.e[6]=f2bf(v1.z); t8.e[7]=f2bf(v1.w);
            *(short8*)&Xp[(tt*4 + ks)*520 + (qd*16 + lo)*8] = t8.v;
        }
    }
    __syncthreads();

    float wpv = wp[0];
    for (int h = 0; h < H; ++h) {
        const unsigned short* wsrc = wkpb + (size_t)h*DP*DPh;
        f32x4 acc = (f32x4){0.f,0.f,0.f,0.f};
        #pragma unroll
        for (int ks = 0; ks < 4; ++ks) {
            short8 a = *(const short8*)&Xp[(wave*4 + ks)*520 + lane*8];
            short8 bf = *(const short8*)(wsrc + (size_t)(((ks*4 + quad)*16) + l16)*8);
            acc = __builtin_amdgcn_mfma_f32_16x16x32_bf16(a, bf, acc, 0, 0, 0);
        }
        float bk0 = bkp[h*DPh + l16];
        float q0 = qphat[(size_t)(b*H + h)*DPh + l16];
        #pragma unroll
        for (int reg = 0; reg < 4; ++reg) {
            float v = acc[reg] + bk0;
            float ss = v*v;
            float dp = v*q0;
            #pragma unroll
            for (int d2 = 1; d2 <= 8; d2 <<= 1) {
                ss += __shfl_xor(ss, d2);
                dp += __shfl_xor(dp, d2);
            }
            if (l16 == 0) {
                int j = j0 + wave*16 + quad*4 + reg;
                if (j < WN)
                    logits[(size_t)(b*H + h)*WN + j] += wpv * dp / fmaxf(sqrtf(ss), EPSN);
            }
        }
    }
}

// ---------------------------------------------------------------------------
// OLD kproj (fallback when workspace too small for xbf)
__global__ __launch_bounds__(256, 2) void kproj_band_mfma2(
    const float* __restrict__ memory, const float* __restrict__ x_pre,
    const unsigned short* __restrict__ wkb, const float* __restrict__ bk,
    const float* __restrict__ qhat, const float* __restrict__ wscal,
    float* __restrict__ logits)
{
    int bx = blockIdx.x;
    int hp = bx & 3, b = (bx >> 2) & 7, tile = bx >> 5;
    int t0 = tile * 128;
    int tid = threadIdx.x;
    int wave = tid >> 6, lane = tid & 63;
    int quad = lane >> 4, l16 = lane & 15;

    __shared__ unsigned short Xf[32*520];
    __shared__ unsigned short Wf[16*520];
    __shared__ unsigned short Kb[128][72];
    __shared__ unsigned short Qs[M][72];
    __shared__ float tnloc[159];

    if (tid < 159) tnloc[tid] = 0.f;
    {
        int h = hp*2;
        const float* qsrc = qhat + (size_t)(b*H + h)*M*DK;
        int i = tid * 8;
        float4 a0 = *(const float4*)(qsrc + i);
        float4 a1 = *(const float4*)(qsrc + i + 4);
        S8U t8;
        t8.e[0]=f2bf(a0.x); t8.e[1]=f2bf(a0.y); t8.e[2]=f2bf(a0.z); t8.e[3]=f2bf(a0.w);
        t8.e[4]=f2bf(a1.x); t8.e[5]=f2bf(a1.y); t8.e[6]=f2bf(a1.z); t8.e[7]=f2bf(a1.w);
        *(short8*)&Qs[i >> 6][i & 63] = t8.v;
    }

    f32x4 acc[2][2][4];
    #pragma unroll
    for (int hi = 0; hi < 2; ++hi)
        #pragma unroll
        for (int mt = 0; mt < 2; ++mt)
            #pragma unroll
            for (int nt = 0; nt < 4; ++nt) acc[hi][mt][nt] = (f32x4){0.f,0.f,0.f,0.f};

    for (int ch = 0; ch < 4; ++ch) {
        __syncthreads();
        {
            int r = tid >> 1, half = tid & 1;
            int t = t0 + r;
            const float* xr = ((t < SM1) ? (memory + ((size_t)b*SM1 + t)*DM)
                                         : (x_pre + (size_t)b*DM)) + ch*128 + half*64;
            int tt = r >> 4, lo = r & 15;
            #pragma unroll
            for (int g = 0; g < 8; ++g) {
                float4 v0 = *(const float4*)(xr + g*8);
                float4 v1 = *(const float4*)(xr + g*8 + 4);
                int d0 = half*64 + g*8;
                int ks = d0 >> 5, qd = (d0 >> 3) & 3;
                S8U t8;
                t8.e[0]=f2bf(v0.x); t8.e[1]=f2bf(v0.y); t8.e[2]=f2bf(v0.z); t8.e[3]=f2bf(v0.w);
                t8.e[4]=f2bf(v1.x); t8.e[5]=f2bf(v1.y); t8.e[6]=f2bf(v1.z); t8.e[7]=f2bf(v1.w);
                *(short8*)&Xf[(tt*4 + ks)*520 + (qd*16 + lo)*8] = t8.v;
            }
        }
        {
            const unsigned short* src = wkb + (size_t)(hp*2)*DM*DK + (size_t)ch*8192;
            #pragma unroll
            for (int i = 0; i < 4; ++i) {
                int f = tid + 256*i;
                *(short8*)&Wf[(f >> 6)*520 + (f & 63)*8] = *(const short8*)(src + f*8);
            }
        }
        __syncthreads();
        #pragma unroll
        for (int ks = 0; ks < 4; ++ks) {
            short8 a0 = *(const short8*)&Xf[((wave*2 + 0)*4 + ks)*520 + lane*8];
            short8 a1 = *(const short8*)&Xf[((wave*2 + 1)*4 + ks)*520 + lane*8];
            #pragma unroll
            for (int nt = 0; nt < 4; ++nt) {
                short8 bf = *(const short8*)&Wf[(ks*4 + quad)*520 + (nt*16 + l16)*8];
                acc[0][0][nt] = __builtin_amdgcn_mfma_f32_16x16x32_bf16(a0, bf, acc[0][0][nt], 0, 0, 0);
                acc[0][1][nt] = __builtin_amdgcn_mfma_f32_16x16x32_bf16(a1, bf, acc[0][1][nt], 0, 0, 0);
            }
        }
        __syncthreads();
        {
            const unsigned short* src = wkb + (size_t)(hp*2 + 1)*DM*DK + (size_t)ch*8192;
            #pragma unroll
            for (int i = 0; i < 4; ++i) {
                int f = tid + 256*i;
                *(short8*)&Wf[(f >> 6)*520 + (f & 63)*8] = *(const short8*)(src + f*8);
            }
        }
        __syncthreads();
        #pragma unroll
        for (int ks = 0; ks < 4; ++ks) {
            short8 a0 = *(const short8*)&Xf[((wave*2 + 0)*4 + ks)*520 + lane*8];
            short8 a1 = *(const short8*)&Xf[((wave*2 + 1)*4 + ks)*520 + lane*8];
            #pragma unroll
            for (int nt = 0; nt < 4; ++nt) {
                short8 bf = *(const short8*)&Wf[(ks*4 + quad)*520 + (nt*16 + l16)*8];
                acc[1][0][nt] = __builtin_amdgcn_mfma_f32_16x16x32_bf16(a0, bf, acc[1][0][nt], 0, 0, 0);
                acc[1][1][nt] = __builtin_amdgcn_mfma_f32_16x16x32_bf16(a1, bf, acc[1][1][nt], 0, 0, 0);
            }
        }
    }

    float wom = wscal[0] * (1.f/32.f);

    for (int hi = 0; hi < 2; ++hi) {
        int h = hp*2 + hi;
        __syncthreads();
        {
            float ss[2][4];
            float vv[2][4][4];
            #pragma unroll
            for (int mt = 0; mt < 2; ++mt)
                #pragma unroll
                for (int reg = 0; reg < 4; ++reg) ss[mt][reg] = 0.f;
            #pragma unroll
            for (int nt = 0; nt < 4; ++nt) {
                float bkv = bk[h*DK + nt*16 + l16];
                #pragma unroll
                for (int mt = 0; mt < 2; ++mt)
                    #pragma unroll
                    for (int reg = 0; reg < 4; ++reg) {
                        float v = acc[hi][mt][nt][reg] + bkv;
                        vv[mt][nt][reg] = v;
                        ss[mt][reg] += v*v;
                    }
            }
            #pragma unroll
            for (int d2 = 1; d2 <= 8; d2 <<= 1)
                #pragma unroll
                for (int mt = 0; mt < 2; ++mt)
                    #pragma unroll
                    for (int reg = 0; reg < 4; ++reg)
                        ss[mt][reg] += __shfl_xor(ss[mt][reg], d2);
            #pragma unroll
            for (int mt = 0; mt < 2; ++mt) {
                float inv[4];
                #pragma unroll
                for (int reg = 0; reg < 4; ++reg)
                    inv[reg] = 1.f / fmaxf(sqrtf(ss[mt][reg]), EPSN);
                #pragma unroll
                for (int nt = 0; nt < 4; ++nt)
                    #pragma unroll
                    for (int reg = 0; reg < 4; ++reg)
                        Kb[wave*32 + mt*16 + quad*4 + reg][nt*16 + l16] =
                            f2bf(vv[mt][nt][reg] * inv[reg]);
            }
        }
        __syncthreads();
        {
            f32x4 acc2[2][2];
            #pragma unroll
            for (int mt = 0; mt < 2; ++mt)
                #pragma unroll
                for (int nt = 0; nt < 2; ++nt) acc2[mt][nt] = (f32x4){0.f,0.f,0.f,0.f};
            #pragma unroll
            for (int ks = 0; ks < 2; ++ks) {
                short8 qa0 = *(const short8*)&Qs[l16     ][ks*32 + quad*8];
                short8 qa1 = *(const short8*)&Qs[16 + l16][ks*32 + quad*8];
                #pragma unroll
                for (int nt = 0; nt < 2; ++nt) {
                    short8 kf = *(const short8*)&Kb[wave*32 + nt*16 + l16][ks*32 + quad*8];
                    acc2[0][nt] = __builtin_amdgcn_mfma_f32_16x16x32_bf16(qa0, kf, acc2[0][nt], 0, 0, 0);
                    acc2[1][nt] = __builtin_amdgcn_mfma_f32_16x16x32_bf16(qa1, kf, acc2[1][nt], 0, 0, 0);
                }
            }
            #pragma unroll
            for (int mt = 0; mt < 2; ++mt)
                #pragma unroll
                for (int nt = 0; nt < 2; ++nt) {
                    int tcol = wave*32 + nt*16 + l16;
                    #pragma unroll
                    for (int reg = 0; reg < 4; ++reg) {
                        int m = mt*16 + quad*4 + reg;
                        int j = t0 + tcol - m;
                        if (j >= 0 && j < WN)
                            atomicAdd(&tnloc[tcol - m + 31], acc2[mt][nt][reg]);
                    }
                }
        }
        __syncthreads();
        if (tid < 159) {
            int j = t0 + tid - 31;
            if (j >= 0 && j < WN)
                atomicAdd(&logits[(size_t)(b*H + h)*WN + j], wom * tnloc[tid]);
            tnloc[tid] = 0.f;
        }
        if (hi == 0) {
            const float* qsrc = qhat + (size_t)(b*H + h + 1)*M*DK;
            int i = tid * 8;
            float4 a0 = *(const float4*)(qsrc + i);
            float4 a1 = *(const float4*)(qsrc + i + 4);
            S8U t8;
            t8.e[0]=f2bf(a0.x); t8.e[1]=f2bf(a0.y); t8.e[2]=f2bf(a0.z); t8.e[3]=f2bf(a0.w);
            t8.e[4]=f2bf(a1.x); t8.e[5]=f2bf(a1.y); t8.e[6]=f2bf(a1.z); t8.e[7]=f2bf(a1.w);
            *(short8*)&Qs[i >> 6][i & 63] = t8.v;
        }
    }
}

// ---------------------------------------------------------------------------
__global__ __launch_bounds__(256) void softmax_k(float* __restrict__ logits,
                                                 float* __restrict__ alast)
{
    int bh = blockIdx.x;
    float* L = logits + (size_t)bh*WN;
    __shared__ float red[256];
    int tid = threadIdx.x;
    float mx = -1e30f;
    for (int j = tid; j < WN; j += 256) mx = fmaxf(mx, L[j]);
    red[tid] = mx; __syncthreads();
    for (int s2 = 128; s2 > 0; s2 >>= 1) {
        if (tid < s2) red[tid] = fmaxf(red[tid], red[tid+s2]);
        __syncthreads();
    }
    mx = red[0]; __syncthreads();
    float sm = 0.f;
    for (int j = tid; j < WN; j += 256) sm += expf(L[j] - mx);
    red[tid] = sm; __syncthreads();
    for (int s2 = 128; s2 > 0; s2 >>= 1) {
        if (tid < s2) red[tid] += red[tid+s2];
        __syncthreads();
    }
    float inv = 1.f / red[0];
    for (int j = tid; j < WN; j += 256) {
        float a = expf(L[j] - mx) * inv;
        L[j] = a;
        if (j == WN-1) alast[bh] = a;
    }
}

// ---------------------------------------------------------------------------
#define JC 191
__global__ __launch_bounds__(256) void xbar_bf_k(
    const unsigned short* __restrict__ xbf, const float* __restrict__ attn,
    float* __restrict__ xbar)
{
    int chunk = blockIdx.x & 31;
    int b = blockIdx.x >> 5;
    int j0 = chunk * JC;
    __shared__ float al[H][JC];
    int tid = threadIdx.x;
    for (int i = tid; i < H*JC; i += 256) {
        int hh = i / JC, jj = i - hh*JC;
        al[hh][jj] = attn[(size_t)(b*H + hh)*WN + j0 + jj];
    }
    __syncthreads();
    int d0 = tid * 2;
    const unsigned* p = (const unsigned*)(xbf + ((size_t)b*S + 31 + j0)*DM + d0);
    float acc[H][2];
    #pragma unroll
    for (int hh = 0; hh < H; ++hh) { acc[hh][0] = 0.f; acc[hh][1] = 0.f; }
    for (int jj = 0; jj < JC; ++jj) {
        unsigned u = p[(size_t)jj*(DM/2)];
        float x0 = bf2f((unsigned short)(u & 0xffff));
        float x1 = bf2f((unsigned short)(u >> 16));
        #pragma unroll
        for (int hh = 0; hh < H; ++hh) {
            float a = al[hh][jj];
            acc[hh][0] += a * x0;
            acc[hh][1] += a * x1;
        }
    }
    #pragma unroll
    for (int hh = 0; hh < H; ++hh) {
        atomicAdd(&xbar[(size_t)(b*H+hh)*DM + d0],     acc[hh][0]);
        atomicAdd(&xbar[(size_t)(b*H+hh)*DM + d0 + 1], acc[hh][1]);
    }
}

__global__ __launch_bounds__(256) void xbar_k(
    const float* __restrict__ memory, const float* __restrict__ attn,
    float* __restrict__ xbar)
{
    int chunk = blockIdx.x & 31;
    int b = blockIdx.x >> 5;
    int j0 = chunk * JC;
    __shared__ float al[H][JC];
    int tid = threadIdx.x;
    for (int i = tid; i < H*JC; i += 256) {
        int hh = i / JC, jj = i - hh*JC;
        al[hh][jj] = attn[(size_t)(b*H + hh)*WN + j0 + jj];
    }
    __syncthreads();
    int d0 = tid * 2;
    float acc[H][2];
    #pragma unroll
    for (int hh = 0; hh < H; ++hh) { acc[hh][0] = 0.f; acc[hh][1] = 0.f; }
    for (int jj = 0; jj < JC; ++jj) {
        int t = 31 + j0 + jj;
        const float2 xv = *(const float2*)(memory + ((size_t)b*SM1 + t)*DM + d0);
        #pragma unroll
        for (int hh = 0; hh < H; ++hh) {
            float a = al[hh][jj];
            acc[hh][0] += a * xv.x;
            acc[hh][1] += a * xv.y;
        }
    }
    #pragma unroll
    for (int hh = 0; hh < H; ++hh) {
        atomicAdd(&xbar[(size_t)(b*H+hh)*DM + d0],     acc[hh][0]);
        atomicAdd(&xbar[(size_t)(b*H+hh)*DM + d0 + 1], acc[hh][1]);
    }
}

// ---------------------------------------------------------------------------
__global__ __launch_bounds__(192) void gi_k(
    const float* __restrict__ memory, const float* __restrict__ W_ih,
    const float* __restrict__ b_ih, float* __restrict__ gi_all)
{
    int t = blockIdx.x >> 3;
    int b = blockIdx.x & 7;
    int c = threadIdx.x;
    const float* xr = memory + ((size_t)b*SM1 + (S - M) + t)*DM;
    const float* wr = W_ih + (size_t)c*DM;
    float s = b_ih[c];
    for (int d = 0; d < DM; d += 4) {
        float4 x4 = *(const float4*)(xr + d);
        float4 w4 = *(const float4*)(wr + d);
        s += x4.x*w4.x + x4.y*w4.y + x4.z*w4.z + x4.w*w4.w;
    }
    gi_all[((size_t)t*BB + b)*192 + c] = s;
}

__global__ __launch_bounds__(512) void gru_scan(
    const float* __restrict__ gi_all, const float* __restrict__ W_hh,
    const float* __restrict__ b_hh, float* __restrict__ res)
{
    int b = threadIdx.x >> 6;
    int l = threadIdx.x & 63;

    float w0[64], w1[64], w2[64];
    {
        const float* r0p = W_hh + (size_t)l*DK;
        const float* r1p = W_hh + (size_t)(64 + l)*DK;
        const float* r2p = W_hh + (size_t)(128 + l)*DK;
        #pragma unroll
        for (int i = 0; i < 16; ++i) {
            float4 a = *(const float4*)(r0p + i*4);
            w0[i*4]=a.x; w0[i*4+1]=a.y; w0[i*4+2]=a.z; w0[i*4+3]=a.w;
            float4 c = *(const float4*)(r1p + i*4);
            w1[i*4]=c.x; w1[i*4+1]=c.y; w1[i*4+2]=c.z; w1[i*4+3]=c.w;
            float4 e = *(const float4*)(r2p + i*4);
            w2[i*4]=e.x; w2[i*4+1]=e.y; w2[i*4+2]=e.z; w2[i*4+3]=e.w;
        }
    }
    float bh0 = b_hh[l], bh1 = b_hh[64 + l], bh2 = b_hh[128 + l];

    float h = 0.f;
    const float* g0 = gi_all + (size_t)b*192;
    float gr = g0[l], gz = g0[64 + l], gn = g0[128 + l];

    #pragma unroll 1
    for (int t = 0; t < 31; ++t) {
        float a0 = bh0, a1 = bh1, a2 = bh2;
        #pragma unroll
        for (int k = 0; k < 64; ++k) {
            float hk = __int_as_float(__builtin_amdgcn_readlane(__float_as_int(h), k));
            a0 += hk * w0[k];
            a1 += hk * w1[k];
            a2 += hk * w2[k];
        }
        float ngr = 0.f, ngz = 0.f, ngn = 0.f;
        if (t < 30) {
            const float* g2 = gi_all + ((size_t)(t+1)*BB + b)*192;
            ngr = g2[l]; ngz = g2[64 + l]; ngn = g2[128 + l];
        }
        float r = 1.f / (1.f + expf(-(gr + a0)));
        float z = 1.f / (1.f + expf(-(gz + a1)));
        float n = tanhf(gn + r * a2);
        h = (1.f - z)*n + z*h;
        gr = ngr; gz = ngz; gn = ngn;
    }
    res[b*DK + l] = h;
}

// ---------------------------------------------------------------------------
__global__ __launch_bounds__(512) void final_k(
    const float* __restrict__ x_pre, const float* __restrict__ xbar,
    const float* __restrict__ Wv, const float* __restrict__ bv,
    const float* __restrict__ WO, const float* __restrict__ bO,
    const float* __restrict__ alast, const float* __restrict__ res,
    const int* __restrict__ G, float* __restrict__ out)
{
    int b = blockIdx.x;
    int tid = threadIdx.x;
    __shared__ float gl[64*64];
    __shared__ float deta[512];
    for (int i = tid; i < 4096; i += 512) gl[i] = (float)G[(i & 63)*64 + (i >> 6)];
    __syncthreads();
    int h = tid >> 6, dk = tid & 63;
    float ala = alast[b*H + h];
    const float* xb  = xbar + (size_t)(b*H + h)*DM;
    const float* wvr = Wv + (size_t)tid*DM;
    const float* gcol = gl + dk;
    float s = 0.f;
    for (int e = 0; e < DM; e += 4) {
        float4 wv4 = *(const float4*)(wvr + e);
        float4 xb4 = *(const float4*)(xb + e);
        int eb = e & 63;
        s += wv4.x*gcol[eb*64]     *xb4.x + wv4.y*gcol[(eb+1)*64]*xb4.y
           + wv4.z*gcol[(eb+2)*64]*xb4.z + wv4.w*gcol[(eb+3)*64]*xb4.w;
    }
    float hist = s + bv[tid]*(1.f - ala);
    deta[tid] = hist + ala * res[b*DK + dk];
    __syncthreads();
    int dpos = tid;
    const float* wor = WO + (size_t)dpos*DM;
    const float* gcol2 = gl + (dpos & 63);
    float o = 0.f;
    for (int jj = 0; jj < DM; jj += 4) {
        float4 wo4 = *(const float4*)(wor + jj);
        int jb = jj & 63;
        o += wo4.x*gcol2[jb*64]     *deta[jj]   + wo4.y*gcol2[(jb+1)*64]*deta[jj+1]
           + wo4.z*gcol2[(jb+2)*64]*deta[jj+2] + wo4.w*gcol2[(jb+3)*64]*deta[jj+3];
    }
    out[(size_t)b*DM + dpos] = x_pre[(size_t)b*DM + dpos] + o + bO[dpos];
}

// ---------------------------------------------------------------------------
extern "C" void kernel_launch(void* const* d_in, const int* in_sizes, int n_in,
                              void* d_out, int out_size, void* d_ws, size_t ws_size,
                              hipStream_t stream)
{
    const float* memory = (const float*)d_in[0];
    const float* x_pre  = (const float*)d_in[1];
    const float* aux    = (const float*)d_in[2];
    const float* pos    = (const float*)d_in[3];
    const float* Wq  = (const float*)d_in[4];
    const float* bq  = (const float*)d_in[5];
    const float* Wk  = (const float*)d_in[6];
    const float* bk  = (const float*)d_in[7];
    const float* Wv  = (const float*)d_in[8];
    const float* bv  = (const float*)d_in[9];
    const float* Wqa = (const float*)d_in[10];
    const float* bqa = (const float*)d_in[11];
    const float* Wka = (const float*)d_in[12];
    const float* bka = (const float*)d_in[13];
    const float* Wqp = (const float*)d_in[14];
    const float* bqp = (const float*)d_in[15];
    const float* Wkp = (const float*)d_in[16];
    const float* bkp = (const float*)d_in[17];
    const float* W_ih = (const float*)d_in[18];
    const float* W_hh = (const float*)d_in[19];
    const float* b_ih = (const float*)d_in[20];
    const float* b_hh = (const float*)d_in[21];
    const float* WO  = (const float*)d_in[22];
    const float* bO  = (const float*)d_in[23];
    const float* w   = (const float*)d_in[24];
    const float* w_a = (const float*)d_in[25];
    const float* w_p = (const float*)d_in[26];
    const int*   G   = (const int*)d_in[27];
    (void)in_sizes; (void)n_in; (void)out_size;

    float* ws = (float*)d_ws;
    unsigned short* wkb  = (unsigned short*)(ws + WS_WKT);
    unsigned short* wkab = (unsigned short*)(ws + WS_WKAT);
    unsigned short* wkpb = (unsigned short*)(ws + WS_WKPT);
    float* qhat   = ws + WS_QHAT;
    float* qahat  = ws + WS_QAHAT;
    float* qphat  = ws + WS_QPHAT;
    float* logits = ws + WS_LOGITS;
    float* xbar   = ws + WS_XBAR;
    float* alast  = ws + WS_ALAST;
    float* resb   = ws + WS_RES;
    float* gi_all = ws + WS_GI;
    float* wqm    = ws + WS_WQM;
    unsigned short* xbf = (unsigned short*)(ws + WS_XBF);
    float* outp   = (float*)d_out;

    const size_t need = ((size_t)WS_XBF + 12582912) * 4;   // ~55.2 MB
    const bool big = (ws_size >= need);

    hipMemsetAsync(logits, 0, (size_t)(N_LOGITS + N_XBAR)*sizeof(float), stream);

    prep_weights<<<(H*DM*DK + H*DA*DAh + H*DP*DPh + H*DK*DM + 255)/256, 256, 0, stream>>>(
        Wk, Wka, Wkp, Wq, G, wkb, wkab, wkpb, wqm);

    if (big)
        xcast_k<<<12288, 256, 0, stream>>>(memory, x_pre, xbf);

    gi_k<<<31*BB, 192, 0, stream>>>(memory, W_ih, b_ih, gi_all);
    gru_scan<<<1, 512, 0, stream>>>(gi_all, W_hh, b_hh, resb);

    qhat_k<<<BB*H, 256, 0, stream>>>(memory, x_pre, aux, pos, wqm, bq, Wqa, bqa,
                                     Wqp, bqp, qhat, qahat, qphat);

    if (big)
        kproj_mfma3<<<96*8*BB, 256, 0, stream>>>(xbf, wkb, bk, qhat, w, logits);
    else
        kproj_band_mfma2<<<48*BB*4, 256, 0, stream>>>(memory, x_pre, wkb, bk, qhat,
                                                      w, logits);

    ka_proj_mfma<<<BB*96, 256, 0, stream>>>(aux, wkab, bka, qahat, w_a, logits);
    kp_proj_mfma<<<BB*96, 256, 0, stream>>>(pos, wkpb, bkp, qphat, w_p, logits);

    softmax_k<<<BB*H, 256, 0, stream>>>(logits, alast);

    if (big)
        xbar_bf_k<<<BB*32, 256, 0, stream>>>(xbf, logits, xbar);
    else
        xbar_k<<<BB*32, 256, 0, stream>>>(memory, logits, xbar);

    final_k<<<BB, 512, 0, stream>>>(x_pre, xbar, Wv, bv, WO, bO, alast, resb, G, outp);
}